// Round 2
// baseline (25690.927 us; speedup 1.0000x reference)
//
#include <hip/hip_runtime.h>
#include <hip/hip_bf16.h>
#include <math.h>

#define B_ 4
#define SEQ_ 2048
#define DIM_ 768
#define DEPTH_ 6
#define HEADS_ 12
#define DH_ 64
#define MF_ 256
#define FF_ 3072
#define ROWS_ 8192
#define BH_ 48
#define DN_ 0.3535533905932738f   /* 64^-0.25 */
#define RATIO_ 0.0625f            /* 256^-0.5 */
#define EPSK_ 1e-4f
#define EPSLN_ 1e-5f

#define FMA16(acc,a,b) do{ \
  acc[0][0]+=a.x*b.x; acc[0][1]+=a.x*b.y; acc[0][2]+=a.x*b.z; acc[0][3]+=a.x*b.w; \
  acc[1][0]+=a.y*b.x; acc[1][1]+=a.y*b.y; acc[1][2]+=a.y*b.z; acc[1][3]+=a.y*b.w; \
  acc[2][0]+=a.z*b.x; acc[2][1]+=a.z*b.y; acc[2][2]+=a.z*b.z; acc[2][3]+=a.z*b.w; \
  acc[3][0]+=a.w*b.x; acc[3][1]+=a.w*b.y; acc[3][2]+=a.w*b.z; acc[3][3]+=a.w*b.w; }while(0)

// ---------------- embedding ----------------
__global__ void embed_kernel(const int* __restrict__ x, const float4* __restrict__ tok,
                             const float4* __restrict__ pos, float4* __restrict__ h){
  const int C4 = DIM_/4; // 192
  long total = (long)ROWS_*C4;
  for (long i = (long)blockIdx.x*blockDim.x + threadIdx.x; i < total;
       i += (long)gridDim.x*blockDim.x){
    int row = (int)(i / C4); int c = (int)(i - (long)row*C4);
    int n = row & (SEQ_-1);
    float4 a = tok[(long)x[row]*C4 + c];
    float4 p = pos[(long)n*C4 + c];
    float4 o; o.x=a.x+p.x; o.y=a.y+p.y; o.z=a.z+p.z; o.w=a.w+p.w;
    h[i] = o;
  }
}

// ---------------- layernorm (row = 768) ----------------
__global__ __launch_bounds__(256) void ln_kernel(const float* __restrict__ X,
                          const float* __restrict__ g, const float* __restrict__ bta,
                          float* __restrict__ Y){
  int row = blockIdx.x; int t = threadIdx.x;
  const float* xr = X + (long)row*DIM_;
  float v0 = xr[t], v1 = xr[t+256], v2 = xr[t+512];
  float s = v0+v1+v2;
  float ss = v0*v0+v1*v1+v2*v2;
  int lane = t&63, wid = t>>6;
  #pragma unroll
  for (int off=32; off; off>>=1){ s += __shfl_xor(s,off); ss += __shfl_xor(ss,off); }
  __shared__ float red[8];
  if (lane==0){ red[wid]=s; red[4+wid]=ss; }
  __syncthreads();
  s  = red[0]+red[1]+red[2]+red[3];
  ss = red[4]+red[5]+red[6]+red[7];
  float mu  = s*(1.0f/DIM_);
  float var = ss*(1.0f/DIM_) - mu*mu;
  float rs  = rsqrtf(var + EPSLN_);
  float* yr = Y + (long)row*DIM_;
  yr[t]     = (v0-mu)*rs*g[t]     + bta[t];
  yr[t+256] = (v1-mu)*rs*g[t+256] + bta[t+256];
  yr[t+512] = (v2-mu)*rs*g[t+512] + bta[t+512];
}

// ---- generic fp32 GEMM: C[.,ldC] = act(A[M,K;ldA]@B[K,.;ldB] + bias) (+=) ----
// grid.x*64 covers the output-column window; Bm/bias/C pre-offset by caller.
template<int ACT, int ADDTO>
__global__ __launch_bounds__(256) void gemm_kernel(const float* __restrict__ A,
                        const float* __restrict__ Bm, const float* __restrict__ bias,
                        float* __restrict__ C, int M, int K, int ldA, int ldB, int ldC){
  __shared__ alignas(16) float Ast[16][68];
  __shared__ alignas(16) float Bs[16][64];
  int tid = threadIdx.x;
  int tx = tid & 15, ty = tid >> 4;
  int n0 = blockIdx.x*64, m0 = blockIdx.y*64;
  float acc[4][4] = {};
  for (int k0=0; k0<K; k0+=16){
    __syncthreads();
    #pragma unroll
    for (int i=0;i<4;i++){
      int e = tid + i*256;
      int ar = e>>4, ac = e&15;
      Ast[ac][ar] = A[(long)(m0+ar)*ldA + k0+ac];
      int br = e>>6, bc = e&63;
      Bs[br][bc] = Bm[(long)(k0+br)*ldB + n0+bc];
    }
    __syncthreads();
    #pragma unroll
    for (int kk=0;kk<16;kk++){
      float4 a = *(const float4*)&Ast[kk][ty*4];
      float4 b = *(const float4*)&Bs[kk][tx*4];
      FMA16(acc,a,b);
    }
  }
  #pragma unroll
  for (int i=0;i<4;i++){
    int m = m0 + ty*4 + i;
    float* crow = C + (long)m*ldC + n0 + tx*4;
    #pragma unroll
    for (int j=0;j<4;j++){
      float val = acc[i][j];
      if (bias) val += bias[n0+tx*4+j];
      if (ACT==1) val = 0.5f*val*(1.0f+erff(val*0.70710678118654752f));
      if (ADDTO) crow[j] += val; else crow[j] = val;
    }
  }
}

// ---------------- K pass 1: global max of xd per (b,h) ----------------
__global__ __launch_bounds__(256) void kmax_kernel(const float* __restrict__ X,
                        const float* __restrict__ proj, float* __restrict__ kmaxp){
  int z = blockIdx.y; int b = z/HEADS_, hh = z - b*HEADS_;
  int n0 = blockIdx.x*16;
  int t = threadIdx.x;
  __shared__ alignas(16) float qs[16][64];
  __shared__ float bmax_s[4];
  const float* xb = X + ((long)b*SEQ_ + n0)*DIM_ + hh*DH_;
  #pragma unroll
  for (int i=0;i<4;i++){ int e=t+i*256; int r=e>>6, d=e&63; qs[r][d]=xb[(long)r*DIM_+d]; }
  float preg[64];
  const float* pr = proj + t*DH_;
  #pragma unroll
  for (int d4=0; d4<16; d4++){
    float4 p4 = *(const float4*)&pr[d4*4];
    preg[4*d4]=p4.x; preg[4*d4+1]=p4.y; preg[4*d4+2]=p4.z; preg[4*d4+3]=p4.w;
  }
  __syncthreads();
  float bm = -1e30f;
  #pragma unroll
  for (int r=0;r<16;r++){
    float a = 0.f;
    #pragma unroll
    for (int d4=0; d4<16; d4++){
      float4 qv = *(const float4*)&qs[r][d4*4];
      a += qv.x*preg[4*d4] + qv.y*preg[4*d4+1] + qv.z*preg[4*d4+2] + qv.w*preg[4*d4+3];
    }
    bm = fmaxf(bm, a*DN_);
  }
  int lane=t&63, wid=t>>6;
  #pragma unroll
  for (int off=32; off; off>>=1) bm = fmaxf(bm, __shfl_xor(bm,off));
  if (lane==0) bmax_s[wid]=bm;
  __syncthreads();
  if (t==0)
    kmaxp[z*128 + blockIdx.x] = fmaxf(fmaxf(bmax_s[0],bmax_s[1]),fmaxf(bmax_s[2],bmax_s[3]));
}

__global__ void kmax_reduce(const float* __restrict__ part, float* __restrict__ stab){
  int z = blockIdx.x; int t = threadIdx.x; // 64 threads
  float m = fmaxf(part[z*128+t], part[z*128+64+t]);
  #pragma unroll
  for (int off=32; off; off>>=1) m = fmaxf(m, __shfl_xor(m,off));
  if (t==0) stab[z] = m;
}

// -- K pass 2: kp computed on the fly; accumulate ctx partials + ksum partials --
// grid (8 n-chunks, 48 z). thread t owns feature m=t. No kp materialization.
__global__ __launch_bounds__(256) void kctx_kernel(const float* __restrict__ K,
                        const float* __restrict__ V, const float* __restrict__ proj,
                        const float* __restrict__ stab, float* __restrict__ ctxp,
                        float* __restrict__ ksp){
  int chunk = blockIdx.x; int z = blockIdx.y;
  int b = z/HEADS_, hh = z - b*HEADS_;
  int t = threadIdx.x;
  __shared__ alignas(16) float ks_[16][64];
  __shared__ alignas(16) float vs_[16][64];
  __shared__ float diag_s[16];
  float preg[64];
  const float* pr = proj + t*DH_;
  #pragma unroll
  for (int d4=0; d4<16; d4++){
    float4 p4 = *(const float4*)&pr[d4*4];
    preg[4*d4]=p4.x; preg[4*d4+1]=p4.y; preg[4*d4+2]=p4.z; preg[4*d4+3]=p4.w;
  }
  float st = stab[z];
  float actx[64];
  #pragma unroll
  for (int d=0; d<64; d++) actx[d]=0.f;
  float aks = 0.f;
  int nbase = chunk*256;
  for (int sub=0; sub<16; sub++){
    int n0 = nbase + sub*16;
    const float* kb_ = K + ((long)b*SEQ_ + n0)*DIM_ + hh*DH_;
    const float* vb_ = V + ((long)b*SEQ_ + n0)*DIM_ + hh*DH_;
    __syncthreads();
    #pragma unroll
    for (int i=0;i<4;i++){
      int e = t + i*256; int r = e>>6, d = e&63;
      ks_[r][d] = kb_[(long)r*DIM_ + d];
      vs_[r][d] = vb_[(long)r*DIM_ + d];
    }
    __syncthreads();
    if (t<16){
      float sq=0.f;
      #pragma unroll
      for (int d=0; d<64; d++){ float vv=ks_[t][d]; sq+=vv*vv; }
      diag_s[t]=0.5f*DN_*DN_*sq;
    }
    __syncthreads();
    #pragma unroll
    for (int r=0;r<16;r++){
      float a = 0.f;
      #pragma unroll
      for (int d4=0; d4<16; d4++){
        float4 kv = *(const float4*)&ks_[r][d4*4];
        a += kv.x*preg[4*d4] + kv.y*preg[4*d4+1] + kv.z*preg[4*d4+2] + kv.w*preg[4*d4+3];
      }
      float kp = RATIO_*(expf(a*DN_ - diag_s[r] - st) + EPSK_);
      aks += kp;
      #pragma unroll
      for (int d4=0; d4<16; d4++){
        float4 vv = *(const float4*)&vs_[r][d4*4];
        actx[4*d4]   += kp*vv.x;
        actx[4*d4+1] += kp*vv.y;
        actx[4*d4+2] += kp*vv.z;
        actx[4*d4+3] += kp*vv.w;
      }
    }
  }
  float* cp = ctxp + ((long)chunk*BH_ + z)*(MF_*DH_) + (long)t*DH_;
  #pragma unroll
  for (int d4=0; d4<16; d4++){
    float4 o; o.x=actx[4*d4]; o.y=actx[4*d4+1]; o.z=actx[4*d4+2]; o.w=actx[4*d4+3];
    *(float4*)&cp[4*d4] = o;
  }
  ksp[(z*8+chunk)*MF_ + t] = aks;
}

__global__ void ctx_reduce(const float* __restrict__ part, float* __restrict__ ctx){
  const long NT = (long)BH_*MF_*DH_; // 786432
  for (long i = (long)blockIdx.x*256 + threadIdx.x; i < NT; i += (long)gridDim.x*256){
    float s = 0.f;
    #pragma unroll
    for (int c=0;c<8;c++) s += part[(long)c*NT + i];
    ctx[i] = s;
  }
}

__global__ void ksum_reduce(const float* __restrict__ part, float* __restrict__ ksum){
  int z = blockIdx.x; int t = threadIdx.x;
  float s = 0.f;
  #pragma unroll
  for (int c=0;c<8;c++) s += part[(z*8+c)*MF_ + t];
  ksum[z*MF_+t] = s;
}

// ---- fused Q: features + rowmax + dinv + (qp@ctx)*dinv, no qp materialization ----
__global__ __launch_bounds__(256) void qout_kernel(const float* __restrict__ X,
        const float* __restrict__ proj, const float* __restrict__ ctx,
        const float* __restrict__ ksum, float* __restrict__ attn){
  int z = blockIdx.y; int b = z/HEADS_, hh = z - b*HEADS_;
  int n0 = blockIdx.x*16;
  int t = threadIdx.x;
  __shared__ alignas(16) float qs[16][64];
  __shared__ float diag_s[16];
  __shared__ float redm[16][4];
  __shared__ float redd[16][4];
  __shared__ float qp_s[16][260];
  const float* xb = X + ((long)b*SEQ_ + n0)*DIM_ + hh*DH_;
  #pragma unroll
  for (int i=0;i<4;i++){ int e=t+i*256; int r=e>>6, d=e&63; qs[r][d]=xb[(long)r*DIM_+d]; }
  float preg[64];
  const float* pr = proj + t*DH_;
  #pragma unroll
  for (int d4=0; d4<16; d4++){
    float4 p4 = *(const float4*)&pr[d4*4];
    preg[4*d4]=p4.x; preg[4*d4+1]=p4.y; preg[4*d4+2]=p4.z; preg[4*d4+3]=p4.w;
  }
  __syncthreads();
  if (t<16){
    float sq=0.f;
    #pragma unroll
    for (int d=0; d<64; d++){ float vv=qs[t][d]; sq+=vv*vv; }
    diag_s[t]=0.5f*DN_*DN_*sq;
  }
  __syncthreads();
  float xd[16];
  #pragma unroll
  for (int r=0;r<16;r++){
    float a = 0.f;
    #pragma unroll
    for (int d4=0; d4<16; d4++){
      float4 qv = *(const float4*)&qs[r][d4*4];
      a += qv.x*preg[4*d4] + qv.y*preg[4*d4+1] + qv.z*preg[4*d4+2] + qv.w*preg[4*d4+3];
    }
    xd[r] = a*DN_;
  }
  int lane=t&63, wid=t>>6;
  #pragma unroll
  for (int r=0;r<16;r++){
    float m = xd[r];
    #pragma unroll
    for (int off=32; off; off>>=1) m = fmaxf(m, __shfl_xor(m,off));
    if (lane==0) redm[r][wid]=m;
  }
  __syncthreads();
  float ks = ksum[(long)z*MF_ + t];
  #pragma unroll
  for (int r=0;r<16;r++){
    float mx = fmaxf(fmaxf(redm[r][0],redm[r][1]),fmaxf(redm[r][2],redm[r][3]));
    float qp = RATIO_*(expf(xd[r] - diag_s[r] - mx) + EPSK_);
    qp_s[r][t] = qp;
    float dv = qp*ks;
    #pragma unroll
    for (int off=32; off; off>>=1) dv += __shfl_xor(dv,off);
    if (lane==0) redd[r][wid]=dv;
  }
  __syncthreads();
  int r = t>>4, d4 = t&15;
  float di = 1.0f/(redd[r][0]+redd[r][1]+redd[r][2]+redd[r][3]);
  const float* cz = ctx + (long)z*MF_*DH_ + d4*4;
  float ox=0.f, oy=0.f, oz=0.f, ow=0.f;
  #pragma unroll 4
  for (int m=0;m<256;m++){
    float qpv = qp_s[r][m];
    float4 c4 = *(const float4*)&cz[(long)m*DH_];
    ox += qpv*c4.x; oy += qpv*c4.y; oz += qpv*c4.z; ow += qpv*c4.w;
  }
  float4 o; o.x=ox*di; o.y=oy*di; o.z=oz*di; o.w=ow*di;
  *(float4*)(attn + ((long)b*SEQ_ + n0 + r)*DIM_ + hh*DH_ + d4*4) = o;
}

// ---------------- final LN(row0) + pooler + classifier ----------------
__global__ __launch_bounds__(256) void pooler_kernel(const float* __restrict__ h,
                           const float* __restrict__ g, const float* __restrict__ bta,
                           const float* __restrict__ Wp, const float* __restrict__ bp,
                           const float* __restrict__ Wc, const float* __restrict__ bc,
                           float* __restrict__ out){
  int b = blockIdx.x, t = threadIdx.x;
  __shared__ float xn[768];
  __shared__ float pl[768];
  __shared__ float red[8];
  const float* row = h + (long)b*SEQ_*DIM_;
  float v0=row[t], v1=row[t+256], v2=row[t+512];
  float s = v0+v1+v2, ss = v0*v0+v1*v1+v2*v2;
  int lane=t&63, wid=t>>6;
  #pragma unroll
  for (int off=32; off; off>>=1){ s += __shfl_xor(s,off); ss += __shfl_xor(ss,off); }
  if (lane==0){ red[wid]=s; red[4+wid]=ss; }
  __syncthreads();
  s  = red[0]+red[1]+red[2]+red[3];
  ss = red[4]+red[5]+red[6]+red[7];
  float mu = s*(1.0f/DIM_);
  float var = ss*(1.0f/DIM_) - mu*mu;
  float rs = rsqrtf(var + EPSLN_);
  xn[t]     = (v0-mu)*rs*g[t]     + bta[t];
  xn[t+256] = (v1-mu)*rs*g[t+256] + bta[t+256];
  xn[t+512] = (v2-mu)*rs*g[t+512] + bta[t+512];
  __syncthreads();
  #pragma unroll
  for (int jj=0;jj<3;jj++){
    int j = t + jj*256;
    float a = bp[j];
    for (int i=0;i<768;i++) a += xn[i]*Wp[(long)i*DIM_ + j];
    pl[j] = tanhf(a);
  }
  __syncthreads();
  if (wid < 2){
    float a = 0.f;
    for (int i=lane;i<768;i+=64) a += pl[i]*Wc[i*2+wid];
    #pragma unroll
    for (int off=32; off; off>>=1) a += __shfl_xor(a,off);
    if (lane==0) out[b*2+wid] = a + bc[wid];
  }
}

extern "C" void kernel_launch(void* const* d_in, const int* in_sizes, int n_in,
                              void* d_out, int out_size, void* d_ws, size_t ws_size,
                              hipStream_t stream) {
  (void)in_sizes; (void)n_in; (void)out_size; (void)ws_size;
  const int*   x    = (const int*)  d_in[0];
  const float* tok  = (const float*)d_in[1];
  const float* pos  = (const float*)d_in[2];
  const float* ln1g = (const float*)d_in[3];
  const float* ln1b = (const float*)d_in[4];
  const float* Wq   = (const float*)d_in[5];
  const float* Wk   = (const float*)d_in[6];
  const float* Wv   = (const float*)d_in[7];
  const float* Wo   = (const float*)d_in[8];
  const float* bo   = (const float*)d_in[9];
  const float* proj = (const float*)d_in[10];
  const float* ln2g = (const float*)d_in[11];
  const float* ln2b = (const float*)d_in[12];
  const float* W1   = (const float*)d_in[13];
  const float* b1   = (const float*)d_in[14];
  const float* W2   = (const float*)d_in[15];
  const float* b2   = (const float*)d_in[16];
  const float* lnfg = (const float*)d_in[17];
  const float* lnfb = (const float*)d_in[18];
  const float* Wp   = (const float*)d_in[19];
  const float* bp   = (const float*)d_in[20];
  const float* Wc   = (const float*)d_in[21];
  const float* bc   = (const float*)d_in[22];
  float* out = (float*)d_out;

  // workspace: 5*NR + ctx + small  = 32,360,512 floats = 123.4 MiB total
  float* ws = (float*)d_ws;
  const size_t NR = (size_t)ROWS_*DIM_;       // 6,291,456
  float* h    = ws;
  float* y    = h   + NR;      // also: ctx partials (8*48*16384 == NR), attn out
  float* qb   = y   + NR;      // also: ffn chunk buffer (spans qb+kb = 2*NR)
  float* kb   = qb  + NR;
  float* vb   = kb  + NR;
  float* ctx  = vb  + NR;                     // 786,432
  float* ksp  = ctx + (size_t)BH_*MF_*DH_;    // 98,304
  float* ksum = ksp + 48*8*256;               // 12,288
  float* kmaxp= ksum+ 48*256;                 // 6,144
  float* stab = kmaxp + 48*128;               // 64
  float* ctxp = y;
  float* attn = y;
  float* ffnb = qb;

  embed_kernel<<<2048,256,0,stream>>>(x,(const float4*)tok,(const float4*)pos,(float4*)h);

  dim3 gD(12, 128);             // 768-wide output
  dim3 gH(24, 128);             // 1536-wide output (FFN chunk)
  dim3 gfeat(SEQ_/16, BH_);     // (128,48)

  for (int l=0; l<DEPTH_; l++){
    const float* wq  = Wq + (size_t)l*DIM_*DIM_;
    const float* wk  = Wk + (size_t)l*DIM_*DIM_;
    const float* wv  = Wv + (size_t)l*DIM_*DIM_;
    const float* wo  = Wo + (size_t)l*DIM_*DIM_;
    const float* prj = proj + (size_t)l*MF_*DH_;
    const float* w1  = W1 + (size_t)l*DIM_*FF_;
    const float* w2  = W2 + (size_t)l*FF_*DIM_;

    ln_kernel<<<ROWS_,256,0,stream>>>(h, ln1g+(size_t)l*DIM_, ln1b+(size_t)l*DIM_, y);
    gemm_kernel<0,0><<<gD,256,0,stream>>>(y, wq, nullptr, qb, ROWS_, DIM_, DIM_, DIM_, DIM_);
    gemm_kernel<0,0><<<gD,256,0,stream>>>(y, wk, nullptr, kb, ROWS_, DIM_, DIM_, DIM_, DIM_);
    gemm_kernel<0,0><<<gD,256,0,stream>>>(y, wv, nullptr, vb, ROWS_, DIM_, DIM_, DIM_, DIM_);

    kmax_kernel<<<gfeat,256,0,stream>>>(kb, prj, kmaxp);
    kmax_reduce<<<BH_,64,0,stream>>>(kmaxp, stab);
    kctx_kernel<<<dim3(8,BH_),256,0,stream>>>(kb, vb, prj, stab, ctxp, ksp);
    ctx_reduce<<<768,256,0,stream>>>(ctxp, ctx);
    ksum_reduce<<<BH_,256,0,stream>>>(ksp, ksum);

    qout_kernel<<<gfeat,256,0,stream>>>(qb, prj, ctx, ksum, attn);

    gemm_kernel<0,1><<<gD,256,0,stream>>>(attn, wo, bo+(size_t)l*DIM_, h, ROWS_, DIM_, DIM_, DIM_, DIM_);

    ln_kernel<<<ROWS_,256,0,stream>>>(h, ln2g+(size_t)l*DIM_, ln2b+(size_t)l*DIM_, y);
    for (int c=0; c<2; c++){
      gemm_kernel<1,0><<<gH,256,0,stream>>>(y, w1 + c*1536,
          b1+(size_t)l*FF_ + c*1536, ffnb, ROWS_, DIM_, DIM_, FF_, 1536);
      gemm_kernel<0,1><<<gD,256,0,stream>>>(ffnb, w2 + (size_t)c*1536*DIM_,
          (c==0 ? b2+(size_t)l*DIM_ : nullptr), h, ROWS_, 1536, 1536, DIM_, DIM_);
    }
  }

  pooler_kernel<<<B_,256,0,stream>>>(h, lnfg, lnfb, Wp, bp, Wc, bc, out);
}

// Round 3
// 15073.851 us; speedup vs baseline: 1.7043x; 1.7043x over previous
//
#include <hip/hip_runtime.h>
#include <hip/hip_bf16.h>
#include <math.h>

#define B_ 4
#define SEQ_ 2048
#define DIM_ 768
#define DEPTH_ 6
#define HEADS_ 12
#define DH_ 64
#define MF_ 256
#define FF_ 3072
#define ROWS_ 8192
#define BH_ 48
#define DN_ 0.3535533905932738f   /* 64^-0.25 */
#define RATIO_ 0.0625f            /* 256^-0.5 */
#define EPSK_ 1e-4f
#define EPSLN_ 1e-5f

typedef unsigned short u16;
typedef unsigned int   u32;
typedef __bf16 bf16x8 __attribute__((ext_vector_type(8)));
typedef float  f32x4  __attribute__((ext_vector_type(4)));

__device__ inline u16 f2bf(float x){
  u32 u = __builtin_bit_cast(u32, x);
  return (u16)((u + 0x7FFFu + ((u>>16)&1u)) >> 16);
}
__device__ inline float bf2f(u16 v){ return __builtin_bit_cast(float, (u32)v<<16); }

__device__ inline void gload16(const u16* g, u16* lds){
  __builtin_amdgcn_global_load_lds(
    (const __attribute__((address_space(1))) u32*)(const void*)g,
    (__attribute__((address_space(3))) u32*)(void*)lds, 16, 0, 0);
}

// ---------------- embedding (h fp32) ----------------
__global__ void embed_kernel(const int* __restrict__ x, const float4* __restrict__ tok,
                             const float4* __restrict__ pos, float4* __restrict__ h){
  const int C4 = DIM_/4;
  long total = (long)ROWS_*C4;
  for (long i = (long)blockIdx.x*blockDim.x + threadIdx.x; i < total;
       i += (long)gridDim.x*blockDim.x){
    int row = (int)(i / C4); int c = (int)(i - (long)row*C4);
    int n = row & (SEQ_-1);
    float4 a = tok[(long)x[row]*C4 + c];
    float4 p = pos[(long)n*C4 + c];
    float4 o; o.x=a.x+p.x; o.y=a.y+p.y; o.z=a.z+p.z; o.w=a.w+p.w;
    h[i] = o;
  }
}

// ---------------- layernorm fp32 -> bf16 ----------------
__global__ __launch_bounds__(256) void ln_kernel(const float* __restrict__ X,
                          const float* __restrict__ g, const float* __restrict__ bta,
                          u16* __restrict__ Y){
  int row = blockIdx.x; int t = threadIdx.x;
  const float* xr = X + (long)row*DIM_;
  float v0 = xr[t], v1 = xr[t+256], v2 = xr[t+512];
  float s = v0+v1+v2;
  float ss = v0*v0+v1*v1+v2*v2;
  int lane = t&63, wid = t>>6;
  #pragma unroll
  for (int off=32; off; off>>=1){ s += __shfl_xor(s,off); ss += __shfl_xor(ss,off); }
  __shared__ float red[8];
  if (lane==0){ red[wid]=s; red[4+wid]=ss; }
  __syncthreads();
  s  = red[0]+red[1]+red[2]+red[3];
  ss = red[4]+red[5]+red[6]+red[7];
  float mu  = s*(1.0f/DIM_);
  float var = ss*(1.0f/DIM_) - mu*mu;
  float rs  = rsqrtf(var + EPSLN_);
  u16* yr = Y + (long)row*DIM_;
  yr[t]     = f2bf((v0-mu)*rs*g[t]     + bta[t]);
  yr[t+256] = f2bf((v1-mu)*rs*g[t+256] + bta[t+256]);
  yr[t+512] = f2bf((v2-mu)*rs*g[t+512] + bta[t+512]);
}

// ---------------- transpose + convert: WT[n][k] = bf16(W[k][n]) ----------------
__global__ __launch_bounds__(256) void tconv_kernel(const float* __restrict__ W,
        u16* __restrict__ WT, int K, int N){
  __shared__ float tile[32][33];
  int n0 = blockIdx.x*32, k0 = blockIdx.y*32;
  int tx = threadIdx.x & 31, ty = threadIdx.x >> 5;
  #pragma unroll
  for (int i=0;i<32;i+=8) tile[ty+i][tx] = W[(long)(k0+ty+i)*N + n0+tx];
  __syncthreads();
  #pragma unroll
  for (int i=0;i<32;i+=8) WT[(long)(n0+ty+i)*K + k0+tx] = f2bf(tile[tx][ty+i]);
}

// ---------------- MFMA GEMM: C = f(A[M,K]bf16 @ BT[N,K]^T bf16 + bias) ----------------
// 256 thr = 4 waves (WM x WN), wave tile (FM*16) x (FN*16). BK=32.
// Staging: global_load_lds w=16, LDS linear [rows][32] with XOR-swizzled source
// (granule cq of row r holds global granule cq ^ ((r>>1)&3)) -> 2-way-free ds_read_b128.
// CMODE: 0 = bf16 store (+bias,+gelu if ACT); 1 = fp32 C += (+bias); 2 = bf16 store * scale[row]
template<int FM, int FN, int WM, int WN, int ACT, int CMODE, int BATCH>
__global__ __launch_bounds__(256) void mgemm(const u16* __restrict__ A,
     const u16* __restrict__ BT, const float* __restrict__ bias,
     void* __restrict__ Cv, const float* __restrict__ scale,
     int M, int N, int K, int ldC){
  (void)M;
  constexpr int BM = WM*FM*16, BN = WN*FN*16;
  constexpr int ACH = BM/16, BCH = BN/16;   // 1KB staging chunks (16 rows x 64B)
  __shared__ u16 As[BM*32];
  __shared__ u16 Bs[BN*32];
  int tid = threadIdx.x; int w = tid>>6, l = tid&63;
  int m0 = blockIdx.y*BM, n0 = blockIdx.x*BN;
  long coff = 0, srow0 = 0;
  if (BATCH){
    int z = blockIdx.z;
    A  += (long)z*2048*K;
    BT += (long)z*(long)N*K;
    coff  = (long)(z/HEADS_)*SEQ_*(long)ldC + (long)(z%HEADS_)*64;
    srow0 = (long)z*SEQ_;
  }
  f32x4 acc[FM][FN];
  #pragma unroll
  for (int i=0;i<FM;i++)
    #pragma unroll
    for (int j=0;j<FN;j++) acc[i][j] = (f32x4){0.f,0.f,0.f,0.f};

  const int row_l = l>>2, cq_l = l&3;
  const int wm = w / WN, wn = w % WN;
  const int kq = l>>4, rl15 = l&15;

  for (int k0=0; k0<K; k0+=32){
    __syncthreads();
    for (int c = w; c < ACH; c += 4){
      int r = c*16 + row_l;
      int gq = cq_l ^ ((r>>1)&3);
      gload16(A + (long)(m0+r)*K + k0 + gq*8, As + c*512);
    }
    for (int c = w; c < BCH; c += 4){
      int r = c*16 + row_l;
      int gq = cq_l ^ ((r>>1)&3);
      gload16(BT + (long)(n0+r)*K + k0 + gq*8, Bs + c*512);
    }
    __syncthreads();
    bf16x8 af[FM], bfr[FN];
    #pragma unroll
    for (int mi=0; mi<FM; mi++){
      int rr = (wm*FM + mi)*16 + rl15;
      int g = kq ^ ((rr>>1)&3);
      af[mi] = *(const bf16x8*)(As + rr*32 + g*8);
    }
    #pragma unroll
    for (int ni=0; ni<FN; ni++){
      int rr = (wn*FN + ni)*16 + rl15;
      int g = kq ^ ((rr>>1)&3);
      bfr[ni] = *(const bf16x8*)(Bs + rr*32 + g*8);
    }
    #pragma unroll
    for (int mi=0; mi<FM; mi++)
      #pragma unroll
      for (int ni=0; ni<FN; ni++)
        acc[mi][ni] = __builtin_amdgcn_mfma_f32_16x16x32_bf16(af[mi], bfr[ni], acc[mi][ni], 0, 0, 0);
  }

  int cc = l&15, rq = l>>4;
  #pragma unroll
  for (int mi=0; mi<FM; mi++){
    #pragma unroll
    for (int ni=0; ni<FN; ni++){
      int gcol = n0 + (wn*FN+ni)*16 + cc;
      float bv = bias ? bias[gcol] : 0.f;
      #pragma unroll
      for (int r4=0; r4<4; r4++){
        int grow = m0 + (wm*FM+mi)*16 + rq*4 + r4;
        float v = acc[mi][ni][r4] + bv;
        if (ACT) v = 0.5f*v*(1.0f + erff(v*0.70710678118654752f));
        if (CMODE==1){
          float* C = (float*)Cv;
          C[(long)grow*ldC + gcol] += v;
        } else if (CMODE==2){
          v *= scale[srow0 + grow];
          ((u16*)Cv)[coff + (long)grow*ldC + gcol] = f2bf(v);
        } else {
          ((u16*)Cv)[(long)grow*ldC + gcol] = f2bf(v);
        }
      }
    }
  }
}

// ---------------- K pass 1: global max of xd per (b,h) (bf16 K input) ----------------
__global__ __launch_bounds__(256) void kmax_kernel(const u16* __restrict__ X,
                        const float* __restrict__ proj, float* __restrict__ kmaxp){
  int z = blockIdx.y; int b = z/HEADS_, hh = z - b*HEADS_;
  int n0 = blockIdx.x*16;
  int t = threadIdx.x;
  __shared__ float qs[16][64];
  __shared__ float bmax_s[4];
  const u16* xb = X + ((long)b*SEQ_ + n0)*DIM_ + hh*DH_;
  #pragma unroll
  for (int i=0;i<4;i++){ int e=t+i*256; int r=e>>6, d=e&63; qs[r][d]=bf2f(xb[(long)r*DIM_+d]); }
  float preg[64];
  const float* pr = proj + t*DH_;
  #pragma unroll
  for (int d4=0; d4<16; d4++){
    float4 p4 = *(const float4*)&pr[d4*4];
    preg[4*d4]=p4.x; preg[4*d4+1]=p4.y; preg[4*d4+2]=p4.z; preg[4*d4+3]=p4.w;
  }
  __syncthreads();
  float bm = -1e30f;
  #pragma unroll
  for (int r=0;r<16;r++){
    float a = 0.f;
    #pragma unroll
    for (int d4=0; d4<16; d4++){
      float4 qv = *(const float4*)&qs[r][d4*4];
      a += qv.x*preg[4*d4] + qv.y*preg[4*d4+1] + qv.z*preg[4*d4+2] + qv.w*preg[4*d4+3];
    }
    bm = fmaxf(bm, a*DN_);
  }
  int lane=t&63, wid=t>>6;
  #pragma unroll
  for (int off=32; off; off>>=1) bm = fmaxf(bm, __shfl_xor(bm,off));
  if (lane==0) bmax_s[wid]=bm;
  __syncthreads();
  if (t==0)
    kmaxp[z*128 + blockIdx.x] = fmaxf(fmaxf(bmax_s[0],bmax_s[1]),fmaxf(bmax_s[2],bmax_s[3]));
}

__global__ void kmax_reduce(const float* __restrict__ part, float* __restrict__ stab){
  int z = blockIdx.x; int t = threadIdx.x; // 64
  float m = fmaxf(part[z*128+t], part[z*128+64+t]);
  #pragma unroll
  for (int off=32; off; off>>=1) m = fmaxf(m, __shfl_xor(m,off));
  if (t==0) stab[z] = m;
}

// -- K pass 2: kp on the fly; ctx partials + ksum partials (bf16 K/V inputs) --
__global__ __launch_bounds__(256) void kctx_kernel(const u16* __restrict__ K,
                        const u16* __restrict__ V, const float* __restrict__ proj,
                        const float* __restrict__ stab, float* __restrict__ ctxp,
                        float* __restrict__ ksp){
  int chunk = blockIdx.x; int z = blockIdx.y;
  int b = z/HEADS_, hh = z - b*HEADS_;
  int t = threadIdx.x;
  __shared__ float ks_[16][64];
  __shared__ float vs_[16][64];
  __shared__ float diag_s[16];
  float preg[64];
  const float* pr = proj + t*DH_;
  #pragma unroll
  for (int d4=0; d4<16; d4++){
    float4 p4 = *(const float4*)&pr[d4*4];
    preg[4*d4]=p4.x; preg[4*d4+1]=p4.y; preg[4*d4+2]=p4.z; preg[4*d4+3]=p4.w;
  }
  float st = stab[z];
  float actx[64];
  #pragma unroll
  for (int d=0; d<64; d++) actx[d]=0.f;
  float aks = 0.f;
  int nbase = chunk*256;
  for (int sub=0; sub<16; sub++){
    int n0 = nbase + sub*16;
    const u16* kb_ = K + ((long)b*SEQ_ + n0)*DIM_ + hh*DH_;
    const u16* vb_ = V + ((long)b*SEQ_ + n0)*DIM_ + hh*DH_;
    __syncthreads();
    #pragma unroll
    for (int i=0;i<4;i++){
      int e = t + i*256; int r = e>>6, d = e&63;
      ks_[r][d] = bf2f(kb_[(long)r*DIM_ + d]);
      vs_[r][d] = bf2f(vb_[(long)r*DIM_ + d]);
    }
    __syncthreads();
    if (t<16){
      float sq=0.f;
      #pragma unroll
      for (int d=0; d<64; d++){ float vv=ks_[t][d]; sq+=vv*vv; }
      diag_s[t]=0.5f*DN_*DN_*sq;
    }
    __syncthreads();
    #pragma unroll
    for (int r=0;r<16;r++){
      float a = 0.f;
      #pragma unroll
      for (int d4=0; d4<16; d4++){
        float4 kv = *(const float4*)&ks_[r][d4*4];
        a += kv.x*preg[4*d4] + kv.y*preg[4*d4+1] + kv.z*preg[4*d4+2] + kv.w*preg[4*d4+3];
      }
      float kp = RATIO_*(expf(a*DN_ - diag_s[r] - st) + EPSK_);
      aks += kp;
      #pragma unroll
      for (int d4=0; d4<16; d4++){
        float4 vv = *(const float4*)&vs_[r][d4*4];
        actx[4*d4]   += kp*vv.x;
        actx[4*d4+1] += kp*vv.y;
        actx[4*d4+2] += kp*vv.z;
        actx[4*d4+3] += kp*vv.w;
      }
    }
  }
  float* cp = ctxp + ((long)chunk*BH_ + z)*(MF_*DH_) + (long)t*DH_;
  #pragma unroll
  for (int d4=0; d4<16; d4++){
    float4 o; o.x=actx[4*d4]; o.y=actx[4*d4+1]; o.z=actx[4*d4+2]; o.w=actx[4*d4+3];
    *(float4*)&cp[4*d4] = o;
  }
  ksp[(z*8+chunk)*MF_ + t] = aks;
}

// reduce ctx partials -> ctxT bf16 [z][d][m]
__global__ void ctx_reduceT(const float* __restrict__ part, u16* __restrict__ ctxT){
  const long NT = (long)BH_*MF_*DH_; // 786432
  for (long i = (long)blockIdx.x*256 + threadIdx.x; i < NT; i += (long)gridDim.x*256){
    float s = 0.f;
    #pragma unroll
    for (int c=0;c<8;c++) s += part[(long)c*NT + i];
    int z = (int)(i >> 14);
    int r = (int)(i & 16383);
    int m = r >> 6, d = r & 63;
    ctxT[(long)z*(MF_*DH_) + (long)d*MF_ + m] = f2bf(s);
  }
}

__global__ void ksum_reduce(const float* __restrict__ part, float* __restrict__ ksum){
  int z = blockIdx.x; int t = threadIdx.x;
  float s = 0.f;
  #pragma unroll
  for (int c=0;c<8;c++) s += part[(z*8+c)*MF_ + t];
  ksum[z*MF_+t] = s;
}

// ---- Q features: qp bf16 [z][n][m] + dinv fp32 [z][n]; no PV here ----
__global__ __launch_bounds__(256) void qfeat_kernel(const u16* __restrict__ X,
        const float* __restrict__ proj, const float* __restrict__ ksum,
        u16* __restrict__ qp, float* __restrict__ dinv){
  int z = blockIdx.y; int b = z/HEADS_, hh = z - b*HEADS_;
  int n0 = blockIdx.x*16;
  int t = threadIdx.x;
  __shared__ float qs[16][64];
  __shared__ float diag_s[16];
  __shared__ float redm[16][4];
  __shared__ float redd[16][4];
  const u16* xb = X + ((long)b*SEQ_ + n0)*DIM_ + hh*DH_;
  #pragma unroll
  for (int i=0;i<4;i++){ int e=t+i*256; int r=e>>6, d=e&63; qs[r][d]=bf2f(xb[(long)r*DIM_+d]); }
  float preg[64];
  const float* pr = proj + t*DH_;
  #pragma unroll
  for (int d4=0; d4<16; d4++){
    float4 p4 = *(const float4*)&pr[d4*4];
    preg[4*d4]=p4.x; preg[4*d4+1]=p4.y; preg[4*d4+2]=p4.z; preg[4*d4+3]=p4.w;
  }
  __syncthreads();
  if (t<16){
    float sq=0.f;
    #pragma unroll
    for (int d=0; d<64; d++){ float vv=qs[t][d]; sq+=vv*vv; }
    diag_s[t]=0.5f*DN_*DN_*sq;
  }
  __syncthreads();
  float xd[16];
  #pragma unroll
  for (int r=0;r<16;r++){
    float a = 0.f;
    #pragma unroll
    for (int d4=0; d4<16; d4++){
      float4 qv = *(const float4*)&qs[r][d4*4];
      a += qv.x*preg[4*d4] + qv.y*preg[4*d4+1] + qv.z*preg[4*d4+2] + qv.w*preg[4*d4+3];
    }
    xd[r] = a*DN_;
  }
  int lane=t&63, wid=t>>6;
  #pragma unroll
  for (int r=0;r<16;r++){
    float m = xd[r];
    #pragma unroll
    for (int off=32; off; off>>=1) m = fmaxf(m, __shfl_xor(m,off));
    if (lane==0) redm[r][wid]=m;
  }
  __syncthreads();
  float ks = ksum[(long)z*MF_ + t];
  #pragma unroll
  for (int r=0;r<16;r++){
    float mx = fmaxf(fmaxf(redm[r][0],redm[r][1]),fmaxf(redm[r][2],redm[r][3]));
    float qpv = RATIO_*(expf(xd[r] - diag_s[r] - mx) + EPSK_);
    u16 qb16 = f2bf(qpv);
    qp[((long)z*SEQ_ + n0 + r)*MF_ + t] = qb16;
    float dv = bf2f(qb16)*ks;
    #pragma unroll
    for (int off=32; off; off>>=1) dv += __shfl_xor(dv,off);
    if (lane==0) redd[r][wid]=dv;
  }
  __syncthreads();
  if (t<16){
    float s = redd[t][0]+redd[t][1]+redd[t][2]+redd[t][3];
    dinv[(long)z*SEQ_ + n0 + t] = 1.0f/s;
  }
}

// ---------------- final LN(row0) + pooler + classifier ----------------
__global__ __launch_bounds__(256) void pooler_kernel(const float* __restrict__ h,
                           const float* __restrict__ g, const float* __restrict__ bta,
                           const float* __restrict__ Wp, const float* __restrict__ bp,
                           const float* __restrict__ Wc, const float* __restrict__ bc,
                           float* __restrict__ out){
  int b = blockIdx.x, t = threadIdx.x;
  __shared__ float xn[768];
  __shared__ float pl[768];
  __shared__ float red[8];
  const float* row = h + (long)b*SEQ_*DIM_;
  float v0=row[t], v1=row[t+256], v2=row[t+512];
  float s = v0+v1+v2, ss = v0*v0+v1*v1+v2*v2;
  int lane=t&63, wid=t>>6;
  #pragma unroll
  for (int off=32; off; off>>=1){ s += __shfl_xor(s,off); ss += __shfl_xor(ss,off); }
  if (lane==0){ red[wid]=s; red[4+wid]=ss; }
  __syncthreads();
  s  = red[0]+red[1]+red[2]+red[3];
  ss = red[4]+red[5]+red[6]+red[7];
  float mu = s*(1.0f/DIM_);
  float var = ss*(1.0f/DIM_) - mu*mu;
  float rs = rsqrtf(var + EPSLN_);
  xn[t]     = (v0-mu)*rs*g[t]     + bta[t];
  xn[t+256] = (v1-mu)*rs*g[t+256] + bta[t+256];
  xn[t+512] = (v2-mu)*rs*g[t+512] + bta[t+512];
  __syncthreads();
  #pragma unroll
  for (int jj=0;jj<3;jj++){
    int j = t + jj*256;
    float a = bp[j];
    for (int i=0;i<768;i++) a += xn[i]*Wp[(long)i*DIM_ + j];
    pl[j] = tanhf(a);
  }
  __syncthreads();
  if (wid < 2){
    float a = 0.f;
    for (int i=lane;i<768;i+=64) a += pl[i]*Wc[i*2+wid];
    #pragma unroll
    for (int off=32; off; off>>=1) a += __shfl_xor(a,off);
    if (lane==0) out[b*2+wid] = a + bc[wid];
  }
}

extern "C" void kernel_launch(void* const* d_in, const int* in_sizes, int n_in,
                              void* d_out, int out_size, void* d_ws, size_t ws_size,
                              hipStream_t stream) {
  (void)in_sizes; (void)n_in; (void)out_size; (void)ws_size;
  const int*   x    = (const int*)  d_in[0];
  const float* tok  = (const float*)d_in[1];
  const float* pos  = (const float*)d_in[2];
  const float* ln1g = (const float*)d_in[3];
  const float* ln1b = (const float*)d_in[4];
  const float* Wq   = (const float*)d_in[5];
  const float* Wk   = (const float*)d_in[6];
  const float* Wv   = (const float*)d_in[7];
  const float* Wo   = (const float*)d_in[8];
  const float* bo   = (const float*)d_in[9];
  const float* proj = (const float*)d_in[10];
  const float* ln2g = (const float*)d_in[11];
  const float* ln2b = (const float*)d_in[12];
  const float* W1   = (const float*)d_in[13];
  const float* b1   = (const float*)d_in[14];
  const float* W2   = (const float*)d_in[15];
  const float* b2   = (const float*)d_in[16];
  const float* lnfg = (const float*)d_in[17];
  const float* lnfb = (const float*)d_in[18];
  const float* Wp   = (const float*)d_in[19];
  const float* bp   = (const float*)d_in[20];
  const float* Wc   = (const float*)d_in[21];
  const float* bc   = (const float*)d_in[22];
  float* out = (float*)d_out;

  // ---- workspace layout (bytes), total ~136 MB ----
  char* wsb = (char*)d_ws;
  float* h     = (float*)(wsb + 0);                       // 25165824 B fp32
  u16*   ybf   = (u16*)  (wsb + 25165824);                // 12582912 B (also attn out)
  u16*   qbf   = (u16*)  (wsb + 37748736);
  u16*   kbf   = (u16*)  (wsb + 50331648);
  u16*   vbf   = (u16*)  (wsb + 62914560);
  u16*   ffnbf = (u16*)  (wsb + 75497472);                // 50331648 B
  u16*   qp    = (u16*)  (wsb + 75497472);                // alias (first half)
  float* ctxp  = (float*)(wsb + 75497472 + 25165824);     // alias (second half)
  u16*   wT    = (u16*)  (wsb + 125829120);               // 14155776 B
  u16*   ctxT  = (u16*)  (wsb + 139984896);               // 1572864 B
  float* ksp   = (float*)(wsb + 141557760);
  float* ksum  = (float*)(wsb + 141950976);
  float* kmaxp = (float*)(wsb + 142000128);
  float* stab  = (float*)(wsb + 142024704);
  float* dinv  = (float*)(wsb + 142024960);
  u16* attnbf  = ybf;

  u16* wtq = wT;
  u16* wtk = wT + 589824;
  u16* wtv = wT + 1179648;
  u16* wto = wT + 1769472;
  u16* wt1 = wT + 2359296;   // [3072][768]
  u16* wt2 = wT + 4718592;   // [768][3072]

  embed_kernel<<<2048,256,0,stream>>>(x,(const float4*)tok,(const float4*)pos,(float4*)h);

  dim3 gD(6, 64);               // N=768 MFMA GEMM
  dim3 gF(24, 64);              // N=3072
  dim3 gQ2(1, 16, BH_);         // PV batched
  dim3 gfeat(SEQ_/16, BH_);

  for (int l=0; l<DEPTH_; l++){
    const float* wq  = Wq + (size_t)l*DIM_*DIM_;
    const float* wk  = Wk + (size_t)l*DIM_*DIM_;
    const float* wv  = Wv + (size_t)l*DIM_*DIM_;
    const float* wo  = Wo + (size_t)l*DIM_*DIM_;
    const float* prj = proj + (size_t)l*MF_*DH_;
    const float* w1  = W1 + (size_t)l*DIM_*FF_;
    const float* w2  = W2 + (size_t)l*FF_*DIM_;

    tconv_kernel<<<dim3(24,24),256,0,stream>>>(wq, wtq, 768, 768);
    tconv_kernel<<<dim3(24,24),256,0,stream>>>(wk, wtk, 768, 768);
    tconv_kernel<<<dim3(24,24),256,0,stream>>>(wv, wtv, 768, 768);
    tconv_kernel<<<dim3(24,24),256,0,stream>>>(wo, wto, 768, 768);
    tconv_kernel<<<dim3(96,24),256,0,stream>>>(w1, wt1, 768, 3072);
    tconv_kernel<<<dim3(24,96),256,0,stream>>>(w2, wt2, 3072, 768);

    ln_kernel<<<ROWS_,256,0,stream>>>(h, ln1g+(size_t)l*DIM_, ln1b+(size_t)l*DIM_, ybf);
    mgemm<4,4,2,2,0,0,0><<<gD,256,0,stream>>>(ybf, wtq, nullptr, qbf, nullptr, ROWS_, 768, 768, 768);
    mgemm<4,4,2,2,0,0,0><<<gD,256,0,stream>>>(ybf, wtk, nullptr, kbf, nullptr, ROWS_, 768, 768, 768);
    mgemm<4,4,2,2,0,0,0><<<gD,256,0,stream>>>(ybf, wtv, nullptr, vbf, nullptr, ROWS_, 768, 768, 768);

    kmax_kernel<<<gfeat,256,0,stream>>>(kbf, prj, kmaxp);
    kmax_reduce<<<BH_,64,0,stream>>>(kmaxp, stab);
    kctx_kernel<<<dim3(8,BH_),256,0,stream>>>(kbf, vbf, prj, stab, ctxp, ksp);
    ctx_reduceT<<<768,256,0,stream>>>(ctxp, ctxT);
    ksum_reduce<<<BH_,256,0,stream>>>(ksp, ksum);

    qfeat_kernel<<<gfeat,256,0,stream>>>(qbf, prj, ksum, qp, dinv);
    mgemm<2,4,4,1,0,2,1><<<gQ2,256,0,stream>>>(qp, ctxT, nullptr, attnbf, dinv, SEQ_, 64, 256, 768);

    mgemm<4,4,2,2,0,1,0><<<gD,256,0,stream>>>(attnbf, wto, bo+(size_t)l*DIM_, h, nullptr, ROWS_, 768, 768, 768);

    ln_kernel<<<ROWS_,256,0,stream>>>(h, ln2g+(size_t)l*DIM_, ln2b+(size_t)l*DIM_, ybf);
    mgemm<4,4,2,2,1,0,0><<<gF,256,0,stream>>>(ybf, wt1, b1+(size_t)l*FF_, ffnbf, nullptr, ROWS_, 3072, 768, 3072);
    mgemm<4,4,2,2,0,1,0><<<gD,256,0,stream>>>(ffnbf, wt2, b2+(size_t)l*DIM_, h, nullptr, ROWS_, 768, 3072, 768);
  }

  pooler_kernel<<<B_,256,0,stream>>>(h, lnfg, lnfb, Wp, bp, Wc, bc, out);
}

// Round 4
// 6069.005 us; speedup vs baseline: 4.2331x; 2.4837x over previous
//
#include <hip/hip_runtime.h>
#include <hip/hip_bf16.h>
#include <math.h>

#define B_ 4
#define SEQ_ 2048
#define DIM_ 768
#define DEPTH_ 6
#define HEADS_ 12
#define DH_ 64
#define MF_ 256
#define FF_ 3072
#define ROWS_ 8192
#define BH_ 48
#define DN_ 0.3535533905932738f   /* 64^-0.25 */
#define RATIO_ 0.0625f            /* 256^-0.5 */
#define EPSK_ 1e-4f
#define EPSLN_ 1e-5f

typedef unsigned short u16;
typedef unsigned int   u32;
typedef __bf16 bf16x8 __attribute__((ext_vector_type(8)));
typedef float  f32x4  __attribute__((ext_vector_type(4)));

__device__ inline u16 f2bf(float x){
  u32 u = __builtin_bit_cast(u32, x);
  return (u16)((u + 0x7FFFu + ((u>>16)&1u)) >> 16);
}
__device__ inline float bf2f(u16 v){ return __builtin_bit_cast(float, (u32)v<<16); }

__device__ inline void gload16(const u16* g, u16* lds){
  __builtin_amdgcn_global_load_lds(
    (const __attribute__((address_space(1))) u32*)(const void*)g,
    (__attribute__((address_space(3))) u32*)(void*)lds, 16, 0, 0);
}

// ---------------- embedding (h fp32) ----------------
__global__ void embed_kernel(const int* __restrict__ x, const float4* __restrict__ tok,
                             const float4* __restrict__ pos, float4* __restrict__ h){
  const int C4 = DIM_/4;
  long total = (long)ROWS_*C4;
  for (long i = (long)blockIdx.x*blockDim.x + threadIdx.x; i < total;
       i += (long)gridDim.x*blockDim.x){
    int row = (int)(i / C4); int c = (int)(i - (long)row*C4);
    int n = row & (SEQ_-1);
    float4 a = tok[(long)x[row]*C4 + c];
    float4 p = pos[(long)n*C4 + c];
    float4 o; o.x=a.x+p.x; o.y=a.y+p.y; o.z=a.z+p.z; o.w=a.w+p.w;
    h[i] = o;
  }
}

// ---------------- layernorm fp32 -> bf16 ----------------
__global__ __launch_bounds__(256) void ln_kernel(const float* __restrict__ X,
                          const float* __restrict__ g, const float* __restrict__ bta,
                          u16* __restrict__ Y){
  int row = blockIdx.x; int t = threadIdx.x;
  const float* xr = X + (long)row*DIM_;
  float v0 = xr[t], v1 = xr[t+256], v2 = xr[t+512];
  float s = v0+v1+v2;
  float ss = v0*v0+v1*v1+v2*v2;
  int lane = t&63, wid = t>>6;
  #pragma unroll
  for (int off=32; off; off>>=1){ s += __shfl_xor(s,off); ss += __shfl_xor(ss,off); }
  __shared__ float red[8];
  if (lane==0){ red[wid]=s; red[4+wid]=ss; }
  __syncthreads();
  s  = red[0]+red[1]+red[2]+red[3];
  ss = red[4]+red[5]+red[6]+red[7];
  float mu  = s*(1.0f/DIM_);
  float var = ss*(1.0f/DIM_) - mu*mu;
  float rs  = rsqrtf(var + EPSLN_);
  u16* yr = Y + (long)row*DIM_;
  yr[t]     = f2bf((v0-mu)*rs*g[t]     + bta[t]);
  yr[t+256] = f2bf((v1-mu)*rs*g[t+256] + bta[t+256]);
  yr[t+512] = f2bf((v2-mu)*rs*g[t+512] + bta[t+512]);
}

// ---------------- transpose + convert: WT[n][k] = bf16(W[k][n]) ----------------
__global__ __launch_bounds__(256) void tconv_kernel(const float* __restrict__ W,
        u16* __restrict__ WT, int K, int N){
  __shared__ float tile[32][33];
  int n0 = blockIdx.x*32, k0 = blockIdx.y*32;
  int tx = threadIdx.x & 31, ty = threadIdx.x >> 5;
  #pragma unroll
  for (int i=0;i<32;i+=8) tile[ty+i][tx] = W[(long)(k0+ty+i)*N + n0+tx];
  __syncthreads();
  #pragma unroll
  for (int i=0;i<32;i+=8) WT[(long)(n0+ty+i)*K + k0+tx] = f2bf(tile[tx][ty+i]);
}

// ---------------- MFMA GEMM: C = f(A[M,K]bf16 @ BT[N,K]^T bf16 + bias) ----------------
// 256 thr = 4 waves (WM x WN), wave tile (FM*16) x (FN*16). BK=32.
// CMODE: 0 = bf16 store (+bias,+gelu if ACT); 1 = fp32 C += (+bias); 2 = bf16 store * scale[row]
template<int FM, int FN, int WM, int WN, int ACT, int CMODE, int BATCH>
__global__ __launch_bounds__(256) void mgemm(const u16* __restrict__ A,
     const u16* __restrict__ BT, const float* __restrict__ bias,
     void* __restrict__ Cv, const float* __restrict__ scale,
     int M, int N, int K, int ldC){
  (void)M;
  constexpr int BM = WM*FM*16, BN = WN*FN*16;
  constexpr int ACH = BM/16, BCH = BN/16;   // 1KB staging chunks (16 rows x 64B)
  __shared__ u16 As[BM*32];
  __shared__ u16 Bs[BN*32];
  int tid = threadIdx.x; int w = tid>>6, l = tid&63;
  int m0 = blockIdx.y*BM, n0 = blockIdx.x*BN;
  long coff = 0, srow0 = 0;
  if (BATCH){
    int z = blockIdx.z;
    A  += (long)z*2048*K;
    BT += (long)z*(long)N*K;
    coff  = (long)(z/HEADS_)*SEQ_*(long)ldC + (long)(z%HEADS_)*64;
    srow0 = (long)z*SEQ_;
  }
  f32x4 acc[FM][FN];
  #pragma unroll
  for (int i=0;i<FM;i++)
    #pragma unroll
    for (int j=0;j<FN;j++) acc[i][j] = (f32x4){0.f,0.f,0.f,0.f};

  const int row_l = l>>2, cq_l = l&3;
  const int wm = w / WN, wn = w % WN;
  const int kq = l>>4, rl15 = l&15;

  for (int k0=0; k0<K; k0+=32){
    __syncthreads();
    for (int c = w; c < ACH; c += 4){
      int r = c*16 + row_l;
      int gq = cq_l ^ ((r>>1)&3);
      gload16(A + (long)(m0+r)*K + k0 + gq*8, As + c*512);
    }
    for (int c = w; c < BCH; c += 4){
      int r = c*16 + row_l;
      int gq = cq_l ^ ((r>>1)&3);
      gload16(BT + (long)(n0+r)*K + k0 + gq*8, Bs + c*512);
    }
    __syncthreads();
    bf16x8 af[FM], bfr[FN];
    #pragma unroll
    for (int mi=0; mi<FM; mi++){
      int rr = (wm*FM + mi)*16 + rl15;
      int g = kq ^ ((rr>>1)&3);
      af[mi] = *(const bf16x8*)(As + rr*32 + g*8);
    }
    #pragma unroll
    for (int ni=0; ni<FN; ni++){
      int rr = (wn*FN + ni)*16 + rl15;
      int g = kq ^ ((rr>>1)&3);
      bfr[ni] = *(const bf16x8*)(Bs + rr*32 + g*8);
    }
    #pragma unroll
    for (int mi=0; mi<FM; mi++)
      #pragma unroll
      for (int ni=0; ni<FN; ni++)
        acc[mi][ni] = __builtin_amdgcn_mfma_f32_16x16x32_bf16(af[mi], bfr[ni], acc[mi][ni], 0, 0, 0);
  }

  int cc = l&15, rq = l>>4;
  #pragma unroll
  for (int mi=0; mi<FM; mi++){
    #pragma unroll
    for (int ni=0; ni<FN; ni++){
      int gcol = n0 + (wn*FN+ni)*16 + cc;
      float bv = bias ? bias[gcol] : 0.f;
      #pragma unroll
      for (int r4=0; r4<4; r4++){
        int grow = m0 + (wm*FM+mi)*16 + rq*4 + r4;
        float v = acc[mi][ni][r4] + bv;
        if (ACT) v = 0.5f*v*(1.0f + erff(v*0.70710678118654752f));
        if (CMODE==1){
          float* C = (float*)Cv;
          C[(long)grow*ldC + gcol] += v;
        } else if (CMODE==2){
          v *= scale[srow0 + grow];
          ((u16*)Cv)[coff + (long)grow*ldC + gcol] = f2bf(v);
        } else {
          ((u16*)Cv)[(long)grow*ldC + gcol] = f2bf(v);
        }
      }
    }
  }
}

// ---------------- K pass 1: global max of xd per (b,h) (bf16 K input) ----------------
__global__ __launch_bounds__(256) void kmax_kernel(const u16* __restrict__ X,
                        const float* __restrict__ proj, float* __restrict__ kmaxp){
  int z = blockIdx.y; int b = z/HEADS_, hh = z - b*HEADS_;
  int n0 = blockIdx.x*16;
  int t = threadIdx.x;
  __shared__ float qs[16][64];
  __shared__ float bmax_s[4];
  const u16* xb = X + ((long)b*SEQ_ + n0)*DIM_ + hh*DH_;
  #pragma unroll
  for (int i=0;i<4;i++){ int e=t+i*256; int r=e>>6, d=e&63; qs[r][d]=bf2f(xb[(long)r*DIM_+d]); }
  float preg[64];
  const float* pr = proj + t*DH_;
  #pragma unroll
  for (int d4=0; d4<16; d4++){
    float4 p4 = *(const float4*)&pr[d4*4];
    preg[4*d4]=p4.x; preg[4*d4+1]=p4.y; preg[4*d4+2]=p4.z; preg[4*d4+3]=p4.w;
  }
  __syncthreads();
  float bm = -1e30f;
  #pragma unroll 4
  for (int r=0;r<16;r++){
    float a = 0.f;
    #pragma unroll
    for (int d4=0; d4<16; d4++){
      float4 qv = *(const float4*)&qs[r][d4*4];
      a += qv.x*preg[4*d4] + qv.y*preg[4*d4+1] + qv.z*preg[4*d4+2] + qv.w*preg[4*d4+3];
    }
    bm = fmaxf(bm, a*DN_);
  }
  int lane=t&63, wid=t>>6;
  #pragma unroll
  for (int off=32; off; off>>=1) bm = fmaxf(bm, __shfl_xor(bm,off));
  if (lane==0) bmax_s[wid]=bm;
  __syncthreads();
  if (t==0)
    kmaxp[z*128 + blockIdx.x] = fmaxf(fmaxf(bmax_s[0],bmax_s[1]),fmaxf(bmax_s[2],bmax_s[3]));
}

__global__ void kmax_reduce(const float* __restrict__ part, float* __restrict__ stab){
  int z = blockIdx.x; int t = threadIdx.x; // 64
  float m = fmaxf(part[z*128+t], part[z*128+64+t]);
  #pragma unroll
  for (int off=32; off; off>>=1) m = fmaxf(m, __shfl_xor(m,off));
  if (t==0) stab[z] = m;
}

// -- K pass 2: kp on the fly; ctx partials + ksum partials (bf16 K/V inputs) --
__global__ __launch_bounds__(256) void kctx_kernel(const u16* __restrict__ K,
                        const u16* __restrict__ V, const float* __restrict__ proj,
                        const float* __restrict__ stab, float* __restrict__ ctxp,
                        float* __restrict__ ksp){
  int chunk = blockIdx.x; int z = blockIdx.y;
  int b = z/HEADS_, hh = z - b*HEADS_;
  int t = threadIdx.x;
  __shared__ float ks_[16][64];
  __shared__ float vs_[16][64];
  __shared__ float diag_s[16];
  float preg[64];
  const float* pr = proj + t*DH_;
  #pragma unroll
  for (int d4=0; d4<16; d4++){
    float4 p4 = *(const float4*)&pr[d4*4];
    preg[4*d4]=p4.x; preg[4*d4+1]=p4.y; preg[4*d4+2]=p4.z; preg[4*d4+3]=p4.w;
  }
  float st = stab[z];
  float actx[64];
  #pragma unroll
  for (int d=0; d<64; d++) actx[d]=0.f;
  float aks = 0.f;
  int nbase = chunk*256;
  for (int sub=0; sub<16; sub++){
    int n0 = nbase + sub*16;
    const u16* kb_ = K + ((long)b*SEQ_ + n0)*DIM_ + hh*DH_;
    const u16* vb_ = V + ((long)b*SEQ_ + n0)*DIM_ + hh*DH_;
    __syncthreads();
    #pragma unroll
    for (int i=0;i<4;i++){
      int e = t + i*256; int r = e>>6, d = e&63;
      ks_[r][d] = bf2f(kb_[(long)r*DIM_ + d]);
      vs_[r][d] = bf2f(vb_[(long)r*DIM_ + d]);
    }
    __syncthreads();
    if (t<16){
      float sq=0.f;
      #pragma unroll
      for (int d=0; d<64; d++){ float vv=ks_[t][d]; sq+=vv*vv; }
      diag_s[t]=0.5f*DN_*DN_*sq;
    }
    __syncthreads();
    #pragma unroll 4
    for (int r=0;r<16;r++){
      float a = 0.f;
      #pragma unroll
      for (int d4=0; d4<16; d4++){
        float4 kv = *(const float4*)&ks_[r][d4*4];
        a += kv.x*preg[4*d4] + kv.y*preg[4*d4+1] + kv.z*preg[4*d4+2] + kv.w*preg[4*d4+3];
      }
      float kp = RATIO_*(expf(a*DN_ - diag_s[r] - st) + EPSK_);
      aks += kp;
      #pragma unroll
      for (int d4=0; d4<16; d4++){
        float4 vv = *(const float4*)&vs_[r][d4*4];
        actx[4*d4]   += kp*vv.x;
        actx[4*d4+1] += kp*vv.y;
        actx[4*d4+2] += kp*vv.z;
        actx[4*d4+3] += kp*vv.w;
      }
    }
  }
  float* cp = ctxp + ((long)chunk*BH_ + z)*(MF_*DH_) + (long)t*DH_;
  #pragma unroll
  for (int d4=0; d4<16; d4++){
    float4 o; o.x=actx[4*d4]; o.y=actx[4*d4+1]; o.z=actx[4*d4+2]; o.w=actx[4*d4+3];
    *(float4*)&cp[4*d4] = o;
  }
  ksp[(z*8+chunk)*MF_ + t] = aks;
}

// reduce ctx partials -> ctxT bf16 [z][d][m]
__global__ void ctx_reduceT(const float* __restrict__ part, u16* __restrict__ ctxT){
  const long NT = (long)BH_*MF_*DH_; // 786432
  for (long i = (long)blockIdx.x*256 + threadIdx.x; i < NT; i += (long)gridDim.x*256){
    float s = 0.f;
    #pragma unroll
    for (int c=0;c<8;c++) s += part[(long)c*NT + i];
    int z = (int)(i >> 14);
    int r = (int)(i & 16383);
    int m = r >> 6, d = r & 63;
    ctxT[(long)z*(MF_*DH_) + (long)d*MF_ + m] = f2bf(s);
  }
}

__global__ void ksum_reduce(const float* __restrict__ part, float* __restrict__ ksum){
  int z = blockIdx.x; int t = threadIdx.x;
  float s = 0.f;
  #pragma unroll
  for (int c=0;c<8;c++) s += part[(z*8+c)*MF_ + t];
  ksum[z*MF_+t] = s;
}

// ---- Q features: qp bf16 [z][n][m] + dinv fp32 [z][n] ----
// Two phases split by an LDS staging tile so preg[64] is dead before the
// shuffle-reduction chains (kills the 256-VGPR spill seen in r2/r3).
__global__ __launch_bounds__(256) void qfeat_kernel(const u16* __restrict__ X,
        const float* __restrict__ proj, const float* __restrict__ ksum,
        u16* __restrict__ qp, float* __restrict__ dinv){
  int z = blockIdx.y; int b = z/HEADS_, hh = z - b*HEADS_;
  int n0 = blockIdx.x*16;
  int t = threadIdx.x;
  __shared__ float qs[16][64];
  __shared__ float diag_s[16];
  __shared__ float xd_s[16][256];
  __shared__ float redm[16][4];
  __shared__ float redd[16][4];
  const u16* xb = X + ((long)b*SEQ_ + n0)*DIM_ + hh*DH_;
  #pragma unroll
  for (int i=0;i<4;i++){ int e=t+i*256; int r=e>>6, d=e&63; qs[r][d]=bf2f(xb[(long)r*DIM_+d]); }
  {
    float preg[64];
    const float* pr = proj + t*DH_;
    #pragma unroll
    for (int d4=0; d4<16; d4++){
      float4 p4 = *(const float4*)&pr[d4*4];
      preg[4*d4]=p4.x; preg[4*d4+1]=p4.y; preg[4*d4+2]=p4.z; preg[4*d4+3]=p4.w;
    }
    __syncthreads();
    if (t<16){
      float sq=0.f;
      #pragma unroll
      for (int d=0; d<64; d++){ float vv=qs[t][d]; sq+=vv*vv; }
      diag_s[t]=0.5f*DN_*DN_*sq;
    }
    // phase 1: features -> LDS immediately (no xd[] register array)
    #pragma unroll 4
    for (int r=0;r<16;r++){
      float a = 0.f;
      #pragma unroll
      for (int d4=0; d4<16; d4++){
        float4 qv = *(const float4*)&qs[r][d4*4];
        a += qv.x*preg[4*d4] + qv.y*preg[4*d4+1] + qv.z*preg[4*d4+2] + qv.w*preg[4*d4+3];
      }
      xd_s[r][t] = a*DN_;
    }
  }
  __syncthreads();
  // phase 2: light-register reductions from LDS
  int lane=t&63, wid=t>>6;
  #pragma unroll
  for (int r=0;r<16;r++){
    float m = xd_s[r][t];
    #pragma unroll
    for (int off=32; off; off>>=1) m = fmaxf(m, __shfl_xor(m,off));
    if (lane==0) redm[r][wid]=m;
  }
  __syncthreads();
  float ks = ksum[(long)z*MF_ + t];
  #pragma unroll
  for (int r=0;r<16;r++){
    float mx = fmaxf(fmaxf(redm[r][0],redm[r][1]),fmaxf(redm[r][2],redm[r][3]));
    float qpv = RATIO_*(expf(xd_s[r][t] - diag_s[r] - mx) + EPSK_);
    u16 qb16 = f2bf(qpv);
    qp[((long)z*SEQ_ + n0 + r)*MF_ + t] = qb16;
    float dv = bf2f(qb16)*ks;
    #pragma unroll
    for (int off=32; off; off>>=1) dv += __shfl_xor(dv,off);
    if (lane==0) redd[r][wid]=dv;
  }
  __syncthreads();
  if (t<16){
    float s = redd[t][0]+redd[t][1]+redd[t][2]+redd[t][3];
    dinv[(long)z*SEQ_ + n0 + t] = 1.0f/s;
  }
}

// ---------------- final LN(row0) + pooler + classifier ----------------
__global__ __launch_bounds__(256) void pooler_kernel(const float* __restrict__ h,
                           const float* __restrict__ g, const float* __restrict__ bta,
                           const float* __restrict__ Wp, const float* __restrict__ bp,
                           const float* __restrict__ Wc, const float* __restrict__ bc,
                           float* __restrict__ out){
  int b = blockIdx.x, t = threadIdx.x;
  __shared__ float xn[768];
  __shared__ float pl[768];
  __shared__ float red[8];
  const float* row = h + (long)b*SEQ_*DIM_;
  float v0=row[t], v1=row[t+256], v2=row[t+512];
  float s = v0+v1+v2, ss = v0*v0+v1*v1+v2*v2;
  int lane=t&63, wid=t>>6;
  #pragma unroll
  for (int off=32; off; off>>=1){ s += __shfl_xor(s,off); ss += __shfl_xor(ss,off); }
  if (lane==0){ red[wid]=s; red[4+wid]=ss; }
  __syncthreads();
  s  = red[0]+red[1]+red[2]+red[3];
  ss = red[4]+red[5]+red[6]+red[7];
  float mu = s*(1.0f/DIM_);
  float var = ss*(1.0f/DIM_) - mu*mu;
  float rs = rsqrtf(var + EPSLN_);
  xn[t]     = (v0-mu)*rs*g[t]     + bta[t];
  xn[t+256] = (v1-mu)*rs*g[t+256] + bta[t+256];
  xn[t+512] = (v2-mu)*rs*g[t+512] + bta[t+512];
  __syncthreads();
  #pragma unroll
  for (int jj=0;jj<3;jj++){
    int j = t + jj*256;
    float a = bp[j];
    for (int i=0;i<768;i++) a += xn[i]*Wp[(long)i*DIM_ + j];
    pl[j] = tanhf(a);
  }
  __syncthreads();
  if (wid < 2){
    float a = 0.f;
    for (int i=lane;i<768;i+=64) a += pl[i]*Wc[i*2+wid];
    #pragma unroll
    for (int off=32; off; off>>=1) a += __shfl_xor(a,off);
    if (lane==0) out[b*2+wid] = a + bc[wid];
  }
}

extern "C" void kernel_launch(void* const* d_in, const int* in_sizes, int n_in,
                              void* d_out, int out_size, void* d_ws, size_t ws_size,
                              hipStream_t stream) {
  (void)in_sizes; (void)n_in; (void)out_size; (void)ws_size;
  const int*   x    = (const int*)  d_in[0];
  const float* tok  = (const float*)d_in[1];
  const float* pos  = (const float*)d_in[2];
  const float* ln1g = (const float*)d_in[3];
  const float* ln1b = (const float*)d_in[4];
  const float* Wq   = (const float*)d_in[5];
  const float* Wk   = (const float*)d_in[6];
  const float* Wv   = (const float*)d_in[7];
  const float* Wo   = (const float*)d_in[8];
  const float* bo   = (const float*)d_in[9];
  const float* proj = (const float*)d_in[10];
  const float* ln2g = (const float*)d_in[11];
  const float* ln2b = (const float*)d_in[12];
  const float* W1   = (const float*)d_in[13];
  const float* b1   = (const float*)d_in[14];
  const float* W2   = (const float*)d_in[15];
  const float* b2   = (const float*)d_in[16];
  const float* lnfg = (const float*)d_in[17];
  const float* lnfb = (const float*)d_in[18];
  const float* Wp   = (const float*)d_in[19];
  const float* bp   = (const float*)d_in[20];
  const float* Wc   = (const float*)d_in[21];
  const float* bc   = (const float*)d_in[22];
  float* out = (float*)d_out;

  // ---- workspace layout (bytes), total ~136 MB ----
  char* wsb = (char*)d_ws;
  float* h     = (float*)(wsb + 0);                       // 25165824 B fp32
  u16*   ybf   = (u16*)  (wsb + 25165824);                // 12582912 B (also attn out)
  u16*   qbf   = (u16*)  (wsb + 37748736);
  u16*   kbf   = (u16*)  (wsb + 50331648);
  u16*   vbf   = (u16*)  (wsb + 62914560);
  u16*   ffnbf = (u16*)  (wsb + 75497472);                // 50331648 B
  u16*   qp    = (u16*)  (wsb + 75497472);                // alias (first half)
  float* ctxp  = (float*)(wsb + 75497472 + 25165824);     // alias (second half)
  u16*   wT    = (u16*)  (wsb + 125829120);               // 14155776 B
  u16*   ctxT  = (u16*)  (wsb + 139984896);               // 1572864 B
  float* ksp   = (float*)(wsb + 141557760);
  float* ksum  = (float*)(wsb + 141950976);
  float* kmaxp = (float*)(wsb + 142000128);
  float* stab  = (float*)(wsb + 142024704);
  float* dinv  = (float*)(wsb + 142024960);
  u16* attnbf  = ybf;

  u16* wtq = wT;
  u16* wtk = wT + 589824;
  u16* wtv = wT + 1179648;
  u16* wto = wT + 1769472;
  u16* wt1 = wT + 2359296;   // [3072][768]
  u16* wt2 = wT + 4718592;   // [768][3072]

  embed_kernel<<<2048,256,0,stream>>>(x,(const float4*)tok,(const float4*)pos,(float4*)h);

  dim3 gD(6, 64);               // N=768 MFMA GEMM
  dim3 gF(24, 64);              // N=3072
  dim3 gQ2(1, 16, BH_);         // PV batched
  dim3 gfeat(SEQ_/16, BH_);

  for (int l=0; l<DEPTH_; l++){
    const float* wq  = Wq + (size_t)l*DIM_*DIM_;
    const float* wk  = Wk + (size_t)l*DIM_*DIM_;
    const float* wv  = Wv + (size_t)l*DIM_*DIM_;
    const float* wo  = Wo + (size_t)l*DIM_*DIM_;
    const float* prj = proj + (size_t)l*MF_*DH_;
    const float* w1  = W1 + (size_t)l*DIM_*FF_;
    const float* w2  = W2 + (size_t)l*FF_*DIM_;

    tconv_kernel<<<dim3(24,24),256,0,stream>>>(wq, wtq, 768, 768);
    tconv_kernel<<<dim3(24,24),256,0,stream>>>(wk, wtk, 768, 768);
    tconv_kernel<<<dim3(24,24),256,0,stream>>>(wv, wtv, 768, 768);
    tconv_kernel<<<dim3(24,24),256,0,stream>>>(wo, wto, 768, 768);
    tconv_kernel<<<dim3(96,24),256,0,stream>>>(w1, wt1, 768, 3072);
    tconv_kernel<<<dim3(24,96),256,0,stream>>>(w2, wt2, 3072, 768);

    ln_kernel<<<ROWS_,256,0,stream>>>(h, ln1g+(size_t)l*DIM_, ln1b+(size_t)l*DIM_, ybf);
    mgemm<4,4,2,2,0,0,0><<<gD,256,0,stream>>>(ybf, wtq, nullptr, qbf, nullptr, ROWS_, 768, 768, 768);
    mgemm<4,4,2,2,0,0,0><<<gD,256,0,stream>>>(ybf, wtk, nullptr, kbf, nullptr, ROWS_, 768, 768, 768);
    mgemm<4,4,2,2,0,0,0><<<gD,256,0,stream>>>(ybf, wtv, nullptr, vbf, nullptr, ROWS_, 768, 768, 768);

    kmax_kernel<<<gfeat,256,0,stream>>>(kbf, prj, kmaxp);
    kmax_reduce<<<BH_,64,0,stream>>>(kmaxp, stab);
    kctx_kernel<<<dim3(8,BH_),256,0,stream>>>(kbf, vbf, prj, stab, ctxp, ksp);
    ctx_reduceT<<<768,256,0,stream>>>(ctxp, ctxT);
    ksum_reduce<<<BH_,256,0,stream>>>(ksp, ksum);

    qfeat_kernel<<<gfeat,256,0,stream>>>(qbf, prj, ksum, qp, dinv);
    mgemm<2,4,4,1,0,2,1><<<gQ2,256,0,stream>>>(qp, ctxT, nullptr, attnbf, dinv, SEQ_, 64, 256, 768);

    mgemm<4,4,2,2,0,1,0><<<gD,256,0,stream>>>(attnbf, wto, bo+(size_t)l*DIM_, h, nullptr, ROWS_, 768, 768, 768);

    ln_kernel<<<ROWS_,256,0,stream>>>(h, ln2g+(size_t)l*DIM_, ln2b+(size_t)l*DIM_, ybf);
    mgemm<4,4,2,2,1,0,0><<<gF,256,0,stream>>>(ybf, wt1, b1+(size_t)l*FF_, ffnbf, nullptr, ROWS_, 3072, 768, 3072);
    mgemm<4,4,2,2,0,1,0><<<gD,256,0,stream>>>(ffnbf, wt2, b2+(size_t)l*DIM_, h, nullptr, ROWS_, 768, 3072, 768);
  }

  pooler_kernel<<<B_,256,0,stream>>>(h, lnfg, lnfb, Wp, bp, Wc, bc, out);
}

// Round 5
// 5259.475 us; speedup vs baseline: 4.8847x; 1.1539x over previous
//
#include <hip/hip_runtime.h>
#include <hip/hip_bf16.h>
#include <math.h>

#define B_ 4
#define SEQ_ 2048
#define DIM_ 768
#define DEPTH_ 6
#define HEADS_ 12
#define DH_ 64
#define MF_ 256
#define FF_ 3072
#define ROWS_ 8192
#define BH_ 48
#define QKVW_ 2304
#define DN_ 0.3535533905932738f   /* 64^-0.25 */
#define RATIO_ 0.0625f            /* 256^-0.5 */
#define EPSK_ 1e-4f
#define EPSLN_ 1e-5f
#define NCH_ 16                   /* kctx n-chunks */

typedef unsigned short u16;
typedef unsigned int   u32;
typedef __bf16 bf16x8 __attribute__((ext_vector_type(8)));
typedef float  f32x4  __attribute__((ext_vector_type(4)));

__device__ inline u16 f2bf(float x){
  u32 u = __builtin_bit_cast(u32, x);
  return (u16)((u + 0x7FFFu + ((u>>16)&1u)) >> 16);
}
__device__ inline float bf2f(u16 v){ return __builtin_bit_cast(float, (u32)v<<16); }

__device__ inline void gload16(const u16* g, u16* lds){
  __builtin_amdgcn_global_load_lds(
    (const __attribute__((address_space(1))) u32*)(const void*)g,
    (__attribute__((address_space(3))) u32*)(void*)lds, 16, 0, 0);
}

// ---------------- embedding (h fp32) ----------------
__global__ void embed_kernel(const int* __restrict__ x, const float4* __restrict__ tok,
                             const float4* __restrict__ pos, float4* __restrict__ h){
  const int C4 = DIM_/4;
  long total = (long)ROWS_*C4;
  for (long i = (long)blockIdx.x*blockDim.x + threadIdx.x; i < total;
       i += (long)gridDim.x*blockDim.x){
    int row = (int)(i / C4); int c = (int)(i - (long)row*C4);
    int n = row & (SEQ_-1);
    float4 a = tok[(long)x[row]*C4 + c];
    float4 p = pos[(long)n*C4 + c];
    float4 o; o.x=a.x+p.x; o.y=a.y+p.y; o.z=a.z+p.z; o.w=a.w+p.w;
    h[i] = o;
  }
}

// ---------------- layernorm fp32 -> bf16 ----------------
__global__ __launch_bounds__(256) void ln_kernel(const float* __restrict__ X,
                          const float* __restrict__ g, const float* __restrict__ bta,
                          u16* __restrict__ Y){
  int row = blockIdx.x; int t = threadIdx.x;
  const float* xr = X + (long)row*DIM_;
  float v0 = xr[t], v1 = xr[t+256], v2 = xr[t+512];
  float s = v0+v1+v2;
  float ss = v0*v0+v1*v1+v2*v2;
  int lane = t&63, wid = t>>6;
  #pragma unroll
  for (int off=32; off; off>>=1){ s += __shfl_xor(s,off); ss += __shfl_xor(ss,off); }
  __shared__ float red[8];
  if (lane==0){ red[wid]=s; red[4+wid]=ss; }
  __syncthreads();
  s  = red[0]+red[1]+red[2]+red[3];
  ss = red[4]+red[5]+red[6]+red[7];
  float mu  = s*(1.0f/DIM_);
  float var = ss*(1.0f/DIM_) - mu*mu;
  float rs  = rsqrtf(var + EPSLN_);
  u16* yr = Y + (long)row*DIM_;
  yr[t]     = f2bf((v0-mu)*rs*g[t]     + bta[t]);
  yr[t+256] = f2bf((v1-mu)*rs*g[t+256] + bta[t+256]);
  yr[t+512] = f2bf((v2-mu)*rs*g[t+512] + bta[t+512]);
}

// ---------------- transpose + convert: WT[n][k] = bf16(W[k][n]) ----------------
__global__ __launch_bounds__(256) void tconv_kernel(const float* __restrict__ W,
        u16* __restrict__ WT, int K, int N){
  __shared__ float tile[32][33];
  int n0 = blockIdx.x*32, k0 = blockIdx.y*32;
  int tx = threadIdx.x & 31, ty = threadIdx.x >> 5;
  #pragma unroll
  for (int i=0;i<32;i+=8) tile[ty+i][tx] = W[(long)(k0+ty+i)*N + n0+tx];
  __syncthreads();
  #pragma unroll
  for (int i=0;i<32;i+=8) WT[(long)(n0+ty+i)*K + k0+tx] = f2bf(tile[tx][ty+i]);
}

// ---------------- MFMA GEMM: C = f(A[M,K]bf16 @ BT[N,K]^T bf16 + bias) ----------------
// CMODE: 0 = bf16 store (+bias,+gelu if ACT); 1 = fp32 C += (+bias); 2 = bf16 store * scale[row]
template<int FM, int FN, int WM, int WN, int ACT, int CMODE, int BATCH>
__global__ __launch_bounds__(256) void mgemm(const u16* __restrict__ A,
     const u16* __restrict__ BT, const float* __restrict__ bias,
     void* __restrict__ Cv, const float* __restrict__ scale,
     int M, int N, int K, int ldC){
  (void)M;
  constexpr int BM = WM*FM*16, BN = WN*FN*16;
  constexpr int ACH = BM/16, BCH = BN/16;
  __shared__ u16 As[BM*32];
  __shared__ u16 Bs[BN*32];
  int tid = threadIdx.x; int w = tid>>6, l = tid&63;
  int m0 = blockIdx.y*BM, n0 = blockIdx.x*BN;
  long coff = 0, srow0 = 0;
  if (BATCH){
    int z = blockIdx.z;
    A  += (long)z*2048*K;
    BT += (long)z*(long)N*K;
    coff  = (long)(z/HEADS_)*SEQ_*(long)ldC + (long)(z%HEADS_)*64;
    srow0 = (long)z*SEQ_;
  }
  f32x4 acc[FM][FN];
  #pragma unroll
  for (int i=0;i<FM;i++)
    #pragma unroll
    for (int j=0;j<FN;j++) acc[i][j] = (f32x4){0.f,0.f,0.f,0.f};

  const int row_l = l>>2, cq_l = l&3;
  const int wm = w / WN, wn = w % WN;
  const int kq = l>>4, rl15 = l&15;

  for (int k0=0; k0<K; k0+=32){
    __syncthreads();
    for (int c = w; c < ACH; c += 4){
      int r = c*16 + row_l;
      int gq = cq_l ^ ((r>>1)&3);
      gload16(A + (long)(m0+r)*K + k0 + gq*8, As + c*512);
    }
    for (int c = w; c < BCH; c += 4){
      int r = c*16 + row_l;
      int gq = cq_l ^ ((r>>1)&3);
      gload16(BT + (long)(n0+r)*K + k0 + gq*8, Bs + c*512);
    }
    __syncthreads();
    bf16x8 af[FM], bfr[FN];
    #pragma unroll
    for (int mi=0; mi<FM; mi++){
      int rr = (wm*FM + mi)*16 + rl15;
      int g = kq ^ ((rr>>1)&3);
      af[mi] = *(const bf16x8*)(As + rr*32 + g*8);
    }
    #pragma unroll
    for (int ni=0; ni<FN; ni++){
      int rr = (wn*FN + ni)*16 + rl15;
      int g = kq ^ ((rr>>1)&3);
      bfr[ni] = *(const bf16x8*)(Bs + rr*32 + g*8);
    }
    #pragma unroll
    for (int mi=0; mi<FM; mi++)
      #pragma unroll
      for (int ni=0; ni<FN; ni++)
        acc[mi][ni] = __builtin_amdgcn_mfma_f32_16x16x32_bf16(af[mi], bfr[ni], acc[mi][ni], 0, 0, 0);
  }

  int cc = l&15, rq = l>>4;
  #pragma unroll
  for (int mi=0; mi<FM; mi++){
    #pragma unroll
    for (int ni=0; ni<FN; ni++){
      int gcol = n0 + (wn*FN+ni)*16 + cc;
      float bv = bias ? bias[gcol] : 0.f;
      #pragma unroll
      for (int r4=0; r4<4; r4++){
        int grow = m0 + (wm*FM+mi)*16 + rq*4 + r4;
        float v = acc[mi][ni][r4] + bv;
        if (ACT) v = 0.5f*v*(1.0f + erff(v*0.70710678118654752f));
        if (CMODE==1){
          float* C = (float*)Cv;
          C[(long)grow*ldC + gcol] += v;
        } else if (CMODE==2){
          v *= scale[srow0 + grow];
          ((u16*)Cv)[coff + (long)grow*ldC + gcol] = f2bf(v);
        } else {
          ((u16*)Cv)[(long)grow*ldC + gcol] = f2bf(v);
        }
      }
    }
  }
}

// ---------------- K pass 1: global max of xd per (b,h) ----------------
__global__ __launch_bounds__(256) void kmax_kernel(const u16* __restrict__ X, int ld,
                        const float* __restrict__ proj, float* __restrict__ kmaxp){
  int z = blockIdx.y; int b = z/HEADS_, hh = z - b*HEADS_;
  int n0 = blockIdx.x*16;
  int t = threadIdx.x;
  __shared__ float qs[16][64];
  __shared__ float bmax_s[4];
  const u16* xb = X + ((long)b*SEQ_ + n0)*ld + hh*DH_;
  #pragma unroll
  for (int i=0;i<4;i++){ int e=t+i*256; int r=e>>6, d=e&63; qs[r][d]=bf2f(xb[(long)r*ld+d]); }
  float preg[64];
  const float* pr = proj + t*DH_;
  #pragma unroll
  for (int d4=0; d4<16; d4++){
    float4 p4 = *(const float4*)&pr[d4*4];
    preg[4*d4]=p4.x; preg[4*d4+1]=p4.y; preg[4*d4+2]=p4.z; preg[4*d4+3]=p4.w;
  }
  __syncthreads();
  float bm = -1e30f;
  #pragma unroll 4
  for (int r=0;r<16;r++){
    float a = 0.f;
    #pragma unroll
    for (int d4=0; d4<16; d4++){
      float4 qv = *(const float4*)&qs[r][d4*4];
      a += qv.x*preg[4*d4] + qv.y*preg[4*d4+1] + qv.z*preg[4*d4+2] + qv.w*preg[4*d4+3];
    }
    bm = fmaxf(bm, a*DN_);
  }
  int lane=t&63, wid=t>>6;
  #pragma unroll
  for (int off=32; off; off>>=1) bm = fmaxf(bm, __shfl_xor(bm,off));
  if (lane==0) bmax_s[wid]=bm;
  __syncthreads();
  if (t==0)
    kmaxp[z*128 + blockIdx.x] = fmaxf(fmaxf(bmax_s[0],bmax_s[1]),fmaxf(bmax_s[2],bmax_s[3]));
}

__global__ void kmax_reduce(const float* __restrict__ part, float* __restrict__ stab){
  int z = blockIdx.x; int t = threadIdx.x; // 64
  float m = fmaxf(part[z*128+t], part[z*128+64+t]);
  #pragma unroll
  for (int off=32; off; off>>=1) m = fmaxf(m, __shfl_xor(m,off));
  if (t==0) stab[z] = m;
}

// -- K pass 2: kp on the fly; ctx partials + ksum partials. NCH_ n-chunks. --
__global__ __launch_bounds__(256) void kctx_kernel(const u16* __restrict__ K, int ld,
                        const u16* __restrict__ V, const float* __restrict__ proj,
                        const float* __restrict__ stab, float* __restrict__ ctxp,
                        float* __restrict__ ksp){
  int chunk = blockIdx.x; int z = blockIdx.y;
  int b = z/HEADS_, hh = z - b*HEADS_;
  int t = threadIdx.x;
  __shared__ float ks_[16][64];
  __shared__ float vs_[16][64];
  __shared__ float diag_s[16];
  float preg[64];
  const float* pr = proj + t*DH_;
  #pragma unroll
  for (int d4=0; d4<16; d4++){
    float4 p4 = *(const float4*)&pr[d4*4];
    preg[4*d4]=p4.x; preg[4*d4+1]=p4.y; preg[4*d4+2]=p4.z; preg[4*d4+3]=p4.w;
  }
  float st = stab[z];
  float actx[64];
  #pragma unroll
  for (int d=0; d<64; d++) actx[d]=0.f;
  float aks = 0.f;
  const int RPC = SEQ_/NCH_;            // rows per chunk = 128
  int nbase = chunk*RPC;
  for (int sub=0; sub<RPC/16; sub++){
    int n0 = nbase + sub*16;
    const u16* kb_ = K + ((long)b*SEQ_ + n0)*ld + hh*DH_;
    const u16* vb_ = V + ((long)b*SEQ_ + n0)*ld + hh*DH_;
    __syncthreads();
    #pragma unroll
    for (int i=0;i<4;i++){
      int e = t + i*256; int r = e>>6, d = e&63;
      ks_[r][d] = bf2f(kb_[(long)r*ld + d]);
      vs_[r][d] = bf2f(vb_[(long)r*ld + d]);
    }
    __syncthreads();
    {
      int r = t>>4, p = t&15;
      float4 kv = *(const float4*)&ks_[r][p*4];
      float sq = kv.x*kv.x + kv.y*kv.y + kv.z*kv.z + kv.w*kv.w;
      sq += __shfl_xor(sq,1); sq += __shfl_xor(sq,2);
      sq += __shfl_xor(sq,4); sq += __shfl_xor(sq,8);
      if (p==0) diag_s[r] = 0.5f*DN_*DN_*sq;
    }
    __syncthreads();
    #pragma unroll 4
    for (int r=0;r<16;r++){
      float a = 0.f;
      #pragma unroll
      for (int d4=0; d4<16; d4++){
        float4 kv = *(const float4*)&ks_[r][d4*4];
        a += kv.x*preg[4*d4] + kv.y*preg[4*d4+1] + kv.z*preg[4*d4+2] + kv.w*preg[4*d4+3];
      }
      float kp = RATIO_*(expf(a*DN_ - diag_s[r] - st) + EPSK_);
      aks += kp;
      #pragma unroll
      for (int d4=0; d4<16; d4++){
        float4 vv = *(const float4*)&vs_[r][d4*4];
        actx[4*d4]   += kp*vv.x;
        actx[4*d4+1] += kp*vv.y;
        actx[4*d4+2] += kp*vv.z;
        actx[4*d4+3] += kp*vv.w;
      }
    }
  }
  float* cp = ctxp + ((long)chunk*BH_ + z)*(MF_*DH_) + (long)t*DH_;
  #pragma unroll
  for (int d4=0; d4<16; d4++){
    float4 o; o.x=actx[4*d4]; o.y=actx[4*d4+1]; o.z=actx[4*d4+2]; o.w=actx[4*d4+3];
    *(float4*)&cp[4*d4] = o;
  }
  ksp[(z*NCH_+chunk)*MF_ + t] = aks;
}

// reduce ctx partials -> ctxT bf16 [z][d][m]
__global__ void ctx_reduceT(const float* __restrict__ part, u16* __restrict__ ctxT){
  const long NT = (long)BH_*MF_*DH_; // 786432
  for (long i = (long)blockIdx.x*256 + threadIdx.x; i < NT; i += (long)gridDim.x*256){
    float s = 0.f;
    #pragma unroll
    for (int c=0;c<NCH_;c++) s += part[(long)c*NT + i];
    int z = (int)(i >> 14);
    int r = (int)(i & 16383);
    int m = r >> 6, d = r & 63;
    ctxT[(long)z*(MF_*DH_) + (long)d*MF_ + m] = f2bf(s);
  }
}

__global__ void ksum_reduce(const float* __restrict__ part, float* __restrict__ ksum){
  int z = blockIdx.x; int t = threadIdx.x;
  float s = 0.f;
  #pragma unroll
  for (int c=0;c<NCH_;c++) s += part[(z*NCH_+c)*MF_ + t];
  ksum[z*MF_+t] = s;
}

// ---- Q features: qp bf16 [z][n][m] + dinv fp32 [z][n] (two-phase, spill-free) ----
__global__ __launch_bounds__(256) void qfeat_kernel(const u16* __restrict__ X, int ld,
        const float* __restrict__ proj, const float* __restrict__ ksum,
        u16* __restrict__ qp, float* __restrict__ dinv){
  int z = blockIdx.y; int b = z/HEADS_, hh = z - b*HEADS_;
  int n0 = blockIdx.x*16;
  int t = threadIdx.x;
  __shared__ float qs[16][64];
  __shared__ float diag_s[16];
  __shared__ float xd_s[16][256];
  __shared__ float redm[16][4];
  __shared__ float redd[16][4];
  const u16* xb = X + ((long)b*SEQ_ + n0)*ld + hh*DH_;
  #pragma unroll
  for (int i=0;i<4;i++){ int e=t+i*256; int r=e>>6, d=e&63; qs[r][d]=bf2f(xb[(long)r*ld+d]); }
  {
    float preg[64];
    const float* pr = proj + t*DH_;
    #pragma unroll
    for (int d4=0; d4<16; d4++){
      float4 p4 = *(const float4*)&pr[d4*4];
      preg[4*d4]=p4.x; preg[4*d4+1]=p4.y; preg[4*d4+2]=p4.z; preg[4*d4+3]=p4.w;
    }
    __syncthreads();
    {
      int r = t>>4, p = t&15;
      float4 qv = *(const float4*)&qs[r][p*4];
      float sq = qv.x*qv.x + qv.y*qv.y + qv.z*qv.z + qv.w*qv.w;
      sq += __shfl_xor(sq,1); sq += __shfl_xor(sq,2);
      sq += __shfl_xor(sq,4); sq += __shfl_xor(sq,8);
      if (p==0) diag_s[r] = 0.5f*DN_*DN_*sq;
    }
    #pragma unroll 4
    for (int r=0;r<16;r++){
      float a = 0.f;
      #pragma unroll
      for (int d4=0; d4<16; d4++){
        float4 qv = *(const float4*)&qs[r][d4*4];
        a += qv.x*preg[4*d4] + qv.y*preg[4*d4+1] + qv.z*preg[4*d4+2] + qv.w*preg[4*d4+3];
      }
      xd_s[r][t] = a*DN_;
    }
  }
  __syncthreads();
  int lane=t&63, wid=t>>6;
  #pragma unroll
  for (int r=0;r<16;r++){
    float m = xd_s[r][t];
    #pragma unroll
    for (int off=32; off; off>>=1) m = fmaxf(m, __shfl_xor(m,off));
    if (lane==0) redm[r][wid]=m;
  }
  __syncthreads();
  float ks = ksum[(long)z*MF_ + t];
  #pragma unroll
  for (int r=0;r<16;r++){
    float mx = fmaxf(fmaxf(redm[r][0],redm[r][1]),fmaxf(redm[r][2],redm[r][3]));
    float qpv = RATIO_*(expf(xd_s[r][t] - diag_s[r] - mx) + EPSK_);
    u16 qb16 = f2bf(qpv);
    qp[((long)z*SEQ_ + n0 + r)*MF_ + t] = qb16;
    float dv = bf2f(qb16)*ks;
    #pragma unroll
    for (int off=32; off; off>>=1) dv += __shfl_xor(dv,off);
    if (lane==0) redd[r][wid]=dv;
  }
  __syncthreads();
  if (t<16){
    float s = redd[t][0]+redd[t][1]+redd[t][2]+redd[t][3];
    dinv[(long)z*SEQ_ + n0 + t] = 1.0f/s;
  }
}

// ---------------- final LN(row0) + pooler + classifier ----------------
__global__ __launch_bounds__(256) void pooler_kernel(const float* __restrict__ h,
                           const float* __restrict__ g, const float* __restrict__ bta,
                           const float* __restrict__ Wp, const float* __restrict__ bp,
                           const float* __restrict__ Wc, const float* __restrict__ bc,
                           float* __restrict__ out){
  int b = blockIdx.x, t = threadIdx.x;
  __shared__ float xn[768];
  __shared__ float pl[768];
  __shared__ float red[8];
  const float* row = h + (long)b*SEQ_*DIM_;
  float v0=row[t], v1=row[t+256], v2=row[t+512];
  float s = v0+v1+v2, ss = v0*v0+v1*v1+v2*v2;
  int lane=t&63, wid=t>>6;
  #pragma unroll
  for (int off=32; off; off>>=1){ s += __shfl_xor(s,off); ss += __shfl_xor(ss,off); }
  if (lane==0){ red[wid]=s; red[4+wid]=ss; }
  __syncthreads();
  s  = red[0]+red[1]+red[2]+red[3];
  ss = red[4]+red[5]+red[6]+red[7];
  float mu = s*(1.0f/DIM_);
  float var = ss*(1.0f/DIM_) - mu*mu;
  float rs = rsqrtf(var + EPSLN_);
  xn[t]     = (v0-mu)*rs*g[t]     + bta[t];
  xn[t+256] = (v1-mu)*rs*g[t+256] + bta[t+256];
  xn[t+512] = (v2-mu)*rs*g[t+512] + bta[t+512];
  __syncthreads();
  #pragma unroll
  for (int jj=0;jj<3;jj++){
    int j = t + jj*256;
    float a = bp[j];
    for (int i=0;i<768;i++) a += xn[i]*Wp[(long)i*DIM_ + j];
    pl[j] = tanhf(a);
  }
  __syncthreads();
  if (wid < 2){
    float a = 0.f;
    for (int i=lane;i<768;i+=64) a += pl[i]*Wc[i*2+wid];
    #pragma unroll
    for (int off=32; off; off>>=1) a += __shfl_xor(a,off);
    if (lane==0) out[b*2+wid] = a + bc[wid];
  }
}

extern "C" void kernel_launch(void* const* d_in, const int* in_sizes, int n_in,
                              void* d_out, int out_size, void* d_ws, size_t ws_size,
                              hipStream_t stream) {
  (void)in_sizes; (void)n_in; (void)out_size; (void)ws_size;
  const int*   x    = (const int*)  d_in[0];
  const float* tok  = (const float*)d_in[1];
  const float* pos  = (const float*)d_in[2];
  const float* ln1g = (const float*)d_in[3];
  const float* ln1b = (const float*)d_in[4];
  const float* Wq   = (const float*)d_in[5];
  const float* Wk   = (const float*)d_in[6];
  const float* Wv   = (const float*)d_in[7];
  const float* Wo   = (const float*)d_in[8];
  const float* bo   = (const float*)d_in[9];
  const float* proj = (const float*)d_in[10];
  const float* ln2g = (const float*)d_in[11];
  const float* ln2b = (const float*)d_in[12];
  const float* W1   = (const float*)d_in[13];
  const float* b1   = (const float*)d_in[14];
  const float* W2   = (const float*)d_in[15];
  const float* b2   = (const float*)d_in[16];
  const float* lnfg = (const float*)d_in[17];
  const float* lnfb = (const float*)d_in[18];
  const float* Wp   = (const float*)d_in[19];
  const float* bp   = (const float*)d_in[20];
  const float* Wc   = (const float*)d_in[21];
  const float* bc   = (const float*)d_in[22];
  float* out = (float*)d_out;

  // ---- workspace layout (bytes), max ~135.9 MiB ----
  char* wsb = (char*)d_ws;
  float* h     = (float*)(wsb + 0);                       // 25165824 B fp32
  u16*   ybf   = (u16*)  (wsb + 25165824);                // 12582912 B (ln out / attn out)
  float* ksp   = (float*)(wsb + 25165824);                // alias: dead between QKV-gemm & PV
  u16*   qkv   = (u16*)  (wsb + 37748736);                // 37748736 B = [8192][2304] bf16
  u16*   ffnbf = (u16*)  (wsb + 75497472);                // 50331648 B region
  u16*   qp    = (u16*)  (wsb + 75497472);                // alias (25 MB, after ctxp dead)
  float* ctxp  = (float*)(wsb + 75497472);                // alias: NCH_*48*16384*4 = 50331648 B exact
  u16*   wT    = (u16*)  (wsb + 125829120);               // 14155776 B
  u16*   ctxT  = (u16*)  (wsb + 139984896);               // 1572864 B
  float* ksum  = (float*)(wsb + 141557760);               // 49152 B
  float* kmaxp = (float*)(wsb + 141606912);               // 24576 B
  float* stab  = (float*)(wsb + 141631488);               // 256 B
  float* dinv  = (float*)(wsb + 141631744);               // 393216 B -> end 142024960
  u16* attnbf  = ybf;

  u16* wtq = wT;                 // [2304][768] stacked q,k,v
  u16* wto = wT + 1769472;
  u16* wt1 = wT + 2359296;       // [3072][768]
  u16* wt2 = wT + 4718592;       // [768][3072]

  embed_kernel<<<2048,256,0,stream>>>(x,(const float4*)tok,(const float4*)pos,(float4*)h);

  dim3 gD(6, 64);               // N=768
  dim3 gQKV(18, 64);            // N=2304
  dim3 gF(24, 64);              // N=3072
  dim3 gQ2(1, 16, BH_);         // PV batched
  dim3 gfeat(SEQ_/16, BH_);

  for (int l=0; l<DEPTH_; l++){
    const float* wq  = Wq + (size_t)l*DIM_*DIM_;
    const float* wk  = Wk + (size_t)l*DIM_*DIM_;
    const float* wv  = Wv + (size_t)l*DIM_*DIM_;
    const float* wo  = Wo + (size_t)l*DIM_*DIM_;
    const float* prj = proj + (size_t)l*MF_*DH_;
    const float* w1  = W1 + (size_t)l*DIM_*FF_;
    const float* w2  = W2 + (size_t)l*FF_*DIM_;

    tconv_kernel<<<dim3(24,24),256,0,stream>>>(wq, wtq,           768, 768);
    tconv_kernel<<<dim3(24,24),256,0,stream>>>(wk, wtq + 589824,  768, 768);
    tconv_kernel<<<dim3(24,24),256,0,stream>>>(wv, wtq + 1179648, 768, 768);
    tconv_kernel<<<dim3(24,24),256,0,stream>>>(wo, wto, 768, 768);
    tconv_kernel<<<dim3(96,24),256,0,stream>>>(w1, wt1, 768, 3072);
    tconv_kernel<<<dim3(24,96),256,0,stream>>>(w2, wt2, 3072, 768);

    ln_kernel<<<ROWS_,256,0,stream>>>(h, ln1g+(size_t)l*DIM_, ln1b+(size_t)l*DIM_, ybf);
    mgemm<4,4,2,2,0,0,0><<<gQKV,256,0,stream>>>(ybf, wtq, nullptr, qkv, nullptr, ROWS_, QKVW_, 768, QKVW_);

    kmax_kernel<<<gfeat,256,0,stream>>>(qkv + 768, QKVW_, prj, kmaxp);
    kmax_reduce<<<BH_,64,0,stream>>>(kmaxp, stab);
    kctx_kernel<<<dim3(NCH_,BH_),256,0,stream>>>(qkv + 768, QKVW_, qkv + 1536, prj, stab, ctxp, ksp);
    ctx_reduceT<<<768,256,0,stream>>>(ctxp, ctxT);
    ksum_reduce<<<BH_,256,0,stream>>>(ksp, ksum);

    qfeat_kernel<<<gfeat,256,0,stream>>>(qkv, QKVW_, prj, ksum, qp, dinv);
    mgemm<2,4,4,1,0,2,1><<<gQ2,256,0,stream>>>(qp, ctxT, nullptr, attnbf, dinv, SEQ_, 64, 256, 768);

    mgemm<4,4,2,2,0,1,0><<<gD,256,0,stream>>>(attnbf, wto, bo+(size_t)l*DIM_, h, nullptr, ROWS_, 768, 768, 768);

    ln_kernel<<<ROWS_,256,0,stream>>>(h, ln2g+(size_t)l*DIM_, ln2b+(size_t)l*DIM_, ybf);
    mgemm<4,4,2,2,1,0,0><<<gF,256,0,stream>>>(ybf, wt1, b1+(size_t)l*FF_, ffnbf, nullptr, ROWS_, 3072, 768, 3072);
    mgemm<4,4,2,2,0,1,0><<<gD,256,0,stream>>>(ffnbf, wt2, b2+(size_t)l*DIM_, h, nullptr, ROWS_, 768, 3072, 768);
  }

  pooler_kernel<<<B_,256,0,stream>>>(h, lnfg, lnfb, Wp, bp, Wc, bc, out);
}

// Round 6
// 3539.695 us; speedup vs baseline: 7.2579x; 1.4859x over previous
//
#include <hip/hip_runtime.h>
#include <hip/hip_bf16.h>
#include <math.h>

#define B_ 4
#define SEQ_ 2048
#define DIM_ 768
#define DEPTH_ 6
#define HEADS_ 12
#define DH_ 64
#define MF_ 256
#define FF_ 3072
#define ROWS_ 8192
#define BH_ 48
#define QKVW_ 2304
#define DN_ 0.3535533905932738f   /* 64^-0.25 */
#define RATIO_ 0.0625f            /* 256^-0.5 */
#define EPSK_ 1e-4f
#define EPSLN_ 1e-5f

typedef unsigned short u16;
typedef unsigned int   u32;
typedef __bf16 bf16x8 __attribute__((ext_vector_type(8)));
typedef u16    u16x8  __attribute__((ext_vector_type(8)));
typedef float  f32x4  __attribute__((ext_vector_type(4)));

__device__ inline u16 f2bf(float x){
  u32 u = __builtin_bit_cast(u32, x);
  return (u16)((u + 0x7FFFu + ((u>>16)&1u)) >> 16);
}
__device__ inline float bf2f(u16 v){ return __builtin_bit_cast(float, (u32)v<<16); }

__device__ inline void gload16(const u16* g, u16* lds){
  __builtin_amdgcn_global_load_lds(
    (const __attribute__((address_space(1))) u32*)(const void*)g,
    (__attribute__((address_space(3))) u32*)(void*)lds, 16, 0, 0);
}

// ---------------- embedding (h fp32) ----------------
__global__ void embed_kernel(const int* __restrict__ x, const float4* __restrict__ tok,
                             const float4* __restrict__ pos, float4* __restrict__ h){
  const int C4 = DIM_/4;
  long total = (long)ROWS_*C4;
  for (long i = (long)blockIdx.x*blockDim.x + threadIdx.x; i < total;
       i += (long)gridDim.x*blockDim.x){
    int row = (int)(i / C4); int c = (int)(i - (long)row*C4);
    int n = row & (SEQ_-1);
    float4 a = tok[(long)x[row]*C4 + c];
    float4 p = pos[(long)n*C4 + c];
    float4 o; o.x=a.x+p.x; o.y=a.y+p.y; o.z=a.z+p.z; o.w=a.w+p.w;
    h[i] = o;
  }
}

// ---------------- layernorm fp32 -> bf16 ----------------
__global__ __launch_bounds__(256) void ln_kernel(const float* __restrict__ X,
                          const float* __restrict__ g, const float* __restrict__ bta,
                          u16* __restrict__ Y){
  int row = blockIdx.x; int t = threadIdx.x;
  const float* xr = X + (long)row*DIM_;
  float v0 = xr[t], v1 = xr[t+256], v2 = xr[t+512];
  float s = v0+v1+v2;
  float ss = v0*v0+v1*v1+v2*v2;
  int lane = t&63, wid = t>>6;
  #pragma unroll
  for (int off=32; off; off>>=1){ s += __shfl_xor(s,off); ss += __shfl_xor(ss,off); }
  __shared__ float red[8];
  if (lane==0){ red[wid]=s; red[4+wid]=ss; }
  __syncthreads();
  s  = red[0]+red[1]+red[2]+red[3];
  ss = red[4]+red[5]+red[6]+red[7];
  float mu  = s*(1.0f/DIM_);
  float var = ss*(1.0f/DIM_) - mu*mu;
  float rs  = rsqrtf(var + EPSLN_);
  u16* yr = Y + (long)row*DIM_;
  yr[t]     = f2bf((v0-mu)*rs*g[t]     + bta[t]);
  yr[t+256] = f2bf((v1-mu)*rs*g[t+256] + bta[t+256]);
  yr[t+512] = f2bf((v2-mu)*rs*g[t+512] + bta[t+512]);
}

// ---------------- transpose + convert: WT[n][k] = bf16(W[k][n]) ----------------
__global__ __launch_bounds__(256) void tconv_kernel(const float* __restrict__ W,
        u16* __restrict__ WT, int K, int N){
  __shared__ float tile[32][33];
  int n0 = blockIdx.x*32, k0 = blockIdx.y*32;
  int tx = threadIdx.x & 31, ty = threadIdx.x >> 5;
  #pragma unroll
  for (int i=0;i<32;i+=8) tile[ty+i][tx] = W[(long)(k0+ty+i)*N + n0+tx];
  __syncthreads();
  #pragma unroll
  for (int i=0;i<32;i+=8) WT[(long)(n0+ty+i)*K + k0+tx] = f2bf(tile[tx][ty+i]);
}

// ---------------- MFMA GEMM: C = f(A[M,K]bf16 @ BT[N,K]^T bf16 + bias) ----------------
// CMODE: 0 = bf16 store (+bias,+gelu if ACT); 1 = fp32 C += (+bias); 2 = bf16 store * scale[row]
template<int FM, int FN, int WM, int WN, int ACT, int CMODE, int BATCH>
__global__ __launch_bounds__(256) void mgemm(const u16* __restrict__ A,
     const u16* __restrict__ BT, const float* __restrict__ bias,
     void* __restrict__ Cv, const float* __restrict__ scale,
     int M, int N, int K, int ldC){
  (void)M;
  constexpr int BM = WM*FM*16, BN = WN*FN*16;
  constexpr int ACH = BM/16, BCH = BN/16;
  __shared__ u16 As[BM*32];
  __shared__ u16 Bs[BN*32];
  int tid = threadIdx.x; int w = tid>>6, l = tid&63;
  int m0 = blockIdx.y*BM, n0 = blockIdx.x*BN;
  long coff = 0, srow0 = 0;
  if (BATCH){
    int z = blockIdx.z;
    A  += (long)z*2048*K;
    BT += (long)z*(long)N*K;
    coff  = (long)(z/HEADS_)*SEQ_*(long)ldC + (long)(z%HEADS_)*64;
    srow0 = (long)z*SEQ_;
  }
  f32x4 acc[FM][FN];
  #pragma unroll
  for (int i=0;i<FM;i++)
    #pragma unroll
    for (int j=0;j<FN;j++) acc[i][j] = (f32x4){0.f,0.f,0.f,0.f};

  const int row_l = l>>2, cq_l = l&3;
  const int wm = w / WN, wn = w % WN;
  const int kq = l>>4, rl15 = l&15;

  for (int k0=0; k0<K; k0+=32){
    __syncthreads();
    for (int c = w; c < ACH; c += 4){
      int r = c*16 + row_l;
      int gq = cq_l ^ ((r>>1)&3);
      gload16(A + (long)(m0+r)*K + k0 + gq*8, As + c*512);
    }
    for (int c = w; c < BCH; c += 4){
      int r = c*16 + row_l;
      int gq = cq_l ^ ((r>>1)&3);
      gload16(BT + (long)(n0+r)*K + k0 + gq*8, Bs + c*512);
    }
    __syncthreads();
    bf16x8 af[FM], bfr[FN];
    #pragma unroll
    for (int mi=0; mi<FM; mi++){
      int rr = (wm*FM + mi)*16 + rl15;
      int g = kq ^ ((rr>>1)&3);
      af[mi] = *(const bf16x8*)(As + rr*32 + g*8);
    }
    #pragma unroll
    for (int ni=0; ni<FN; ni++){
      int rr = (wn*FN + ni)*16 + rl15;
      int g = kq ^ ((rr>>1)&3);
      bfr[ni] = *(const bf16x8*)(Bs + rr*32 + g*8);
    }
    #pragma unroll
    for (int mi=0; mi<FM; mi++)
      #pragma unroll
      for (int ni=0; ni<FN; ni++)
        acc[mi][ni] = __builtin_amdgcn_mfma_f32_16x16x32_bf16(af[mi], bfr[ni], acc[mi][ni], 0, 0, 0);
  }

  int cc = l&15, rq = l>>4;
  #pragma unroll
  for (int mi=0; mi<FM; mi++){
    #pragma unroll
    for (int ni=0; ni<FN; ni++){
      int gcol = n0 + (wn*FN+ni)*16 + cc;
      float bv = bias ? bias[gcol] : 0.f;
      #pragma unroll
      for (int r4=0; r4<4; r4++){
        int grow = m0 + (wm*FM+mi)*16 + rq*4 + r4;
        float v = acc[mi][ni][r4] + bv;
        if (ACT) v = 0.5f*v*(1.0f + erff(v*0.70710678118654752f));
        if (CMODE==1){
          float* C = (float*)Cv;
          C[(long)grow*ldC + gcol] += v;
        } else if (CMODE==2){
          v *= scale[srow0 + grow];
          ((u16*)Cv)[coff + (long)grow*ldC + gcol] = f2bf(v);
        } else {
          ((u16*)Cv)[(long)grow*ldC + gcol] = f2bf(v);
        }
      }
    }
  }
}

// ---- projcvt: proj fp32 [256][64] -> bf16 ----
__global__ void projcvt_kernel(const float* __restrict__ p, u16* __restrict__ pb){
  int i = blockIdx.x*256 + threadIdx.x;   // grid 64 -> 16384
  pb[i] = f2bf(p[i]);
}

// ---- diag: diag[z][n] = 0.5*DN^2*||K_row||^2 ----
__global__ __launch_bounds__(256) void diag_kernel(const u16* __restrict__ X,
        float* __restrict__ diag){
  int chunk = blockIdx.x, z = blockIdx.y, t = threadIdx.x;
  int n = chunk*256 + t;
  const u16* r = X + ((long)(z/HEADS_)*SEQ_ + n)*QKVW_ + (z%HEADS_)*DH_;
  float s = 0.f;
  #pragma unroll
  for (int q=0;q<8;q++){
    u16x8 v = *(const u16x8*)(r + q*8);
    #pragma unroll
    for (int j=0;j<8;j++){ float f = bf2f(v[j]); s += f*f; }
  }
  diag[(long)z*SEQ_ + n] = 0.5f*DN_*DN_*s;
}

// ---- FAVOR feature GEMM (batched per z): xd = K_head[2048x64] @ projbf[256x64]^T
// MODE 0: write per-block max of xd*DN -> fmaxp[z*32 + by*2 + bx]
// MODE 1: kp[z][n][m] = bf16( RATIO*(exp(xd*DN - diag[z][n] - stab[z]) + EPS) )
template<int MODE>
__global__ __launch_bounds__(256) void featgemm(const u16* __restrict__ X,
     const u16* __restrict__ PB, const float* __restrict__ diag,
     const float* __restrict__ stab, u16* __restrict__ kp,
     float* __restrict__ fmaxp){
  __shared__ u16 As[128*32];
  __shared__ u16 Bs[128*32];
  __shared__ float wred[4];
  int tid = threadIdx.x; int w = tid>>6, l = tid&63;
  int n0 = blockIdx.x*128, m0 = blockIdx.y*128;
  int z = blockIdx.z;
  const u16* A = X + (long)(z/HEADS_)*SEQ_*QKVW_ + (z%HEADS_)*DH_;
  f32x4 acc[4][4];
  #pragma unroll
  for (int i=0;i<4;i++)
    #pragma unroll
    for (int j=0;j<4;j++) acc[i][j] = (f32x4){0.f,0.f,0.f,0.f};
  const int row_l = l>>2, cq_l = l&3;
  const int wm = w>>1, wn = w&1;
  const int kq = l>>4, rl15 = l&15;

  for (int k0=0; k0<64; k0+=32){
    __syncthreads();
    for (int c = w; c < 8; c += 4){
      int r = c*16 + row_l;
      int gq = cq_l ^ ((r>>1)&3);
      gload16(A + (long)(m0+r)*QKVW_ + k0 + gq*8, As + c*512);
    }
    for (int c = w; c < 8; c += 4){
      int r = c*16 + row_l;
      int gq = cq_l ^ ((r>>1)&3);
      gload16(PB + (long)(n0+r)*64 + k0 + gq*8, Bs + c*512);
    }
    __syncthreads();
    bf16x8 af[4], bfr[4];
    #pragma unroll
    for (int mi=0; mi<4; mi++){
      int rr = (wm*4 + mi)*16 + rl15;
      int g = kq ^ ((rr>>1)&3);
      af[mi] = *(const bf16x8*)(As + rr*32 + g*8);
    }
    #pragma unroll
    for (int ni=0; ni<4; ni++){
      int rr = (wn*4 + ni)*16 + rl15;
      int g = kq ^ ((rr>>1)&3);
      bfr[ni] = *(const bf16x8*)(Bs + rr*32 + g*8);
    }
    #pragma unroll
    for (int mi=0; mi<4; mi++)
      #pragma unroll
      for (int ni=0; ni<4; ni++)
        acc[mi][ni] = __builtin_amdgcn_mfma_f32_16x16x32_bf16(af[mi], bfr[ni], acc[mi][ni], 0, 0, 0);
  }

  if (MODE==0){
    float bm = -1e30f;
    #pragma unroll
    for (int mi=0;mi<4;mi++)
      #pragma unroll
      for (int ni=0;ni<4;ni++)
        #pragma unroll
        for (int r4=0;r4<4;r4++) bm = fmaxf(bm, acc[mi][ni][r4]);
    bm *= DN_;
    #pragma unroll
    for (int off=32; off; off>>=1) bm = fmaxf(bm, __shfl_xor(bm,off));
    if (l==0) wred[w] = bm;
    __syncthreads();
    if (tid==0)
      fmaxp[z*32 + blockIdx.y*2 + blockIdx.x] =
        fmaxf(fmaxf(wred[0],wred[1]),fmaxf(wred[2],wred[3]));
  } else {
    float st = stab[z];
    int cc = l&15, rq = l>>4;
    #pragma unroll
    for (int mi=0; mi<4; mi++){
      #pragma unroll
      for (int ni=0; ni<4; ni++){
        int gcol = n0 + (wn*4+ni)*16 + cc;
        #pragma unroll
        for (int r4=0; r4<4; r4++){
          int grow = m0 + (wm*4+mi)*16 + rq*4 + r4;
          float v = acc[mi][ni][r4]*DN_;
          float e = RATIO_*(expf(v - diag[(long)z*SEQ_ + grow] - st) + EPSK_);
          kp[((long)z*SEQ_ + grow)*MF_ + gcol] = f2bf(e);
        }
      }
    }
  }
}

__global__ void fmax_reduce(const float* __restrict__ fmaxp, float* __restrict__ stab){
  int z = blockIdx.x, t = threadIdx.x; // 64
  float m = (t<32) ? fmaxp[z*32+t] : -1e30f;
  #pragma unroll
  for (int off=32; off; off>>=1) m = fmaxf(m, __shfl_xor(m,off));
  if (t==0) stab[z] = m;
}

// ---- ctxgemm: ctxT-partial[d=64][m=256] = sum_n V[n][d]*kp[n][m] (TN, transpose-on-stage)
__global__ __launch_bounds__(256) void ctxgemm(const u16* __restrict__ qkv,
     const u16* __restrict__ kp, float* __restrict__ part){
  int kc = blockIdx.x;      // 0..1 (1024 rows each)
  int z  = blockIdx.y;
  int b = z/HEADS_, hh = z%HEADS_;
  int tid = threadIdx.x; int w = tid>>6, l = tid&63;
  __shared__ u16 Vt[64*40];
  __shared__ u16 Kpt[256*40];
  f32x4 acc[4][4];
  #pragma unroll
  for (int i=0;i<4;i++)
    #pragma unroll
    for (int j=0;j<4;j++) acc[i][j] = (f32x4){0.f,0.f,0.f,0.f};
  int n_l = tid&31, grp = tid>>5;
  const int kq = l>>4, rl15 = l&15;
  const long vbase = (long)b*SEQ_*QKVW_ + hh*DH_ + 1536;
  const long kbase = (long)z*SEQ_*MF_;

  for (int s=0; s<32; s++){
    int nG = kc*1024 + s*32 + n_l;
    __syncthreads();
    {
      u16x8 v = *(const u16x8*)(qkv + vbase + (long)nG*QKVW_ + grp*8);
      #pragma unroll
      for (int j=0;j<8;j++) Vt[(grp*8+j)*40 + n_l] = v[j];
    }
    {
      const u16* src = kp + kbase + (long)nG*MF_ + grp*32;
      #pragma unroll
      for (int q=0;q<4;q++){
        u16x8 v = *(const u16x8*)(src + q*8);
        #pragma unroll
        for (int j=0;j<8;j++) Kpt[(grp*32+q*8+j)*40 + n_l] = v[j];
      }
    }
    __syncthreads();
    bf16x8 af[4], bfr[4];
    #pragma unroll
    for (int mi=0; mi<4; mi++)
      af[mi] = *(const bf16x8*)(Vt + (mi*16+rl15)*40 + kq*8);
    #pragma unroll
    for (int ni=0; ni<4; ni++)
      bfr[ni] = *(const bf16x8*)(Kpt + ((w*4+ni)*16+rl15)*40 + kq*8);
    #pragma unroll
    for (int mi=0; mi<4; mi++)
      #pragma unroll
      for (int ni=0; ni<4; ni++)
        acc[mi][ni] = __builtin_amdgcn_mfma_f32_16x16x32_bf16(af[mi], bfr[ni], acc[mi][ni], 0, 0, 0);
  }

  int cc = l&15, rq = l>>4;
  float* pb = part + ((long)kc*BH_ + z)*(64*MF_);
  #pragma unroll
  for (int mi=0; mi<4; mi++){
    #pragma unroll
    for (int ni=0; ni<4; ni++){
      int m = (w*4+ni)*16 + cc;
      #pragma unroll
      for (int r4=0; r4<4; r4++){
        int d = mi*16 + rq*4 + r4;
        pb[(long)d*MF_ + m] = acc[mi][ni][r4];
      }
    }
  }
}

// reduce 2 ctx partials -> ctxT bf16 [z][d][m]
__global__ void ctx_reduce2(const float* __restrict__ part, u16* __restrict__ ctxT){
  const long NT = (long)BH_*64*MF_; // 786432
  for (long i = (long)blockIdx.x*256 + threadIdx.x; i < NT; i += (long)gridDim.x*256){
    ctxT[i] = f2bf(part[i] + part[NT + i]);
  }
}

// ---- ksum: column sums of kp ----
__global__ void ksum_part_kernel(const u16* __restrict__ kp, float* __restrict__ ksp){
  int kc = blockIdx.x, z = blockIdx.y, t = threadIdx.x;
  const u16* base = kp + ((long)z*SEQ_ + kc*256)*MF_ + t;
  float s = 0.f;
  for (int n=0;n<256;n++) s += bf2f(base[(long)n*MF_]);
  ksp[(z*8+kc)*MF_ + t] = s;
}

__global__ void ksum_reduce(const float* __restrict__ part, float* __restrict__ ksum){
  int z = blockIdx.x; int t = threadIdx.x;
  float s = 0.f;
  #pragma unroll
  for (int c=0;c<8;c++) s += part[(z*8+c)*MF_ + t];
  ksum[z*MF_+t] = s;
}

// ---- Q features: qp bf16 [z][n][m] + dinv fp32 [z][n] (two-phase, spill-free) ----
__global__ __launch_bounds__(256) void qfeat_kernel(const u16* __restrict__ X, int ld,
        const float* __restrict__ proj, const float* __restrict__ ksum,
        u16* __restrict__ qp, float* __restrict__ dinv){
  int z = blockIdx.y; int b = z/HEADS_, hh = z - b*HEADS_;
  int n0 = blockIdx.x*16;
  int t = threadIdx.x;
  __shared__ float qs[16][64];
  __shared__ float diag_s[16];
  __shared__ float xd_s[16][256];
  __shared__ float redm[16][4];
  __shared__ float redd[16][4];
  const u16* xb = X + ((long)b*SEQ_ + n0)*ld + hh*DH_;
  #pragma unroll
  for (int i=0;i<4;i++){ int e=t+i*256; int r=e>>6, d=e&63; qs[r][d]=bf2f(xb[(long)r*ld+d]); }
  {
    float preg[64];
    const float* pr = proj + t*DH_;
    #pragma unroll
    for (int d4=0; d4<16; d4++){
      float4 p4 = *(const float4*)&pr[d4*4];
      preg[4*d4]=p4.x; preg[4*d4+1]=p4.y; preg[4*d4+2]=p4.z; preg[4*d4+3]=p4.w;
    }
    __syncthreads();
    {
      int r = t>>4, p = t&15;
      float4 qv = *(const float4*)&qs[r][p*4];
      float sq = qv.x*qv.x + qv.y*qv.y + qv.z*qv.z + qv.w*qv.w;
      sq += __shfl_xor(sq,1); sq += __shfl_xor(sq,2);
      sq += __shfl_xor(sq,4); sq += __shfl_xor(sq,8);
      if (p==0) diag_s[r] = 0.5f*DN_*DN_*sq;
    }
    #pragma unroll 4
    for (int r=0;r<16;r++){
      float a = 0.f;
      #pragma unroll
      for (int d4=0; d4<16; d4++){
        float4 qv = *(const float4*)&qs[r][d4*4];
        a += qv.x*preg[4*d4] + qv.y*preg[4*d4+1] + qv.z*preg[4*d4+2] + qv.w*preg[4*d4+3];
      }
      xd_s[r][t] = a*DN_;
    }
  }
  __syncthreads();
  int lane=t&63, wid=t>>6;
  #pragma unroll
  for (int r=0;r<16;r++){
    float m = xd_s[r][t];
    #pragma unroll
    for (int off=32; off; off>>=1) m = fmaxf(m, __shfl_xor(m,off));
    if (lane==0) redm[r][wid]=m;
  }
  __syncthreads();
  float ks = ksum[(long)z*MF_ + t];
  #pragma unroll
  for (int r=0;r<16;r++){
    float mx = fmaxf(fmaxf(redm[r][0],redm[r][1]),fmaxf(redm[r][2],redm[r][3]));
    float qpv = RATIO_*(expf(xd_s[r][t] - diag_s[r] - mx) + EPSK_);
    u16 qb16 = f2bf(qpv);
    qp[((long)z*SEQ_ + n0 + r)*MF_ + t] = qb16;
    float dv = bf2f(qb16)*ks;
    #pragma unroll
    for (int off=32; off; off>>=1) dv += __shfl_xor(dv,off);
    if (lane==0) redd[r][wid]=dv;
  }
  __syncthreads();
  if (t<16){
    float s = redd[t][0]+redd[t][1]+redd[t][2]+redd[t][3];
    dinv[(long)z*SEQ_ + n0 + t] = 1.0f/s;
  }
}

// ---------------- final LN(row0) + pooler + classifier ----------------
__global__ __launch_bounds__(256) void pooler_kernel(const float* __restrict__ h,
                           const float* __restrict__ g, const float* __restrict__ bta,
                           const float* __restrict__ Wp, const float* __restrict__ bp,
                           const float* __restrict__ Wc, const float* __restrict__ bc,
                           float* __restrict__ out){
  int b = blockIdx.x, t = threadIdx.x;
  __shared__ float xn[768];
  __shared__ float pl[768];
  __shared__ float red[8];
  const float* row = h + (long)b*SEQ_*DIM_;
  float v0=row[t], v1=row[t+256], v2=row[t+512];
  float s = v0+v1+v2, ss = v0*v0+v1*v1+v2*v2;
  int lane=t&63, wid=t>>6;
  #pragma unroll
  for (int off=32; off; off>>=1){ s += __shfl_xor(s,off); ss += __shfl_xor(ss,off); }
  if (lane==0){ red[wid]=s; red[4+wid]=ss; }
  __syncthreads();
  s  = red[0]+red[1]+red[2]+red[3];
  ss = red[4]+red[5]+red[6]+red[7];
  float mu = s*(1.0f/DIM_);
  float var = ss*(1.0f/DIM_) - mu*mu;
  float rs = rsqrtf(var + EPSLN_);
  xn[t]     = (v0-mu)*rs*g[t]     + bta[t];
  xn[t+256] = (v1-mu)*rs*g[t+256] + bta[t+256];
  xn[t+512] = (v2-mu)*rs*g[t+512] + bta[t+512];
  __syncthreads();
  #pragma unroll
  for (int jj=0;jj<3;jj++){
    int j = t + jj*256;
    float a = bp[j];
    for (int i=0;i<768;i++) a += xn[i]*Wp[(long)i*DIM_ + j];
    pl[j] = tanhf(a);
  }
  __syncthreads();
  if (wid < 2){
    float a = 0.f;
    for (int i=lane;i<768;i+=64) a += pl[i]*Wc[i*2+wid];
    #pragma unroll
    for (int off=32; off; off>>=1) a += __shfl_xor(a,off);
    if (lane==0) out[b*2+wid] = a + bc[wid];
  }
}

extern "C" void kernel_launch(void* const* d_in, const int* in_sizes, int n_in,
                              void* d_out, int out_size, void* d_ws, size_t ws_size,
                              hipStream_t stream) {
  (void)in_sizes; (void)n_in; (void)out_size; (void)ws_size;
  const int*   x    = (const int*)  d_in[0];
  const float* tok  = (const float*)d_in[1];
  const float* pos  = (const float*)d_in[2];
  const float* ln1g = (const float*)d_in[3];
  const float* ln1b = (const float*)d_in[4];
  const float* Wq   = (const float*)d_in[5];
  const float* Wk   = (const float*)d_in[6];
  const float* Wv   = (const float*)d_in[7];
  const float* Wo   = (const float*)d_in[8];
  const float* bo   = (const float*)d_in[9];
  const float* proj = (const float*)d_in[10];
  const float* ln2g = (const float*)d_in[11];
  const float* ln2b = (const float*)d_in[12];
  const float* W1   = (const float*)d_in[13];
  const float* b1   = (const float*)d_in[14];
  const float* W2   = (const float*)d_in[15];
  const float* b2   = (const float*)d_in[16];
  const float* lnfg = (const float*)d_in[17];
  const float* lnfb = (const float*)d_in[18];
  const float* Wp   = (const float*)d_in[19];
  const float* bp   = (const float*)d_in[20];
  const float* Wc   = (const float*)d_in[21];
  const float* bc   = (const float*)d_in[22];
  float* out = (float*)d_out;

  // ---- workspace layout (bytes), peak 142,000,128 (<= proven 142,024,960) ----
  char* wsb = (char*)d_ws;
  float* h     = (float*)(wsb + 0);                 // 25165824 B fp32
  u16*   ybf   = (u16*)  (wsb + 25165824);          // 12582912 B region (ln out / attn out)
  // early-attn aliases inside ybf region (ln1-out dead after QKV gemm):
  float* ctxp2 = (float*)(wsb + 25165824);          // 6291456 B (2 partials)
  float* diag  = (float*)(wsb + 31457280);          // 393216 B
  float* ksp   = (float*)(wsb + 31850496);          // 393216 B
  float* fmaxp = (float*)(wsb + 32243712);          // 6144 B
  u16*   projbf= (u16*)  (wsb + 32249856);          // 32768 B
  float* stab  = (float*)(wsb + 32282624);          // 256 B
  u16*   qkv   = (u16*)  (wsb + 37748736);          // 37748736 B = [8192][2304] bf16
  u16*   ffnbf = (u16*)  (wsb + 75497472);          // 50331648 B region
  u16*   kp    = (u16*)  (wsb + 75497472);          // alias: kp then qp then ffn
  u16*   qp    = (u16*)  (wsb + 75497472);
  u16*   wT    = (u16*)  (wsb + 125829120);         // 14155776 B
  u16*   ctxT  = (u16*)  (wsb + 139984896);         // 1572864 B
  float* ksum  = (float*)(wsb + 141557760);         // 49152 B
  float* dinv  = (float*)(wsb + 141606912);         // 393216 B -> 142000128
  u16* attnbf  = ybf;

  u16* wtq = wT;                 // [2304][768] stacked q,k,v
  u16* wto = wT + 1769472;
  u16* wt1 = wT + 2359296;       // [3072][768]
  u16* wt2 = wT + 4718592;       // [768][3072]

  embed_kernel<<<2048,256,0,stream>>>(x,(const float4*)tok,(const float4*)pos,(float4*)h);

  dim3 gD(6, 64);               // N=768
  dim3 gQKV(18, 64);            // N=2304
  dim3 gF(24, 64);              // N=3072
  dim3 gQ2(1, 16, BH_);         // PV batched
  dim3 gfeat(SEQ_/16, BH_);
  dim3 gFG(2, 16, BH_);         // featgemm

  for (int l=0; l<DEPTH_; l++){
    const float* wq  = Wq + (size_t)l*DIM_*DIM_;
    const float* wk  = Wk + (size_t)l*DIM_*DIM_;
    const float* wv  = Wv + (size_t)l*DIM_*DIM_;
    const float* wo  = Wo + (size_t)l*DIM_*DIM_;
    const float* prj = proj + (size_t)l*MF_*DH_;
    const float* w1  = W1 + (size_t)l*DIM_*FF_;
    const float* w2  = W2 + (size_t)l*FF_*DIM_;

    tconv_kernel<<<dim3(24,24),256,0,stream>>>(wq, wtq,           768, 768);
    tconv_kernel<<<dim3(24,24),256,0,stream>>>(wk, wtq + 589824,  768, 768);
    tconv_kernel<<<dim3(24,24),256,0,stream>>>(wv, wtq + 1179648, 768, 768);
    tconv_kernel<<<dim3(24,24),256,0,stream>>>(wo, wto, 768, 768);
    tconv_kernel<<<dim3(96,24),256,0,stream>>>(w1, wt1, 768, 3072);
    tconv_kernel<<<dim3(24,96),256,0,stream>>>(w2, wt2, 3072, 768);

    ln_kernel<<<ROWS_,256,0,stream>>>(h, ln1g+(size_t)l*DIM_, ln1b+(size_t)l*DIM_, ybf);
    mgemm<4,4,2,2,0,0,0><<<gQKV,256,0,stream>>>(ybf, wtq, nullptr, qkv, nullptr, ROWS_, QKVW_, 768, QKVW_);

    // ---- K-side FAVOR on MFMA ----
    projcvt_kernel<<<64,256,0,stream>>>(prj, projbf);
    diag_kernel<<<dim3(8,BH_),256,0,stream>>>(qkv + 768, diag);
    featgemm<0><<<gFG,256,0,stream>>>(qkv + 768, projbf, nullptr, nullptr, nullptr, fmaxp);
    fmax_reduce<<<BH_,64,0,stream>>>(fmaxp, stab);
    featgemm<1><<<gFG,256,0,stream>>>(qkv + 768, projbf, diag, stab, kp, nullptr);
    ctxgemm<<<dim3(2,BH_),256,0,stream>>>(qkv, kp, ctxp2);
    ctx_reduce2<<<768,256,0,stream>>>(ctxp2, ctxT);
    ksum_part_kernel<<<dim3(8,BH_),256,0,stream>>>(kp, ksp);
    ksum_reduce<<<BH_,256,0,stream>>>(ksp, ksum);

    // ---- Q-side + PV ----
    qfeat_kernel<<<gfeat,256,0,stream>>>(qkv, QKVW_, prj, ksum, qp, dinv);
    mgemm<2,4,4,1,0,2,1><<<gQ2,256,0,stream>>>(qp, ctxT, nullptr, attnbf, dinv, SEQ_, 64, 256, 768);

    mgemm<4,4,2,2,0,1,0><<<gD,256,0,stream>>>(attnbf, wto, bo+(size_t)l*DIM_, h, nullptr, ROWS_, 768, 768, 768);

    ln_kernel<<<ROWS_,256,0,stream>>>(h, ln2g+(size_t)l*DIM_, ln2b+(size_t)l*DIM_, ybf);
    mgemm<4,4,2,2,1,0,0><<<gF,256,0,stream>>>(ybf, wt1, b1+(size_t)l*FF_, ffnbf, nullptr, ROWS_, 3072, 768, 3072);
    mgemm<4,4,2,2,0,1,0><<<gD,256,0,stream>>>(ffnbf, wt2, b2+(size_t)l*DIM_, h, nullptr, ROWS_, 768, 3072, 768);
  }

  pooler_kernel<<<B_,256,0,stream>>>(h, lnfg, lnfb, Wp, bp, Wc, bc, out);
}

// Round 7
// 2773.588 us; speedup vs baseline: 9.2627x; 1.2762x over previous
//
#include <hip/hip_runtime.h>
#include <hip/hip_bf16.h>
#include <math.h>

#define B_ 4
#define SEQ_ 2048
#define DIM_ 768
#define DEPTH_ 6
#define HEADS_ 12
#define DH_ 64
#define MF_ 256
#define FF_ 3072
#define ROWS_ 8192
#define BH_ 48
#define QKVW_ 2304
#define DN_ 0.3535533905932738f   /* 64^-0.25 */
#define RATIO_ 0.0625f            /* 256^-0.5 */
#define EPSK_ 1e-4f
#define EPSLN_ 1e-5f

typedef unsigned short u16;
typedef unsigned int   u32;
typedef __bf16 bf16x8 __attribute__((ext_vector_type(8)));
typedef u16    u16x8  __attribute__((ext_vector_type(8)));
typedef float  f32x4  __attribute__((ext_vector_type(4)));

__device__ inline u16 f2bf(float x){
  u32 u = __builtin_bit_cast(u32, x);
  return (u16)((u + 0x7FFFu + ((u>>16)&1u)) >> 16);
}
__device__ inline float bf2f(u16 v){ return __builtin_bit_cast(float, (u32)v<<16); }

__device__ inline void gload16(const u16* g, u16* lds){
  __builtin_amdgcn_global_load_lds(
    (const __attribute__((address_space(1))) u32*)(const void*)g,
    (__attribute__((address_space(3))) u32*)(void*)lds, 16, 0, 0);
}

// ---------------- embedding (h fp32) ----------------
__global__ void embed_kernel(const int* __restrict__ x, const float4* __restrict__ tok,
                             const float4* __restrict__ pos, float4* __restrict__ h){
  const int C4 = DIM_/4;
  long total = (long)ROWS_*C4;
  for (long i = (long)blockIdx.x*blockDim.x + threadIdx.x; i < total;
       i += (long)gridDim.x*blockDim.x){
    int row = (int)(i / C4); int c = (int)(i - (long)row*C4);
    int n = row & (SEQ_-1);
    float4 a = tok[(long)x[row]*C4 + c];
    float4 p = pos[(long)n*C4 + c];
    float4 o; o.x=a.x+p.x; o.y=a.y+p.y; o.z=a.z+p.z; o.w=a.w+p.w;
    h[i] = o;
  }
}

// ---------------- layernorm fp32 -> bf16 ----------------
__global__ __launch_bounds__(256) void ln_kernel(const float* __restrict__ X,
                          const float* __restrict__ g, const float* __restrict__ bta,
                          u16* __restrict__ Y){
  int row = blockIdx.x; int t = threadIdx.x;
  const float* xr = X + (long)row*DIM_;
  float v0 = xr[t], v1 = xr[t+256], v2 = xr[t+512];
  float s = v0+v1+v2;
  float ss = v0*v0+v1*v1+v2*v2;
  int lane = t&63, wid = t>>6;
  #pragma unroll
  for (int off=32; off; off>>=1){ s += __shfl_xor(s,off); ss += __shfl_xor(ss,off); }
  __shared__ float red[8];
  if (lane==0){ red[wid]=s; red[4+wid]=ss; }
  __syncthreads();
  s  = red[0]+red[1]+red[2]+red[3];
  ss = red[4]+red[5]+red[6]+red[7];
  float mu  = s*(1.0f/DIM_);
  float var = ss*(1.0f/DIM_) - mu*mu;
  float rs  = rsqrtf(var + EPSLN_);
  u16* yr = Y + (long)row*DIM_;
  yr[t]     = f2bf((v0-mu)*rs*g[t]     + bta[t]);
  yr[t+256] = f2bf((v1-mu)*rs*g[t+256] + bta[t+256]);
  yr[t+512] = f2bf((v2-mu)*rs*g[t+512] + bta[t+512]);
}

// ---------------- transpose + convert: WT[n][k] = bf16(W[k][n]) ----------------
__global__ __launch_bounds__(256) void tconv_kernel(const float* __restrict__ W,
        u16* __restrict__ WT, int K, int N){
  __shared__ float tile[32][33];
  int n0 = blockIdx.x*32, k0 = blockIdx.y*32;
  int tx = threadIdx.x & 31, ty = threadIdx.x >> 5;
  #pragma unroll
  for (int i=0;i<32;i+=8) tile[ty+i][tx] = W[(long)(k0+ty+i)*N + n0+tx];
  __syncthreads();
  #pragma unroll
  for (int i=0;i<32;i+=8) WT[(long)(n0+ty+i)*K + k0+tx] = f2bf(tile[tx][ty+i]);
}

// ---------------- MFMA GEMM: C = f(A[M,K]bf16 @ BT[N,K]^T bf16 + bias) ----------------
// CMODE: 0 = bf16 store (+bias,+gelu if ACT); 1 = fp32 C += (+bias); 2 = bf16 store * scale[row]
template<int FM, int FN, int WM, int WN, int ACT, int CMODE, int BATCH>
__global__ __launch_bounds__(256) void mgemm(const u16* __restrict__ A,
     const u16* __restrict__ BT, const float* __restrict__ bias,
     void* __restrict__ Cv, const float* __restrict__ scale,
     int M, int N, int K, int ldC){
  (void)M;
  constexpr int BM = WM*FM*16, BN = WN*FN*16;
  constexpr int ACH = BM/16, BCH = BN/16;
  __shared__ u16 As[BM*32];
  __shared__ u16 Bs[BN*32];
  int tid = threadIdx.x; int w = tid>>6, l = tid&63;
  int m0 = blockIdx.y*BM, n0 = blockIdx.x*BN;
  long coff = 0, srow0 = 0;
  if (BATCH){
    int z = blockIdx.z;
    A  += (long)z*2048*K;
    BT += (long)z*(long)N*K;
    coff  = (long)(z/HEADS_)*SEQ_*(long)ldC + (long)(z%HEADS_)*64;
    srow0 = (long)z*SEQ_;
  }
  f32x4 acc[FM][FN];
  #pragma unroll
  for (int i=0;i<FM;i++)
    #pragma unroll
    for (int j=0;j<FN;j++) acc[i][j] = (f32x4){0.f,0.f,0.f,0.f};

  const int row_l = l>>2, cq_l = l&3;
  const int wm = w / WN, wn = w % WN;
  const int kq = l>>4, rl15 = l&15;

  for (int k0=0; k0<K; k0+=32){
    __syncthreads();
    for (int c = w; c < ACH; c += 4){
      int r = c*16 + row_l;
      int gq = cq_l ^ ((r>>1)&3);
      gload16(A + (long)(m0+r)*K + k0 + gq*8, As + c*512);
    }
    for (int c = w; c < BCH; c += 4){
      int r = c*16 + row_l;
      int gq = cq_l ^ ((r>>1)&3);
      gload16(BT + (long)(n0+r)*K + k0 + gq*8, Bs + c*512);
    }
    __syncthreads();
    bf16x8 af[FM], bfr[FN];
    #pragma unroll
    for (int mi=0; mi<FM; mi++){
      int rr = (wm*FM + mi)*16 + rl15;
      int g = kq ^ ((rr>>1)&3);
      af[mi] = *(const bf16x8*)(As + rr*32 + g*8);
    }
    #pragma unroll
    for (int ni=0; ni<FN; ni++){
      int rr = (wn*FN + ni)*16 + rl15;
      int g = kq ^ ((rr>>1)&3);
      bfr[ni] = *(const bf16x8*)(Bs + rr*32 + g*8);
    }
    #pragma unroll
    for (int mi=0; mi<FM; mi++)
      #pragma unroll
      for (int ni=0; ni<FN; ni++)
        acc[mi][ni] = __builtin_amdgcn_mfma_f32_16x16x32_bf16(af[mi], bfr[ni], acc[mi][ni], 0, 0, 0);
  }

  int cc = l&15, rq = l>>4;
  #pragma unroll
  for (int mi=0; mi<FM; mi++){
    #pragma unroll
    for (int ni=0; ni<FN; ni++){
      int gcol = n0 + (wn*FN+ni)*16 + cc;
      float bv = bias ? bias[gcol] : 0.f;
      #pragma unroll
      for (int r4=0; r4<4; r4++){
        int grow = m0 + (wm*FM+mi)*16 + rq*4 + r4;
        float v = acc[mi][ni][r4] + bv;
        if (ACT) v = 0.5f*v*(1.0f + erff(v*0.70710678118654752f));
        if (CMODE==1){
          float* C = (float*)Cv;
          C[(long)grow*ldC + gcol] += v;
        } else if (CMODE==2){
          v *= scale[srow0 + grow];
          ((u16*)Cv)[coff + (long)grow*ldC + gcol] = f2bf(v);
        } else {
          ((u16*)Cv)[(long)grow*ldC + gcol] = f2bf(v);
        }
      }
    }
  }
}

// ---- projcvt: proj fp32 [256][64] -> bf16 hi + bf16 lo (residual) ----
__global__ void projcvt_kernel(const float* __restrict__ p, u16* __restrict__ hi,
                               u16* __restrict__ lo){
  int i = blockIdx.x*256 + threadIdx.x;   // grid 64 -> 16384
  float v = p[i];
  u16 h = f2bf(v);
  hi[i] = h;
  lo[i] = f2bf(v - bf2f(h));
}

// ---- diag: diag[z][n] = 0.5*DN^2*||row||^2 (X = q or k cols of qkv) ----
__global__ __launch_bounds__(256) void diag_kernel(const u16* __restrict__ X,
        float* __restrict__ diag){
  int chunk = blockIdx.x, z = blockIdx.y, t = threadIdx.x;
  int n = chunk*256 + t;
  const u16* r = X + ((long)(z/HEADS_)*SEQ_ + n)*QKVW_ + (z%HEADS_)*DH_;
  float s = 0.f;
  #pragma unroll
  for (int q=0;q<8;q++){
    u16x8 v = *(const u16x8*)(r + q*8);
    #pragma unroll
    for (int j=0;j<8;j++){ float f = bf2f(v[j]); s += f*f; }
  }
  diag[(long)z*SEQ_ + n] = 0.5f*DN_*DN_*s;
}

// ---- FAVOR K feature GEMM (batched per z): xd = K_head[2048x64] @ projbf[256x64]^T
// MODE 0: write per-block max of xd*DN -> fmaxp[z*32 + by*2 + bx]
// MODE 1: kp[z][n][m] = bf16( RATIO*(exp(xd*DN - diag[z][n] - stab[z]) + EPS) )
template<int MODE>
__global__ __launch_bounds__(256) void featgemm(const u16* __restrict__ X,
     const u16* __restrict__ PB, const float* __restrict__ diag,
     const float* __restrict__ stab, u16* __restrict__ kp,
     float* __restrict__ fmaxp){
  __shared__ u16 As[128*32];
  __shared__ u16 Bs[128*32];
  __shared__ float wred[4];
  int tid = threadIdx.x; int w = tid>>6, l = tid&63;
  int n0 = blockIdx.x*128, m0 = blockIdx.y*128;
  int z = blockIdx.z;
  const u16* A = X + (long)(z/HEADS_)*SEQ_*QKVW_ + (z%HEADS_)*DH_;
  f32x4 acc[4][4];
  #pragma unroll
  for (int i=0;i<4;i++)
    #pragma unroll
    for (int j=0;j<4;j++) acc[i][j] = (f32x4){0.f,0.f,0.f,0.f};
  const int row_l = l>>2, cq_l = l&3;
  const int wm = w>>1, wn = w&1;
  const int kq = l>>4, rl15 = l&15;

  for (int k0=0; k0<64; k0+=32){
    __syncthreads();
    for (int c = w; c < 8; c += 4){
      int r = c*16 + row_l;
      int gq = cq_l ^ ((r>>1)&3);
      gload16(A + (long)(m0+r)*QKVW_ + k0 + gq*8, As + c*512);
    }
    for (int c = w; c < 8; c += 4){
      int r = c*16 + row_l;
      int gq = cq_l ^ ((r>>1)&3);
      gload16(PB + (long)(n0+r)*64 + k0 + gq*8, Bs + c*512);
    }
    __syncthreads();
    bf16x8 af[4], bfr[4];
    #pragma unroll
    for (int mi=0; mi<4; mi++){
      int rr = (wm*4 + mi)*16 + rl15;
      int g = kq ^ ((rr>>1)&3);
      af[mi] = *(const bf16x8*)(As + rr*32 + g*8);
    }
    #pragma unroll
    for (int ni=0; ni<4; ni++){
      int rr = (wn*4 + ni)*16 + rl15;
      int g = kq ^ ((rr>>1)&3);
      bfr[ni] = *(const bf16x8*)(Bs + rr*32 + g*8);
    }
    #pragma unroll
    for (int mi=0; mi<4; mi++)
      #pragma unroll
      for (int ni=0; ni<4; ni++)
        acc[mi][ni] = __builtin_amdgcn_mfma_f32_16x16x32_bf16(af[mi], bfr[ni], acc[mi][ni], 0, 0, 0);
  }

  if (MODE==0){
    float bm = -1e30f;
    #pragma unroll
    for (int mi=0;mi<4;mi++)
      #pragma unroll
      for (int ni=0;ni<4;ni++)
        #pragma unroll
        for (int r4=0;r4<4;r4++) bm = fmaxf(bm, acc[mi][ni][r4]);
    bm *= DN_;
    #pragma unroll
    for (int off=32; off; off>>=1) bm = fmaxf(bm, __shfl_xor(bm,off));
    if (l==0) wred[w] = bm;
    __syncthreads();
    if (tid==0)
      fmaxp[z*32 + blockIdx.y*2 + blockIdx.x] =
        fmaxf(fmaxf(wred[0],wred[1]),fmaxf(wred[2],wred[3]));
  } else {
    float st = stab[z];
    int cc = l&15, rq = l>>4;
    #pragma unroll
    for (int mi=0; mi<4; mi++){
      #pragma unroll
      for (int ni=0; ni<4; ni++){
        int gcol = n0 + (wn*4+ni)*16 + cc;
        #pragma unroll
        for (int r4=0; r4<4; r4++){
          int grow = m0 + (wm*4+mi)*16 + rq*4 + r4;
          float v = acc[mi][ni][r4]*DN_;
          float e = RATIO_*(expf(v - diag[(long)z*SEQ_ + grow] - st) + EPSK_);
          kp[((long)z*SEQ_ + grow)*MF_ + gcol] = f2bf(e);
        }
      }
    }
  }
}

__global__ void fmax_reduce(const float* __restrict__ fmaxp, float* __restrict__ stab){
  int z = blockIdx.x, t = threadIdx.x; // 64
  float m = (t<32) ? fmaxp[z*32+t] : -1e30f;
  #pragma unroll
  for (int off=32; off; off>>=1) m = fmaxf(m, __shfl_xor(m,off));
  if (t==0) stab[z] = m;
}

// ---- Q feature GEMM + per-row max + qp + dinv, all in one block (64 rows x 256 m) ----
// hi/lo split proj for near-fp32 argument precision. grid (32, BH_)
__global__ __launch_bounds__(256) void qfeatgemm(const u16* __restrict__ X,
     const u16* __restrict__ PH, const u16* __restrict__ PL,
     const float* __restrict__ diagq, const float* __restrict__ ksum,
     u16* __restrict__ qp, float* __restrict__ dinv){
  __shared__ u16 As[64*32];       // 4 KB
  __shared__ u16 Bh[256*32];      // 16 KB
  __shared__ u16 Bl[256*32];      // 16 KB
  __shared__ float ksl[256];
  __shared__ float rmax[64][4];
  __shared__ float rsum[64][4];
  int tid = threadIdx.x; int w = tid>>6, l = tid&63;
  int n0 = blockIdx.x*64;
  int z = blockIdx.y;
  const u16* A = X + (long)(z/HEADS_)*SEQ_*QKVW_ + (z%HEADS_)*DH_;  // Q cols
  ksl[tid] = ksum[(long)z*MF_ + tid];
  f32x4 acc[4][4];
  #pragma unroll
  for (int i=0;i<4;i++)
    #pragma unroll
    for (int j=0;j<4;j++) acc[i][j] = (f32x4){0.f,0.f,0.f,0.f};
  const int row_l = l>>2, cq_l = l&3;
  const int kq = l>>4, rl15 = l&15;

  for (int k0=0; k0<64; k0+=32){
    __syncthreads();
    { // A: 4 chunks of 16 rows, one per wave
      int r = w*16 + row_l;
      int gq = cq_l ^ ((r>>1)&3);
      gload16(A + (long)(n0+r)*QKVW_ + k0 + gq*8, As + w*512);
    }
    for (int c = w; c < 16; c += 4){
      int r = c*16 + row_l;
      int gq = cq_l ^ ((r>>1)&3);
      gload16(PH + (long)r*64 + k0 + gq*8, Bh + c*512);
      gload16(PL + (long)r*64 + k0 + gq*8, Bl + c*512);
    }
    __syncthreads();
    bf16x8 af[4], bh[4], bl[4];
    #pragma unroll
    for (int mi=0; mi<4; mi++){
      int rr = mi*16 + rl15;
      int g = kq ^ ((rr>>1)&3);
      af[mi] = *(const bf16x8*)(As + rr*32 + g*8);
    }
    #pragma unroll
    for (int ni=0; ni<4; ni++){
      int rr = (w*4 + ni)*16 + rl15;
      int g = kq ^ ((rr>>1)&3);
      bh[ni] = *(const bf16x8*)(Bh + rr*32 + g*8);
      bl[ni] = *(const bf16x8*)(Bl + rr*32 + g*8);
    }
    #pragma unroll
    for (int mi=0; mi<4; mi++)
      #pragma unroll
      for (int ni=0; ni<4; ni++){
        acc[mi][ni] = __builtin_amdgcn_mfma_f32_16x16x32_bf16(af[mi], bh[ni], acc[mi][ni], 0, 0, 0);
        acc[mi][ni] = __builtin_amdgcn_mfma_f32_16x16x32_bf16(af[mi], bl[ni], acc[mi][ni], 0, 0, 0);
      }
  }

  int cc = l&15, rq = l>>4;
  // per-row max over all 256 m
  #pragma unroll
  for (int mi=0; mi<4; mi++){
    #pragma unroll
    for (int r4=0; r4<4; r4++){
      float pm = fmaxf(fmaxf(acc[mi][0][r4],acc[mi][1][r4]),
                       fmaxf(acc[mi][2][r4],acc[mi][3][r4]));
      pm = fmaxf(pm, __shfl_xor(pm,1)); pm = fmaxf(pm, __shfl_xor(pm,2));
      pm = fmaxf(pm, __shfl_xor(pm,4)); pm = fmaxf(pm, __shfl_xor(pm,8));
      if (cc==0) rmax[mi*16 + rq*4 + r4][w] = pm;
    }
  }
  __syncthreads();
  #pragma unroll
  for (int mi=0; mi<4; mi++){
    #pragma unroll
    for (int r4=0; r4<4; r4++){
      int row = mi*16 + rq*4 + r4;
      float mx = fmaxf(fmaxf(rmax[row][0],rmax[row][1]),
                       fmaxf(rmax[row][2],rmax[row][3])) * DN_;
      float dq = diagq[(long)z*SEQ_ + n0 + row];
      float dv = 0.f;
      #pragma unroll
      for (int ni=0; ni<4; ni++){
        int col = w*64 + ni*16 + cc;
        float qpv = RATIO_*(expf(acc[mi][ni][r4]*DN_ - dq - mx) + EPSK_);
        u16 qb = f2bf(qpv);
        qp[((long)z*SEQ_ + n0 + row)*MF_ + col] = qb;
        dv += bf2f(qb)*ksl[col];
      }
      dv += __shfl_xor(dv,1); dv += __shfl_xor(dv,2);
      dv += __shfl_xor(dv,4); dv += __shfl_xor(dv,8);
      if (cc==0) rsum[row][w] = dv;
    }
  }
  __syncthreads();
  if (tid < 64){
    float s = rsum[tid][0]+rsum[tid][1]+rsum[tid][2]+rsum[tid][3];
    dinv[(long)z*SEQ_ + n0 + tid] = 1.0f/s;
  }
}

// ---- ctxgemm: ctxT-partial[d=64][m=256] = sum_n V[n][d]*kp[n][m] (TN, transpose-on-stage)
__global__ __launch_bounds__(256) void ctxgemm(const u16* __restrict__ qkv,
     const u16* __restrict__ kp, float* __restrict__ part){
  int kc = blockIdx.x;      // 0..1 (1024 rows each)
  int z  = blockIdx.y;
  int b = z/HEADS_, hh = z%HEADS_;
  int tid = threadIdx.x; int w = tid>>6, l = tid&63;
  __shared__ u16 Vt[64*40];
  __shared__ u16 Kpt[256*40];
  f32x4 acc[4][4];
  #pragma unroll
  for (int i=0;i<4;i++)
    #pragma unroll
    for (int j=0;j<4;j++) acc[i][j] = (f32x4){0.f,0.f,0.f,0.f};
  int n_l = tid&31, grp = tid>>5;
  const int kq = l>>4, rl15 = l&15;
  const long vbase = (long)b*SEQ_*QKVW_ + hh*DH_ + 1536;
  const long kbase = (long)z*SEQ_*MF_;

  for (int s=0; s<32; s++){
    int nG = kc*1024 + s*32 + n_l;
    __syncthreads();
    {
      u16x8 v = *(const u16x8*)(qkv + vbase + (long)nG*QKVW_ + grp*8);
      #pragma unroll
      for (int j=0;j<8;j++) Vt[(grp*8+j)*40 + n_l] = v[j];
    }
    {
      const u16* src = kp + kbase + (long)nG*MF_ + grp*32;
      #pragma unroll
      for (int q=0;q<4;q++){
        u16x8 v = *(const u16x8*)(src + q*8);
        #pragma unroll
        for (int j=0;j<8;j++) Kpt[(grp*32+q*8+j)*40 + n_l] = v[j];
      }
    }
    __syncthreads();
    bf16x8 af[4], bfr[4];
    #pragma unroll
    for (int mi=0; mi<4; mi++)
      af[mi] = *(const bf16x8*)(Vt + (mi*16+rl15)*40 + kq*8);
    #pragma unroll
    for (int ni=0; ni<4; ni++)
      bfr[ni] = *(const bf16x8*)(Kpt + ((w*4+ni)*16+rl15)*40 + kq*8);
    #pragma unroll
    for (int mi=0; mi<4; mi++)
      #pragma unroll
      for (int ni=0; ni<4; ni++)
        acc[mi][ni] = __builtin_amdgcn_mfma_f32_16x16x32_bf16(af[mi], bfr[ni], acc[mi][ni], 0, 0, 0);
  }

  int cc = l&15, rq = l>>4;
  float* pb = part + ((long)kc*BH_ + z)*(64*MF_);
  #pragma unroll
  for (int mi=0; mi<4; mi++){
    #pragma unroll
    for (int ni=0; ni<4; ni++){
      int m = (w*4+ni)*16 + cc;
      #pragma unroll
      for (int r4=0; r4<4; r4++){
        int d = mi*16 + rq*4 + r4;
        pb[(long)d*MF_ + m] = acc[mi][ni][r4];
      }
    }
  }
}

// reduce 2 ctx partials -> ctxT bf16 [z][d][m]
__global__ void ctx_reduce2(const float* __restrict__ part, u16* __restrict__ ctxT){
  const long NT = (long)BH_*64*MF_; // 786432
  for (long i = (long)blockIdx.x*256 + threadIdx.x; i < NT; i += (long)gridDim.x*256){
    ctxT[i] = f2bf(part[i] + part[NT + i]);
  }
}

// ---- ksum: column sums of kp ----
__global__ void ksum_part_kernel(const u16* __restrict__ kp, float* __restrict__ ksp){
  int kc = blockIdx.x, z = blockIdx.y, t = threadIdx.x;
  const u16* base = kp + ((long)z*SEQ_ + kc*256)*MF_ + t;
  float s = 0.f;
  for (int n=0;n<256;n++) s += bf2f(base[(long)n*MF_]);
  ksp[(z*8+kc)*MF_ + t] = s;
}

__global__ void ksum_reduce(const float* __restrict__ part, float* __restrict__ ksum){
  int z = blockIdx.x; int t = threadIdx.x;
  float s = 0.f;
  #pragma unroll
  for (int c=0;c<8;c++) s += part[(z*8+c)*MF_ + t];
  ksum[z*MF_+t] = s;
}

// ---------------- final LN(row0) + pooler + classifier ----------------
__global__ __launch_bounds__(256) void pooler_kernel(const float* __restrict__ h,
                           const float* __restrict__ g, const float* __restrict__ bta,
                           const float* __restrict__ Wp, const float* __restrict__ bp,
                           const float* __restrict__ Wc, const float* __restrict__ bc,
                           float* __restrict__ out){
  int b = blockIdx.x, t = threadIdx.x;
  __shared__ float xn[768];
  __shared__ float pl[768];
  __shared__ float red[8];
  const float* row = h + (long)b*SEQ_*DIM_;
  float v0=row[t], v1=row[t+256], v2=row[t+512];
  float s = v0+v1+v2, ss = v0*v0+v1*v1+v2*v2;
  int lane=t&63, wid=t>>6;
  #pragma unroll
  for (int off=32; off; off>>=1){ s += __shfl_xor(s,off); ss += __shfl_xor(ss,off); }
  if (lane==0){ red[wid]=s; red[4+wid]=ss; }
  __syncthreads();
  s  = red[0]+red[1]+red[2]+red[3];
  ss = red[4]+red[5]+red[6]+red[7];
  float mu = s*(1.0f/DIM_);
  float var = ss*(1.0f/DIM_) - mu*mu;
  float rs = rsqrtf(var + EPSLN_);
  xn[t]     = (v0-mu)*rs*g[t]     + bta[t];
  xn[t+256] = (v1-mu)*rs*g[t+256] + bta[t+256];
  xn[t+512] = (v2-mu)*rs*g[t+512] + bta[t+512];
  __syncthreads();
  #pragma unroll
  for (int jj=0;jj<3;jj++){
    int j = t + jj*256;
    float a = bp[j];
    for (int i=0;i<768;i++) a += xn[i]*Wp[(long)i*DIM_ + j];
    pl[j] = tanhf(a);
  }
  __syncthreads();
  if (wid < 2){
    float a = 0.f;
    for (int i=lane;i<768;i+=64) a += pl[i]*Wc[i*2+wid];
    #pragma unroll
    for (int off=32; off; off>>=1) a += __shfl_xor(a,off);
    if (lane==0) out[b*2+wid] = a + bc[wid];
  }
}

extern "C" void kernel_launch(void* const* d_in, const int* in_sizes, int n_in,
                              void* d_out, int out_size, void* d_ws, size_t ws_size,
                              hipStream_t stream) {
  (void)in_sizes; (void)n_in; (void)out_size; (void)ws_size;
  const int*   x    = (const int*)  d_in[0];
  const float* tok  = (const float*)d_in[1];
  const float* pos  = (const float*)d_in[2];
  const float* ln1g = (const float*)d_in[3];
  const float* ln1b = (const float*)d_in[4];
  const float* Wq   = (const float*)d_in[5];
  const float* Wk   = (const float*)d_in[6];
  const float* Wv   = (const float*)d_in[7];
  const float* Wo   = (const float*)d_in[8];
  const float* bo   = (const float*)d_in[9];
  const float* proj = (const float*)d_in[10];
  const float* ln2g = (const float*)d_in[11];
  const float* ln2b = (const float*)d_in[12];
  const float* W1   = (const float*)d_in[13];
  const float* b1   = (const float*)d_in[14];
  const float* W2   = (const float*)d_in[15];
  const float* b2   = (const float*)d_in[16];
  const float* lnfg = (const float*)d_in[17];
  const float* lnfb = (const float*)d_in[18];
  const float* Wp   = (const float*)d_in[19];
  const float* bp   = (const float*)d_in[20];
  const float* Wc   = (const float*)d_in[21];
  const float* bc   = (const float*)d_in[22];
  float* out = (float*)d_out;

  // ---- workspace layout (bytes), peak 142,000,128 ----
  char* wsb = (char*)d_ws;
  float* h     = (float*)(wsb + 0);                 // 25165824 B fp32
  u16*   ybf   = (u16*)  (wsb + 25165824);          // 12582912 B region (ln out / attn out)
  // early-attn aliases inside ybf region (ln1-out dead after QKV gemm; all dead before PV):
  float* ctxp2 = (float*)(wsb + 25165824);          // 6291456 B (2 partials)
  float* diag  = (float*)(wsb + 31457280);          // 393216 B (K)
  float* diagq = (float*)(wsb + 31850496);          // 393216 B (Q)
  float* ksp   = (float*)(wsb + 32243712);          // 393216 B
  float* fmaxp = (float*)(wsb + 32636928);          // 6144 B
  u16*   projbf= (u16*)  (wsb + 32643072);          // 32768 B (hi)
  u16*   projlo= (u16*)  (wsb + 32675840);          // 32768 B (lo)
  float* stab  = (float*)(wsb + 32708608);          // 256 B
  u16*   qkv   = (u16*)  (wsb + 37748736);          // 37748736 B = [8192][2304] bf16
  u16*   ffnbf = (u16*)  (wsb + 75497472);          // 50331648 B region
  u16*   kp    = (u16*)  (wsb + 75497472);          // alias: kp then qp then ffn
  u16*   qp    = (u16*)  (wsb + 75497472);
  u16*   wT    = (u16*)  (wsb + 125829120);         // 14155776 B
  u16*   ctxT  = (u16*)  (wsb + 139984896);         // 1572864 B
  float* ksum  = (float*)(wsb + 141557760);         // 49152 B
  float* dinv  = (float*)(wsb + 141606912);         // 393216 B -> 142000128
  u16* attnbf  = ybf;

  u16* wtq = wT;                 // [2304][768] stacked q,k,v
  u16* wto = wT + 1769472;
  u16* wt1 = wT + 2359296;       // [3072][768]
  u16* wt2 = wT + 4718592;       // [768][3072]

  embed_kernel<<<2048,256,0,stream>>>(x,(const float4*)tok,(const float4*)pos,(float4*)h);

  dim3 gD(6, 64);               // N=768
  dim3 gQKV(18, 64);            // N=2304
  dim3 gF(24, 64);              // N=3072
  dim3 gQ2(1, 16, BH_);         // PV batched
  dim3 gFG(2, 16, BH_);         // featgemm K
  dim3 gQF(32, BH_);            // qfeatgemm

  for (int l=0; l<DEPTH_; l++){
    const float* wq  = Wq + (size_t)l*DIM_*DIM_;
    const float* wk  = Wk + (size_t)l*DIM_*DIM_;
    const float* wv  = Wv + (size_t)l*DIM_*DIM_;
    const float* wo  = Wo + (size_t)l*DIM_*DIM_;
    const float* prj = proj + (size_t)l*MF_*DH_;
    const float* w1  = W1 + (size_t)l*DIM_*FF_;
    const float* w2  = W2 + (size_t)l*FF_*DIM_;

    tconv_kernel<<<dim3(24,24),256,0,stream>>>(wq, wtq,           768, 768);
    tconv_kernel<<<dim3(24,24),256,0,stream>>>(wk, wtq + 589824,  768, 768);
    tconv_kernel<<<dim3(24,24),256,0,stream>>>(wv, wtq + 1179648, 768, 768);
    tconv_kernel<<<dim3(24,24),256,0,stream>>>(wo, wto, 768, 768);
    tconv_kernel<<<dim3(96,24),256,0,stream>>>(w1, wt1, 768, 3072);
    tconv_kernel<<<dim3(24,96),256,0,stream>>>(w2, wt2, 3072, 768);

    ln_kernel<<<ROWS_,256,0,stream>>>(h, ln1g+(size_t)l*DIM_, ln1b+(size_t)l*DIM_, ybf);
    mgemm<4,4,2,2,0,0,0><<<gQKV,256,0,stream>>>(ybf, wtq, nullptr, qkv, nullptr, ROWS_, QKVW_, 768, QKVW_);

    // ---- K-side FAVOR on MFMA ----
    projcvt_kernel<<<64,256,0,stream>>>(prj, projbf, projlo);
    diag_kernel<<<dim3(8,BH_),256,0,stream>>>(qkv + 768, diag);
    diag_kernel<<<dim3(8,BH_),256,0,stream>>>(qkv, diagq);
    featgemm<0><<<gFG,256,0,stream>>>(qkv + 768, projbf, nullptr, nullptr, nullptr, fmaxp);
    fmax_reduce<<<BH_,64,0,stream>>>(fmaxp, stab);
    featgemm<1><<<gFG,256,0,stream>>>(qkv + 768, projbf, diag, stab, kp, nullptr);
    ctxgemm<<<dim3(2,BH_),256,0,stream>>>(qkv, kp, ctxp2);
    ctx_reduce2<<<768,256,0,stream>>>(ctxp2, ctxT);
    ksum_part_kernel<<<dim3(8,BH_),256,0,stream>>>(kp, ksp);
    ksum_reduce<<<BH_,256,0,stream>>>(ksp, ksum);

    // ---- Q-side on MFMA + PV ----
    qfeatgemm<<<gQF,256,0,stream>>>(qkv, projbf, projlo, diagq, ksum, qp, dinv);
    mgemm<2,4,4,1,0,2,1><<<gQ2,256,0,stream>>>(qp, ctxT, nullptr, attnbf, dinv, SEQ_, 64, 256, 768);

    mgemm<4,4,2,2,0,1,0><<<gD,256,0,stream>>>(attnbf, wto, bo+(size_t)l*DIM_, h, nullptr, ROWS_, 768, 768, 768);

    ln_kernel<<<ROWS_,256,0,stream>>>(h, ln2g+(size_t)l*DIM_, ln2b+(size_t)l*DIM_, ybf);
    mgemm<4,4,2,2,1,0,0><<<gF,256,0,stream>>>(ybf, wt1, b1+(size_t)l*FF_, ffnbf, nullptr, ROWS_, 3072, 768, 3072);
    mgemm<4,4,2,2,0,1,0><<<gD,256,0,stream>>>(ffnbf, wt2, b2+(size_t)l*DIM_, h, nullptr, ROWS_, 768, 3072, 768);
  }

  pooler_kernel<<<B_,256,0,stream>>>(h, lnfg, lnfb, Wp, bp, Wc, bc, out);
}

// Round 8
// 2495.511 us; speedup vs baseline: 10.2949x; 1.1114x over previous
//
#include <hip/hip_runtime.h>
#include <hip/hip_bf16.h>
#include <math.h>

#define B_ 4
#define SEQ_ 2048
#define DIM_ 768
#define DEPTH_ 6
#define HEADS_ 12
#define DH_ 64
#define MF_ 256
#define FF_ 3072
#define ROWS_ 8192
#define BH_ 48
#define QKVW_ 2304
#define DN_ 0.3535533905932738f   /* 64^-0.25 */
#define RATIO_ 0.0625f            /* 256^-0.5 */
#define EPSK_ 1e-4f
#define EPSLN_ 1e-5f

typedef unsigned short u16;
typedef unsigned int   u32;
typedef __bf16 bf16x8 __attribute__((ext_vector_type(8)));
typedef u16    u16x8  __attribute__((ext_vector_type(8)));
typedef float  f32x4  __attribute__((ext_vector_type(4)));

__device__ inline u16 f2bf(float x){
  u32 u = __builtin_bit_cast(u32, x);
  return (u16)((u + 0x7FFFu + ((u>>16)&1u)) >> 16);
}
__device__ inline float bf2f(u16 v){ return __builtin_bit_cast(float, (u32)v<<16); }

__device__ inline void gload16(const u16* g, u16* lds){
  __builtin_amdgcn_global_load_lds(
    (const __attribute__((address_space(1))) u32*)(const void*)g,
    (__attribute__((address_space(3))) u32*)(void*)lds, 16, 0, 0);
}

// ---------------- embedding (h fp32) ----------------
__global__ void embed_kernel(const int* __restrict__ x, const float4* __restrict__ tok,
                             const float4* __restrict__ pos, float4* __restrict__ h){
  const int C4 = DIM_/4;
  long total = (long)ROWS_*C4;
  for (long i = (long)blockIdx.x*blockDim.x + threadIdx.x; i < total;
       i += (long)gridDim.x*blockDim.x){
    int row = (int)(i / C4); int c = (int)(i - (long)row*C4);
    int n = row & (SEQ_-1);
    float4 a = tok[(long)x[row]*C4 + c];
    float4 p = pos[(long)n*C4 + c];
    float4 o; o.x=a.x+p.x; o.y=a.y+p.y; o.z=a.z+p.z; o.w=a.w+p.w;
    h[i] = o;
  }
}

// ---------------- layernorm fp32 -> bf16 ----------------
__global__ __launch_bounds__(256) void ln_kernel(const float* __restrict__ X,
                          const float* __restrict__ g, const float* __restrict__ bta,
                          u16* __restrict__ Y){
  int row = blockIdx.x; int t = threadIdx.x;
  const float* xr = X + (long)row*DIM_;
  float v0 = xr[t], v1 = xr[t+256], v2 = xr[t+512];
  float s = v0+v1+v2;
  float ss = v0*v0+v1*v1+v2*v2;
  int lane = t&63, wid = t>>6;
  #pragma unroll
  for (int off=32; off; off>>=1){ s += __shfl_xor(s,off); ss += __shfl_xor(ss,off); }
  __shared__ float red[8];
  if (lane==0){ red[wid]=s; red[4+wid]=ss; }
  __syncthreads();
  s  = red[0]+red[1]+red[2]+red[3];
  ss = red[4]+red[5]+red[6]+red[7];
  float mu  = s*(1.0f/DIM_);
  float var = ss*(1.0f/DIM_) - mu*mu;
  float rs  = rsqrtf(var + EPSLN_);
  u16* yr = Y + (long)row*DIM_;
  yr[t]     = f2bf((v0-mu)*rs*g[t]     + bta[t]);
  yr[t+256] = f2bf((v1-mu)*rs*g[t+256] + bta[t+256]);
  yr[t+512] = f2bf((v2-mu)*rs*g[t+512] + bta[t+512]);
}

// ---------------- transpose + convert: WT[n][k] = bf16(W[k][n]) ----------------
__global__ __launch_bounds__(256) void tconv_kernel(const float* __restrict__ W,
        u16* __restrict__ WT, int K, int N){
  __shared__ float tile[32][33];
  int n0 = blockIdx.x*32, k0 = blockIdx.y*32;
  int tx = threadIdx.x & 31, ty = threadIdx.x >> 5;
  #pragma unroll
  for (int i=0;i<32;i+=8) tile[ty+i][tx] = W[(long)(k0+ty+i)*N + n0+tx];
  __syncthreads();
  #pragma unroll
  for (int i=0;i<32;i+=8) WT[(long)(n0+ty+i)*K + k0+tx] = f2bf(tile[tx][ty+i]);
}

// 4x 768x768 transposes in one launch (z selects q,k,v,o); dst blocks contiguous
__global__ __launch_bounds__(256) void tconv4_kernel(const float* __restrict__ Wq,
        const float* __restrict__ Wk, const float* __restrict__ Wv,
        const float* __restrict__ Wo, u16* __restrict__ dst){
  __shared__ float tile[32][33];
  int z = blockIdx.z;
  const float* W = (z==0)?Wq:(z==1)?Wk:(z==2)?Wv:Wo;
  u16* WT = dst + (long)z*589824;
  int n0 = blockIdx.x*32, k0 = blockIdx.y*32;
  int tx = threadIdx.x & 31, ty = threadIdx.x >> 5;
  #pragma unroll
  for (int i=0;i<32;i+=8) tile[ty+i][tx] = W[(long)(k0+ty+i)*768 + n0+tx];
  __syncthreads();
  #pragma unroll
  for (int i=0;i<32;i+=8) WT[(long)(n0+ty+i)*768 + k0+tx] = f2bf(tile[tx][ty+i]);
}

// ---------------- MFMA GEMM: C = f(A[M,K]bf16 @ BT[N,K]^T bf16 + bias) ----------------
// CMODE: 0 = bf16 store (+bias,+gelu if ACT); 1 = fp32 C += (+bias); 2 = bf16 store * scale[row]
// BATCH==0: XCD-aware bijective block swizzle (requires gridDim.x*gridDim.y % 8 == 0)
template<int FM, int FN, int WM, int WN, int ACT, int CMODE, int BATCH>
__global__ __launch_bounds__(256) void mgemm(const u16* __restrict__ A,
     const u16* __restrict__ BT, const float* __restrict__ bias,
     void* __restrict__ Cv, const float* __restrict__ scale,
     int M, int N, int K, int ldC){
  (void)M;
  constexpr int BM = WM*FM*16, BN = WN*FN*16;
  constexpr int ACH = BM/16, BCH = BN/16;
  __shared__ u16 As[BM*32];
  __shared__ u16 Bs[BN*32];
  int tid = threadIdx.x; int w = tid>>6, l = tid&63;
  int bx, by;
  if (BATCH){ bx = blockIdx.x; by = blockIdx.y; }
  else {
    int bid = blockIdx.y*gridDim.x + blockIdx.x;
    int cpx = (gridDim.x*gridDim.y) >> 3;
    int swz = (bid & 7)*cpx + (bid >> 3);
    bx = swz % gridDim.x; by = swz / gridDim.x;
  }
  int m0 = by*BM, n0 = bx*BN;
  long coff = 0, srow0 = 0;
  if (BATCH){
    int z = blockIdx.z;
    A  += (long)z*2048*K;
    BT += (long)z*(long)N*K;
    coff  = (long)(z/HEADS_)*SEQ_*(long)ldC + (long)(z%HEADS_)*64;
    srow0 = (long)z*SEQ_;
  }
  f32x4 acc[FM][FN];
  #pragma unroll
  for (int i=0;i<FM;i++)
    #pragma unroll
    for (int j=0;j<FN;j++) acc[i][j] = (f32x4){0.f,0.f,0.f,0.f};

  const int row_l = l>>2, cq_l = l&3;
  const int wm = w / WN, wn = w % WN;
  const int kq = l>>4, rl15 = l&15;

  for (int k0=0; k0<K; k0+=32){
    __syncthreads();
    for (int c = w; c < ACH; c += 4){
      int r = c*16 + row_l;
      int gq = cq_l ^ ((r>>1)&3);
      gload16(A + (long)(m0+r)*K + k0 + gq*8, As + c*512);
    }
    for (int c = w; c < BCH; c += 4){
      int r = c*16 + row_l;
      int gq = cq_l ^ ((r>>1)&3);
      gload16(BT + (long)(n0+r)*K + k0 + gq*8, Bs + c*512);
    }
    __syncthreads();
    bf16x8 af[FM], bfr[FN];
    #pragma unroll
    for (int mi=0; mi<FM; mi++){
      int rr = (wm*FM + mi)*16 + rl15;
      int g = kq ^ ((rr>>1)&3);
      af[mi] = *(const bf16x8*)(As + rr*32 + g*8);
    }
    #pragma unroll
    for (int ni=0; ni<FN; ni++){
      int rr = (wn*FN + ni)*16 + rl15;
      int g = kq ^ ((rr>>1)&3);
      bfr[ni] = *(const bf16x8*)(Bs + rr*32 + g*8);
    }
    #pragma unroll
    for (int mi=0; mi<FM; mi++)
      #pragma unroll
      for (int ni=0; ni<FN; ni++)
        acc[mi][ni] = __builtin_amdgcn_mfma_f32_16x16x32_bf16(af[mi], bfr[ni], acc[mi][ni], 0, 0, 0);
  }

  int cc = l&15, rq = l>>4;
  #pragma unroll
  for (int mi=0; mi<FM; mi++){
    #pragma unroll
    for (int ni=0; ni<FN; ni++){
      int gcol = n0 + (wn*FN+ni)*16 + cc;
      float bv = bias ? bias[gcol] : 0.f;
      #pragma unroll
      for (int r4=0; r4<4; r4++){
        int grow = m0 + (wm*FM+mi)*16 + rq*4 + r4;
        float v = acc[mi][ni][r4] + bv;
        if (ACT) v = 0.5f*v*(1.0f + erff(v*0.70710678118654752f));
        if (CMODE==1){
          float* C = (float*)Cv;
          C[(long)grow*ldC + gcol] += v;
        } else if (CMODE==2){
          v *= scale[srow0 + grow];
          ((u16*)Cv)[coff + (long)grow*ldC + gcol] = f2bf(v);
        } else {
          ((u16*)Cv)[(long)grow*ldC + gcol] = f2bf(v);
        }
      }
    }
  }
}

// ---- projcvt: proj fp32 [256][64] -> bf16 hi + bf16 lo (residual) ----
__global__ void projcvt_kernel(const float* __restrict__ p, u16* __restrict__ hi,
                               u16* __restrict__ lo){
  int i = blockIdx.x*256 + threadIdx.x;   // grid 64 -> 16384
  float v = p[i];
  u16 h = f2bf(v);
  hi[i] = h;
  lo[i] = f2bf(v - bf2f(h));
}

// ---- diag2: z-dim 0 -> Q cols, 1 -> K cols. diag[z][n] = 0.5*DN^2*||row||^2 ----
__global__ __launch_bounds__(256) void diag2_kernel(const u16* __restrict__ qkvp,
        float* __restrict__ diagq, float* __restrict__ diagk){
  int chunk = blockIdx.x, z = blockIdx.y, which = blockIdx.z, t = threadIdx.x;
  const u16* X = qkvp + (which ? 768 : 0);
  float* outp = which ? diagk : diagq;
  int n = chunk*256 + t;
  const u16* r = X + ((long)(z/HEADS_)*SEQ_ + n)*QKVW_ + (z%HEADS_)*DH_;
  float s = 0.f;
  #pragma unroll
  for (int q=0;q<8;q++){
    u16x8 v = *(const u16x8*)(r + q*8);
    #pragma unroll
    for (int j=0;j<8;j++){ float f = bf2f(v[j]); s += f*f; }
  }
  outp[(long)z*SEQ_ + n] = 0.5f*DN_*DN_*s;
}

// ---- FAVOR K feature GEMM (batched per z): xd = K_head[2048x64] @ projbf[256x64]^T
// MODE 0: write per-block max of xd*DN -> fmaxp[z*32 + by*2 + bx]
// MODE 1: kp[z][n][m] = bf16( RATIO*(exp(xd*DN - diag[z][n] - stab[z]) + EPS) )
template<int MODE>
__global__ __launch_bounds__(256) void featgemm(const u16* __restrict__ X,
     const u16* __restrict__ PB, const float* __restrict__ diag,
     const float* __restrict__ stab, u16* __restrict__ kp,
     float* __restrict__ fmaxp){
  __shared__ u16 As[128*32];
  __shared__ u16 Bs[128*32];
  __shared__ float wred[4];
  int tid = threadIdx.x; int w = tid>>6, l = tid&63;
  int n0 = blockIdx.x*128, m0 = blockIdx.y*128;
  int z = blockIdx.z;
  const u16* A = X + (long)(z/HEADS_)*SEQ_*QKVW_ + (z%HEADS_)*DH_;
  f32x4 acc[4][4];
  #pragma unroll
  for (int i=0;i<4;i++)
    #pragma unroll
    for (int j=0;j<4;j++) acc[i][j] = (f32x4){0.f,0.f,0.f,0.f};
  const int row_l = l>>2, cq_l = l&3;
  const int wm = w>>1, wn = w&1;
  const int kq = l>>4, rl15 = l&15;

  for (int k0=0; k0<64; k0+=32){
    __syncthreads();
    for (int c = w; c < 8; c += 4){
      int r = c*16 + row_l;
      int gq = cq_l ^ ((r>>1)&3);
      gload16(A + (long)(m0+r)*QKVW_ + k0 + gq*8, As + c*512);
    }
    for (int c = w; c < 8; c += 4){
      int r = c*16 + row_l;
      int gq = cq_l ^ ((r>>1)&3);
      gload16(PB + (long)(n0+r)*64 + k0 + gq*8, Bs + c*512);
    }
    __syncthreads();
    bf16x8 af[4], bfr[4];
    #pragma unroll
    for (int mi=0; mi<4; mi++){
      int rr = (wm*4 + mi)*16 + rl15;
      int g = kq ^ ((rr>>1)&3);
      af[mi] = *(const bf16x8*)(As + rr*32 + g*8);
    }
    #pragma unroll
    for (int ni=0; ni<4; ni++){
      int rr = (wn*4 + ni)*16 + rl15;
      int g = kq ^ ((rr>>1)&3);
      bfr[ni] = *(const bf16x8*)(Bs + rr*32 + g*8);
    }
    #pragma unroll
    for (int mi=0; mi<4; mi++)
      #pragma unroll
      for (int ni=0; ni<4; ni++)
        acc[mi][ni] = __builtin_amdgcn_mfma_f32_16x16x32_bf16(af[mi], bfr[ni], acc[mi][ni], 0, 0, 0);
  }

  if (MODE==0){
    float bm = -1e30f;
    #pragma unroll
    for (int mi=0;mi<4;mi++)
      #pragma unroll
      for (int ni=0;ni<4;ni++)
        #pragma unroll
        for (int r4=0;r4<4;r4++) bm = fmaxf(bm, acc[mi][ni][r4]);
    bm *= DN_;
    #pragma unroll
    for (int off=32; off; off>>=1) bm = fmaxf(bm, __shfl_xor(bm,off));
    if (l==0) wred[w] = bm;
    __syncthreads();
    if (tid==0)
      fmaxp[z*32 + blockIdx.y*2 + blockIdx.x] =
        fmaxf(fmaxf(wred[0],wred[1]),fmaxf(wred[2],wred[3]));
  } else {
    float st = stab[z];
    int cc = l&15, rq = l>>4;
    #pragma unroll
    for (int mi=0; mi<4; mi++){
      #pragma unroll
      for (int ni=0; ni<4; ni++){
        int gcol = n0 + (wn*4+ni)*16 + cc;
        #pragma unroll
        for (int r4=0; r4<4; r4++){
          int grow = m0 + (wm*4+mi)*16 + rq*4 + r4;
          float v = acc[mi][ni][r4]*DN_;
          float e = RATIO_*(expf(v - diag[(long)z*SEQ_ + grow] - st) + EPSK_);
          kp[((long)z*SEQ_ + grow)*MF_ + gcol] = f2bf(e);
        }
      }
    }
  }
}

__global__ void fmax_reduce(const float* __restrict__ fmaxp, float* __restrict__ stab){
  int z = blockIdx.x, t = threadIdx.x; // 64
  float m = (t<32) ? fmaxp[z*32+t] : -1e30f;
  #pragma unroll
  for (int off=32; off; off>>=1) m = fmaxf(m, __shfl_xor(m,off));
  if (t==0) stab[z] = m;
}

// ---- Q feature GEMM + per-row max + qp + dinv, all in one block (64 rows x 256 m) ----
// hi/lo split proj for near-fp32 argument precision. grid (32, BH_)
__global__ __launch_bounds__(256) void qfeatgemm(const u16* __restrict__ X,
     const u16* __restrict__ PH, const u16* __restrict__ PL,
     const float* __restrict__ diagq, const float* __restrict__ ksum,
     u16* __restrict__ qp, float* __restrict__ dinv){
  __shared__ u16 As[64*32];       // 4 KB
  __shared__ u16 Bh[256*32];      // 16 KB
  __shared__ u16 Bl[256*32];      // 16 KB
  __shared__ float ksl[256];
  __shared__ float rmax[64][4];
  __shared__ float rsum[64][4];
  int tid = threadIdx.x; int w = tid>>6, l = tid&63;
  int n0 = blockIdx.x*64;
  int z = blockIdx.y;
  const u16* A = X + (long)(z/HEADS_)*SEQ_*QKVW_ + (z%HEADS_)*DH_;  // Q cols
  ksl[tid] = ksum[(long)z*MF_ + tid];
  f32x4 acc[4][4];
  #pragma unroll
  for (int i=0;i<4;i++)
    #pragma unroll
    for (int j=0;j<4;j++) acc[i][j] = (f32x4){0.f,0.f,0.f,0.f};
  const int row_l = l>>2, cq_l = l&3;
  const int kq = l>>4, rl15 = l&15;

  for (int k0=0; k0<64; k0+=32){
    __syncthreads();
    { // A: 4 chunks of 16 rows, one per wave
      int r = w*16 + row_l;
      int gq = cq_l ^ ((r>>1)&3);
      gload16(A + (long)(n0+r)*QKVW_ + k0 + gq*8, As + w*512);
    }
    for (int c = w; c < 16; c += 4){
      int r = c*16 + row_l;
      int gq = cq_l ^ ((r>>1)&3);
      gload16(PH + (long)r*64 + k0 + gq*8, Bh + c*512);
      gload16(PL + (long)r*64 + k0 + gq*8, Bl + c*512);
    }
    __syncthreads();
    bf16x8 af[4], bh[4], bl[4];
    #pragma unroll
    for (int mi=0; mi<4; mi++){
      int rr = mi*16 + rl15;
      int g = kq ^ ((rr>>1)&3);
      af[mi] = *(const bf16x8*)(As + rr*32 + g*8);
    }
    #pragma unroll
    for (int ni=0; ni<4; ni++){
      int rr = (w*4 + ni)*16 + rl15;
      int g = kq ^ ((rr>>1)&3);
      bh[ni] = *(const bf16x8*)(Bh + rr*32 + g*8);
      bl[ni] = *(const bf16x8*)(Bl + rr*32 + g*8);
    }
    #pragma unroll
    for (int mi=0; mi<4; mi++)
      #pragma unroll
      for (int ni=0; ni<4; ni++){
        acc[mi][ni] = __builtin_amdgcn_mfma_f32_16x16x32_bf16(af[mi], bh[ni], acc[mi][ni], 0, 0, 0);
        acc[mi][ni] = __builtin_amdgcn_mfma_f32_16x16x32_bf16(af[mi], bl[ni], acc[mi][ni], 0, 0, 0);
      }
  }

  int cc = l&15, rq = l>>4;
  // per-row max over all 256 m
  #pragma unroll
  for (int mi=0; mi<4; mi++){
    #pragma unroll
    for (int r4=0; r4<4; r4++){
      float pm = fmaxf(fmaxf(acc[mi][0][r4],acc[mi][1][r4]),
                       fmaxf(acc[mi][2][r4],acc[mi][3][r4]));
      pm = fmaxf(pm, __shfl_xor(pm,1)); pm = fmaxf(pm, __shfl_xor(pm,2));
      pm = fmaxf(pm, __shfl_xor(pm,4)); pm = fmaxf(pm, __shfl_xor(pm,8));
      if (cc==0) rmax[mi*16 + rq*4 + r4][w] = pm;
    }
  }
  __syncthreads();
  #pragma unroll
  for (int mi=0; mi<4; mi++){
    #pragma unroll
    for (int r4=0; r4<4; r4++){
      int row = mi*16 + rq*4 + r4;
      float mx = fmaxf(fmaxf(rmax[row][0],rmax[row][1]),
                       fmaxf(rmax[row][2],rmax[row][3])) * DN_;
      float dq = diagq[(long)z*SEQ_ + n0 + row];
      float dv = 0.f;
      #pragma unroll
      for (int ni=0; ni<4; ni++){
        int col = w*64 + ni*16 + cc;
        float qpv = RATIO_*(expf(acc[mi][ni][r4]*DN_ - dq - mx) + EPSK_);
        u16 qb = f2bf(qpv);
        qp[((long)z*SEQ_ + n0 + row)*MF_ + col] = qb;
        dv += bf2f(qb)*ksl[col];
      }
      dv += __shfl_xor(dv,1); dv += __shfl_xor(dv,2);
      dv += __shfl_xor(dv,4); dv += __shfl_xor(dv,8);
      if (cc==0) rsum[row][w] = dv;
    }
  }
  __syncthreads();
  if (tid < 64){
    float s = rsum[tid][0]+rsum[tid][1]+rsum[tid][2]+rsum[tid][3];
    dinv[(long)z*SEQ_ + n0 + tid] = 1.0f/s;
  }
}

// ---- ctxgemm: ctxT-partial[d=64][m=256] = sum_n V[n][d]*kp[n][m] (TN, transpose-on-stage)
__global__ __launch_bounds__(256) void ctxgemm(const u16* __restrict__ qkv,
     const u16* __restrict__ kp, float* __restrict__ part){
  int kc = blockIdx.x;      // 0..1 (1024 rows each)
  int z  = blockIdx.y;
  int b = z/HEADS_, hh = z%HEADS_;
  int tid = threadIdx.x; int w = tid>>6, l = tid&63;
  __shared__ u16 Vt[64*40];
  __shared__ u16 Kpt[256*40];
  f32x4 acc[4][4];
  #pragma unroll
  for (int i=0;i<4;i++)
    #pragma unroll
    for (int j=0;j<4;j++) acc[i][j] = (f32x4){0.f,0.f,0.f,0.f};
  int n_l = tid&31, grp = tid>>5;
  const int kq = l>>4, rl15 = l&15;
  const long vbase = (long)b*SEQ_*QKVW_ + hh*DH_ + 1536;
  const long kbase = (long)z*SEQ_*MF_;

  for (int s=0; s<32; s++){
    int nG = kc*1024 + s*32 + n_l;
    __syncthreads();
    {
      u16x8 v = *(const u16x8*)(qkv + vbase + (long)nG*QKVW_ + grp*8);
      #pragma unroll
      for (int j=0;j<8;j++) Vt[(grp*8+j)*40 + n_l] = v[j];
    }
    {
      const u16* src = kp + kbase + (long)nG*MF_ + grp*32;
      #pragma unroll
      for (int q=0;q<4;q++){
        u16x8 v = *(const u16x8*)(src + q*8);
        #pragma unroll
        for (int j=0;j<8;j++) Kpt[(grp*32+q*8+j)*40 + n_l] = v[j];
      }
    }
    __syncthreads();
    bf16x8 af[4], bfr[4];
    #pragma unroll
    for (int mi=0; mi<4; mi++)
      af[mi] = *(const bf16x8*)(Vt + (mi*16+rl15)*40 + kq*8);
    #pragma unroll
    for (int ni=0; ni<4; ni++)
      bfr[ni] = *(const bf16x8*)(Kpt + ((w*4+ni)*16+rl15)*40 + kq*8);
    #pragma unroll
    for (int mi=0; mi<4; mi++)
      #pragma unroll
      for (int ni=0; ni<4; ni++)
        acc[mi][ni] = __builtin_amdgcn_mfma_f32_16x16x32_bf16(af[mi], bfr[ni], acc[mi][ni], 0, 0, 0);
  }

  int cc = l&15, rq = l>>4;
  float* pb = part + ((long)kc*BH_ + z)*(64*MF_);
  #pragma unroll
  for (int mi=0; mi<4; mi++){
    #pragma unroll
    for (int ni=0; ni<4; ni++){
      int m = (w*4+ni)*16 + cc;
      #pragma unroll
      for (int r4=0; r4<4; r4++){
        int d = mi*16 + rq*4 + r4;
        pb[(long)d*MF_ + m] = acc[mi][ni][r4];
      }
    }
  }
}

// reduce 2 ctx partials -> ctxT bf16 [z][d][m]
__global__ void ctx_reduce2(const float* __restrict__ part, u16* __restrict__ ctxT){
  const long NT = (long)BH_*64*MF_; // 786432
  for (long i = (long)blockIdx.x*256 + threadIdx.x; i < NT; i += (long)gridDim.x*256){
    ctxT[i] = f2bf(part[i] + part[NT + i]);
  }
}

// ---- ksum: column sums of kp ----
__global__ void ksum_part_kernel(const u16* __restrict__ kp, float* __restrict__ ksp){
  int kc = blockIdx.x, z = blockIdx.y, t = threadIdx.x;
  const u16* base = kp + ((long)z*SEQ_ + kc*256)*MF_ + t;
  float s = 0.f;
  for (int n=0;n<256;n++) s += bf2f(base[(long)n*MF_]);
  ksp[(z*8+kc)*MF_ + t] = s;
}

__global__ void ksum_reduce(const float* __restrict__ part, float* __restrict__ ksum){
  int z = blockIdx.x; int t = threadIdx.x;
  float s = 0.f;
  #pragma unroll
  for (int c=0;c<8;c++) s += part[(z*8+c)*MF_ + t];
  ksum[z*MF_+t] = s;
}

// ---------------- final LN(row0) + pooler + classifier ----------------
__global__ __launch_bounds__(256) void pooler_kernel(const float* __restrict__ h,
                           const float* __restrict__ g, const float* __restrict__ bta,
                           const float* __restrict__ Wp, const float* __restrict__ bp,
                           const float* __restrict__ Wc, const float* __restrict__ bc,
                           float* __restrict__ out){
  int b = blockIdx.x, t = threadIdx.x;
  __shared__ float xn[768];
  __shared__ float pl[768];
  __shared__ float red[8];
  const float* row = h + (long)b*SEQ_*DIM_;
  float v0=row[t], v1=row[t+256], v2=row[t+512];
  float s = v0+v1+v2, ss = v0*v0+v1*v1+v2*v2;
  int lane=t&63, wid=t>>6;
  #pragma unroll
  for (int off=32; off; off>>=1){ s += __shfl_xor(s,off); ss += __shfl_xor(ss,off); }
  if (lane==0){ red[wid]=s; red[4+wid]=ss; }
  __syncthreads();
  s  = red[0]+red[1]+red[2]+red[3];
  ss = red[4]+red[5]+red[6]+red[7];
  float mu = s*(1.0f/DIM_);
  float var = ss*(1.0f/DIM_) - mu*mu;
  float rs = rsqrtf(var + EPSLN_);
  xn[t]     = (v0-mu)*rs*g[t]     + bta[t];
  xn[t+256] = (v1-mu)*rs*g[t+256] + bta[t+256];
  xn[t+512] = (v2-mu)*rs*g[t+512] + bta[t+512];
  __syncthreads();
  #pragma unroll
  for (int jj=0;jj<3;jj++){
    int j = t + jj*256;
    float a = bp[j];
    for (int i=0;i<768;i++) a += xn[i]*Wp[(long)i*DIM_ + j];
    pl[j] = tanhf(a);
  }
  __syncthreads();
  if (wid < 2){
    float a = 0.f;
    for (int i=lane;i<768;i+=64) a += pl[i]*Wc[i*2+wid];
    #pragma unroll
    for (int off=32; off; off>>=1) a += __shfl_xor(a,off);
    if (lane==0) out[b*2+wid] = a + bc[wid];
  }
}

extern "C" void kernel_launch(void* const* d_in, const int* in_sizes, int n_in,
                              void* d_out, int out_size, void* d_ws, size_t ws_size,
                              hipStream_t stream) {
  (void)in_sizes; (void)n_in; (void)out_size; (void)ws_size;
  const int*   x    = (const int*)  d_in[0];
  const float* tok  = (const float*)d_in[1];
  const float* pos  = (const float*)d_in[2];
  const float* ln1g = (const float*)d_in[3];
  const float* ln1b = (const float*)d_in[4];
  const float* Wq   = (const float*)d_in[5];
  const float* Wk   = (const float*)d_in[6];
  const float* Wv   = (const float*)d_in[7];
  const float* Wo   = (const float*)d_in[8];
  const float* bo   = (const float*)d_in[9];
  const float* proj = (const float*)d_in[10];
  const float* ln2g = (const float*)d_in[11];
  const float* ln2b = (const float*)d_in[12];
  const float* W1   = (const float*)d_in[13];
  const float* b1   = (const float*)d_in[14];
  const float* W2   = (const float*)d_in[15];
  const float* b2   = (const float*)d_in[16];
  const float* lnfg = (const float*)d_in[17];
  const float* lnfb = (const float*)d_in[18];
  const float* Wp   = (const float*)d_in[19];
  const float* bp   = (const float*)d_in[20];
  const float* Wc   = (const float*)d_in[21];
  const float* bc   = (const float*)d_in[22];
  float* out = (float*)d_out;

  // ---- workspace layout (bytes), peak 142,000,128 ----
  char* wsb = (char*)d_ws;
  float* h     = (float*)(wsb + 0);                 // 25165824 B fp32
  u16*   ybf   = (u16*)  (wsb + 25165824);          // 12582912 B region (ln out / attn out)
  // early-attn aliases inside ybf region (ln1-out dead after QKV gemm; all dead before PV):
  float* ctxp2 = (float*)(wsb + 25165824);          // 6291456 B (2 partials)
  float* diag  = (float*)(wsb + 31457280);          // 393216 B (K)
  float* diagq = (float*)(wsb + 31850496);          // 393216 B (Q)
  float* ksp   = (float*)(wsb + 32243712);          // 393216 B
  float* fmaxp = (float*)(wsb + 32636928);          // 6144 B
  u16*   projbf= (u16*)  (wsb + 32643072);          // 32768 B (hi)
  u16*   projlo= (u16*)  (wsb + 32675840);          // 32768 B (lo)
  float* stab  = (float*)(wsb + 32708608);          // 256 B
  u16*   qkv   = (u16*)  (wsb + 37748736);          // 37748736 B = [8192][2304] bf16
  u16*   ffnbf = (u16*)  (wsb + 75497472);          // 50331648 B region
  u16*   kp    = (u16*)  (wsb + 75497472);          // alias: kp then qp then ffn
  u16*   qp    = (u16*)  (wsb + 75497472);
  u16*   wT    = (u16*)  (wsb + 125829120);         // 14155776 B
  u16*   ctxT  = (u16*)  (wsb + 139984896);         // 1572864 B
  float* ksum  = (float*)(wsb + 141557760);         // 49152 B
  float* dinv  = (float*)(wsb + 141606912);         // 393216 B -> 142000128
  u16* attnbf  = ybf;

  u16* wtq = wT;                 // [2304][768] stacked q,k,v (+o right after)
  u16* wto = wT + 1769472;
  u16* wt1 = wT + 2359296;       // [3072][768]
  u16* wt2 = wT + 4718592;       // [768][3072]
  (void)wto;

  embed_kernel<<<2048,256,0,stream>>>(x,(const float4*)tok,(const float4*)pos,(float4*)h);

  dim3 gD64(6, 128);            // N=768, 64-row tiles (FFN2 / Wo)
  dim3 gQKV(18, 64);            // N=2304
  dim3 gF(24, 64);              // N=3072
  dim3 gQ2(1, 16, BH_);         // PV batched
  dim3 gFG(2, 16, BH_);         // featgemm K
  dim3 gQF(32, BH_);            // qfeatgemm

  for (int l=0; l<DEPTH_; l++){
    const float* wq  = Wq + (size_t)l*DIM_*DIM_;
    const float* wk  = Wk + (size_t)l*DIM_*DIM_;
    const float* wv  = Wv + (size_t)l*DIM_*DIM_;
    const float* wo  = Wo + (size_t)l*DIM_*DIM_;
    const float* prj = proj + (size_t)l*MF_*DH_;
    const float* w1  = W1 + (size_t)l*DIM_*FF_;
    const float* w2  = W2 + (size_t)l*FF_*DIM_;

    tconv4_kernel<<<dim3(24,24,4),256,0,stream>>>(wq, wk, wv, wo, wtq);
    tconv_kernel<<<dim3(96,24),256,0,stream>>>(w1, wt1, 768, 3072);
    tconv_kernel<<<dim3(24,96),256,0,stream>>>(w2, wt2, 3072, 768);

    ln_kernel<<<ROWS_,256,0,stream>>>(h, ln1g+(size_t)l*DIM_, ln1b+(size_t)l*DIM_, ybf);
    mgemm<4,4,2,2,0,0,0><<<gQKV,256,0,stream>>>(ybf, wtq, nullptr, qkv, nullptr, ROWS_, QKVW_, 768, QKVW_);

    // ---- K-side FAVOR on MFMA ----
    projcvt_kernel<<<64,256,0,stream>>>(prj, projbf, projlo);
    diag2_kernel<<<dim3(8,BH_,2),256,0,stream>>>(qkv, diagq, diag);
    featgemm<0><<<gFG,256,0,stream>>>(qkv + 768, projbf, nullptr, nullptr, nullptr, fmaxp);
    fmax_reduce<<<BH_,64,0,stream>>>(fmaxp, stab);
    featgemm<1><<<gFG,256,0,stream>>>(qkv + 768, projbf, diag, stab, kp, nullptr);
    ctxgemm<<<dim3(2,BH_),256,0,stream>>>(qkv, kp, ctxp2);
    ctx_reduce2<<<768,256,0,stream>>>(ctxp2, ctxT);
    ksum_part_kernel<<<dim3(8,BH_),256,0,stream>>>(kp, ksp);
    ksum_reduce<<<BH_,256,0,stream>>>(ksp, ksum);

    // ---- Q-side on MFMA + PV ----
    qfeatgemm<<<gQF,256,0,stream>>>(qkv, projbf, projlo, diagq, ksum, qp, dinv);
    mgemm<2,4,4,1,0,2,1><<<gQ2,256,0,stream>>>(qp, ctxT, nullptr, attnbf, dinv, SEQ_, 64, 256, 768);

    mgemm<2,4,2,2,0,1,0><<<gD64,256,0,stream>>>(attnbf, wto, bo+(size_t)l*DIM_, h, nullptr, ROWS_, 768, 768, 768);

    ln_kernel<<<ROWS_,256,0,stream>>>(h, ln2g+(size_t)l*DIM_, ln2b+(size_t)l*DIM_, ybf);
    mgemm<4,4,2,2,1,0,0><<<gF,256,0,stream>>>(ybf, wt1, b1+(size_t)l*FF_, ffnbf, nullptr, ROWS_, 3072, 768, 3072);
    mgemm<2,4,2,2,0,1,0><<<gD64,256,0,stream>>>(ffnbf, wt2, b2+(size_t)l*DIM_, h, nullptr, ROWS_, 768, 3072, 768);
  }

  pooler_kernel<<<B_,256,0,stream>>>(h, lnfg, lnfb, Wp, bp, Wc, bc, out);
}

// Round 9
// 2411.406 us; speedup vs baseline: 10.6539x; 1.0349x over previous
//
#include <hip/hip_runtime.h>
#include <hip/hip_bf16.h>
#include <math.h>

#define B_ 4
#define SEQ_ 2048
#define DIM_ 768
#define DEPTH_ 6
#define HEADS_ 12
#define DH_ 64
#define MF_ 256
#define FF_ 3072
#define ROWS_ 8192
#define BH_ 48
#define QKVW_ 2304
#define DN_ 0.3535533905932738f   /* 64^-0.25 */
#define RATIO_ 0.0625f            /* 256^-0.5 */
#define EPSK_ 1e-4f
#define EPSLN_ 1e-5f

typedef unsigned short u16;
typedef unsigned int   u32;
typedef __bf16 bf16x8 __attribute__((ext_vector_type(8)));
typedef u16    u16x8  __attribute__((ext_vector_type(8)));
typedef float  f32x4  __attribute__((ext_vector_type(4)));

__device__ inline u16 f2bf(float x){
  u32 u = __builtin_bit_cast(u32, x);
  return (u16)((u + 0x7FFFu + ((u>>16)&1u)) >> 16);
}
__device__ inline float bf2f(u16 v){ return __builtin_bit_cast(float, (u32)v<<16); }

__device__ inline void gload16(const u16* g, u16* lds){
  __builtin_amdgcn_global_load_lds(
    (const __attribute__((address_space(1))) u32*)(const void*)g,
    (__attribute__((address_space(3))) u32*)(void*)lds, 16, 0, 0);
}

// ---------------- embedding (h fp32) ----------------
__global__ void embed_kernel(const int* __restrict__ x, const float4* __restrict__ tok,
                             const float4* __restrict__ pos, float4* __restrict__ h){
  const int C4 = DIM_/4;
  long total = (long)ROWS_*C4;
  for (long i = (long)blockIdx.x*blockDim.x + threadIdx.x; i < total;
       i += (long)gridDim.x*blockDim.x){
    int row = (int)(i / C4); int c = (int)(i - (long)row*C4);
    int n = row & (SEQ_-1);
    float4 a = tok[(long)x[row]*C4 + c];
    float4 p = pos[(long)n*C4 + c];
    float4 o; o.x=a.x+p.x; o.y=a.y+p.y; o.z=a.z+p.z; o.w=a.w+p.w;
    h[i] = o;
  }
}

// ---------------- layernorm fp32 -> bf16 ----------------
__global__ __launch_bounds__(256) void ln_kernel(const float* __restrict__ X,
                          const float* __restrict__ g, const float* __restrict__ bta,
                          u16* __restrict__ Y){
  int row = blockIdx.x; int t = threadIdx.x;
  const float* xr = X + (long)row*DIM_;
  float v0 = xr[t], v1 = xr[t+256], v2 = xr[t+512];
  float s = v0+v1+v2;
  float ss = v0*v0+v1*v1+v2*v2;
  int lane = t&63, wid = t>>6;
  #pragma unroll
  for (int off=32; off; off>>=1){ s += __shfl_xor(s,off); ss += __shfl_xor(ss,off); }
  __shared__ float red[8];
  if (lane==0){ red[wid]=s; red[4+wid]=ss; }
  __syncthreads();
  s  = red[0]+red[1]+red[2]+red[3];
  ss = red[4]+red[5]+red[6]+red[7];
  float mu  = s*(1.0f/DIM_);
  float var = ss*(1.0f/DIM_) - mu*mu;
  float rs  = rsqrtf(var + EPSLN_);
  u16* yr = Y + (long)row*DIM_;
  yr[t]     = f2bf((v0-mu)*rs*g[t]     + bta[t]);
  yr[t+256] = f2bf((v1-mu)*rs*g[t+256] + bta[t+256]);
  yr[t+512] = f2bf((v2-mu)*rs*g[t+512] + bta[t+512]);
}

// ---------------- transpose + convert: WT[n][k] = bf16(W[k][n]) ----------------
__global__ __launch_bounds__(256) void tconv_kernel(const float* __restrict__ W,
        u16* __restrict__ WT, int K, int N){
  __shared__ float tile[32][33];
  int n0 = blockIdx.x*32, k0 = blockIdx.y*32;
  int tx = threadIdx.x & 31, ty = threadIdx.x >> 5;
  #pragma unroll
  for (int i=0;i<32;i+=8) tile[ty+i][tx] = W[(long)(k0+ty+i)*N + n0+tx];
  __syncthreads();
  #pragma unroll
  for (int i=0;i<32;i+=8) WT[(long)(n0+ty+i)*K + k0+tx] = f2bf(tile[tx][ty+i]);
}

// 4x 768x768 transposes in one launch (z selects q,k,v,o); dst blocks contiguous
__global__ __launch_bounds__(256) void tconv4_kernel(const float* __restrict__ Wq,
        const float* __restrict__ Wk, const float* __restrict__ Wv,
        const float* __restrict__ Wo, u16* __restrict__ dst){
  __shared__ float tile[32][33];
  int z = blockIdx.z;
  const float* W = (z==0)?Wq:(z==1)?Wk:(z==2)?Wv:Wo;
  u16* WT = dst + (long)z*589824;
  int n0 = blockIdx.x*32, k0 = blockIdx.y*32;
  int tx = threadIdx.x & 31, ty = threadIdx.x >> 5;
  #pragma unroll
  for (int i=0;i<32;i+=8) tile[ty+i][tx] = W[(long)(k0+ty+i)*768 + n0+tx];
  __syncthreads();
  #pragma unroll
  for (int i=0;i<32;i+=8) WT[(long)(n0+ty+i)*768 + k0+tx] = f2bf(tile[tx][ty+i]);
}

// ---------------- MFMA GEMM: C = f(A[M,K]bf16 @ BT[N,K]^T bf16 + bias) ----------------
// CMODE: 0 = bf16 store (+bias,+gelu if ACT); 1 = fp32 C += (+bias); 2 = bf16 store * scale[row]
// BATCH==0: XCD-aware bijective block swizzle (requires gridDim.x*gridDim.y % 8 == 0)
template<int FM, int FN, int WM, int WN, int ACT, int CMODE, int BATCH>
__global__ __launch_bounds__(256) void mgemm(const u16* __restrict__ A,
     const u16* __restrict__ BT, const float* __restrict__ bias,
     void* __restrict__ Cv, const float* __restrict__ scale,
     int M, int N, int K, int ldC){
  (void)M;
  constexpr int BM = WM*FM*16, BN = WN*FN*16;
  constexpr int ACH = BM/16, BCH = BN/16;
  __shared__ u16 As[BM*32];
  __shared__ u16 Bs[BN*32];
  int tid = threadIdx.x; int w = tid>>6, l = tid&63;
  int bx, by;
  if (BATCH){ bx = blockIdx.x; by = blockIdx.y; }
  else {
    int bid = blockIdx.y*gridDim.x + blockIdx.x;
    int cpx = (gridDim.x*gridDim.y) >> 3;
    int swz = (bid & 7)*cpx + (bid >> 3);
    bx = swz % gridDim.x; by = swz / gridDim.x;
  }
  int m0 = by*BM, n0 = bx*BN;
  long coff = 0, srow0 = 0;
  if (BATCH){
    int z = blockIdx.z;
    A  += (long)z*2048*K;
    BT += (long)z*(long)N*K;
    coff  = (long)(z/HEADS_)*SEQ_*(long)ldC + (long)(z%HEADS_)*64;
    srow0 = (long)z*SEQ_;
  }
  f32x4 acc[FM][FN];
  #pragma unroll
  for (int i=0;i<FM;i++)
    #pragma unroll
    for (int j=0;j<FN;j++) acc[i][j] = (f32x4){0.f,0.f,0.f,0.f};

  const int row_l = l>>2, cq_l = l&3;
  const int wm = w / WN, wn = w % WN;
  const int kq = l>>4, rl15 = l&15;

  for (int k0=0; k0<K; k0+=32){
    __syncthreads();
    for (int c = w; c < ACH; c += 4){
      int r = c*16 + row_l;
      int gq = cq_l ^ ((r>>1)&3);
      gload16(A + (long)(m0+r)*K + k0 + gq*8, As + c*512);
    }
    for (int c = w; c < BCH; c += 4){
      int r = c*16 + row_l;
      int gq = cq_l ^ ((r>>1)&3);
      gload16(BT + (long)(n0+r)*K + k0 + gq*8, Bs + c*512);
    }
    __syncthreads();
    bf16x8 af[FM], bfr[FN];
    #pragma unroll
    for (int mi=0; mi<FM; mi++){
      int rr = (wm*FM + mi)*16 + rl15;
      int g = kq ^ ((rr>>1)&3);
      af[mi] = *(const bf16x8*)(As + rr*32 + g*8);
    }
    #pragma unroll
    for (int ni=0; ni<FN; ni++){
      int rr = (wn*FN + ni)*16 + rl15;
      int g = kq ^ ((rr>>1)&3);
      bfr[ni] = *(const bf16x8*)(Bs + rr*32 + g*8);
    }
    #pragma unroll
    for (int mi=0; mi<FM; mi++)
      #pragma unroll
      for (int ni=0; ni<FN; ni++)
        acc[mi][ni] = __builtin_amdgcn_mfma_f32_16x16x32_bf16(af[mi], bfr[ni], acc[mi][ni], 0, 0, 0);
  }

  int cc = l&15, rq = l>>4;
  #pragma unroll
  for (int mi=0; mi<FM; mi++){
    #pragma unroll
    for (int ni=0; ni<FN; ni++){
      int gcol = n0 + (wn*FN+ni)*16 + cc;
      float bv = bias ? bias[gcol] : 0.f;
      #pragma unroll
      for (int r4=0; r4<4; r4++){
        int grow = m0 + (wm*FM+mi)*16 + rq*4 + r4;
        float v = acc[mi][ni][r4] + bv;
        if (ACT) v = 0.5f*v*(1.0f + erff(v*0.70710678118654752f));
        if (CMODE==1){
          float* C = (float*)Cv;
          C[(long)grow*ldC + gcol] += v;
        } else if (CMODE==2){
          v *= scale[srow0 + grow];
          ((u16*)Cv)[coff + (long)grow*ldC + gcol] = f2bf(v);
        } else {
          ((u16*)Cv)[(long)grow*ldC + gcol] = f2bf(v);
        }
      }
    }
  }
}

// ---- projcvt: proj fp32 [256][64] -> bf16 hi + bf16 lo (residual) ----
__global__ void projcvt_kernel(const float* __restrict__ p, u16* __restrict__ hi,
                               u16* __restrict__ lo){
  int i = blockIdx.x*256 + threadIdx.x;   // grid 64 -> 16384
  float v = p[i];
  u16 h = f2bf(v);
  hi[i] = h;
  lo[i] = f2bf(v - bf2f(h));
}

// ---- diag2: z-dim 0 -> Q cols, 1 -> K cols. diag[z][n] = 0.5*DN^2*||row||^2 ----
__global__ __launch_bounds__(256) void diag2_kernel(const u16* __restrict__ qkvp,
        float* __restrict__ diagq, float* __restrict__ diagk){
  int chunk = blockIdx.x, z = blockIdx.y, which = blockIdx.z, t = threadIdx.x;
  const u16* X = qkvp + (which ? 768 : 0);
  float* outp = which ? diagk : diagq;
  int n = chunk*256 + t;
  const u16* r = X + ((long)(z/HEADS_)*SEQ_ + n)*QKVW_ + (z%HEADS_)*DH_;
  float s = 0.f;
  #pragma unroll
  for (int q=0;q<8;q++){
    u16x8 v = *(const u16x8*)(r + q*8);
    #pragma unroll
    for (int j=0;j<8;j++){ float f = bf2f(v[j]); s += f*f; }
  }
  outp[(long)z*SEQ_ + n] = 0.5f*DN_*DN_*s;
}

// ---- FAVOR K feature GEMM (batched per z): xd = K_head[2048x64] @ projbf[256x64]^T
// MODE 0: write per-block max of xd*DN -> fmaxp[z*32 + by*2 + bx]
// MODE 1: kp[z][n][m] = bf16( RATIO*(exp(xd*DN - diag[z][n] - stab[z]) + EPS) )
//         + ksum partials: ksp[(z*16+by)*256 + col] = sum over block's 128 rows
template<int MODE>
__global__ __launch_bounds__(256) void featgemm(const u16* __restrict__ X,
     const u16* __restrict__ PB, const float* __restrict__ diag,
     const float* __restrict__ stab, u16* __restrict__ kp,
     float* __restrict__ fmaxp){
  __shared__ u16 As[128*32];
  __shared__ u16 Bs[128*32];
  __shared__ float wred[4];
  int tid = threadIdx.x; int w = tid>>6, l = tid&63;
  int n0 = blockIdx.x*128, m0 = blockIdx.y*128;
  int z = blockIdx.z;
  const u16* A = X + (long)(z/HEADS_)*SEQ_*QKVW_ + (z%HEADS_)*DH_;
  f32x4 acc[4][4];
  #pragma unroll
  for (int i=0;i<4;i++)
    #pragma unroll
    for (int j=0;j<4;j++) acc[i][j] = (f32x4){0.f,0.f,0.f,0.f};
  const int row_l = l>>2, cq_l = l&3;
  const int wm = w>>1, wn = w&1;
  const int kq = l>>4, rl15 = l&15;

  for (int k0=0; k0<64; k0+=32){
    __syncthreads();
    for (int c = w; c < 8; c += 4){
      int r = c*16 + row_l;
      int gq = cq_l ^ ((r>>1)&3);
      gload16(A + (long)(m0+r)*QKVW_ + k0 + gq*8, As + c*512);
    }
    for (int c = w; c < 8; c += 4){
      int r = c*16 + row_l;
      int gq = cq_l ^ ((r>>1)&3);
      gload16(PB + (long)(n0+r)*64 + k0 + gq*8, Bs + c*512);
    }
    __syncthreads();
    bf16x8 af[4], bfr[4];
    #pragma unroll
    for (int mi=0; mi<4; mi++){
      int rr = (wm*4 + mi)*16 + rl15;
      int g = kq ^ ((rr>>1)&3);
      af[mi] = *(const bf16x8*)(As + rr*32 + g*8);
    }
    #pragma unroll
    for (int ni=0; ni<4; ni++){
      int rr = (wn*4 + ni)*16 + rl15;
      int g = kq ^ ((rr>>1)&3);
      bfr[ni] = *(const bf16x8*)(Bs + rr*32 + g*8);
    }
    #pragma unroll
    for (int mi=0; mi<4; mi++)
      #pragma unroll
      for (int ni=0; ni<4; ni++)
        acc[mi][ni] = __builtin_amdgcn_mfma_f32_16x16x32_bf16(af[mi], bfr[ni], acc[mi][ni], 0, 0, 0);
  }

  if (MODE==0){
    float bm = -1e30f;
    #pragma unroll
    for (int mi=0;mi<4;mi++)
      #pragma unroll
      for (int ni=0;ni<4;ni++)
        #pragma unroll
        for (int r4=0;r4<4;r4++) bm = fmaxf(bm, acc[mi][ni][r4]);
    bm *= DN_;
    #pragma unroll
    for (int off=32; off; off>>=1) bm = fmaxf(bm, __shfl_xor(bm,off));
    if (l==0) wred[w] = bm;
    __syncthreads();
    if (tid==0)
      fmaxp[z*32 + blockIdx.y*2 + blockIdx.x] =
        fmaxf(fmaxf(wred[0],wred[1]),fmaxf(wred[2],wred[3]));
  } else {
    __shared__ float ksred[128][8];
    float st = stab[z];
    int cc = l&15, rq = l>>4;
    #pragma unroll
    for (int ni=0; ni<4; ni++){
      int gcol = n0 + (wn*4+ni)*16 + cc;
      float cs = 0.f;
      #pragma unroll
      for (int mi=0; mi<4; mi++){
        #pragma unroll
        for (int r4=0; r4<4; r4++){
          int grow = m0 + (wm*4+mi)*16 + rq*4 + r4;
          float v = acc[mi][ni][r4]*DN_;
          float e = RATIO_*(expf(v - diag[(long)z*SEQ_ + grow] - st) + EPSK_);
          u16 eb = f2bf(e);
          kp[((long)z*SEQ_ + grow)*MF_ + gcol] = eb;
          cs += bf2f(eb);
        }
      }
      ksred[(wn*4+ni)*16 + cc][wm*4 + rq] = cs;
    }
    __syncthreads();
    if (tid < 128){
      float s = 0.f;
      #pragma unroll
      for (int q=0;q<8;q++) s += ksred[tid][q];
      // fmaxp here is reused as ksp partial buffer in MODE 1 launch args
      fmaxp[((long)z*16 + blockIdx.y)*MF_ + n0 + tid] = s;
    }
  }
}

__global__ void fmax_reduce(const float* __restrict__ fmaxp, float* __restrict__ stab){
  int z = blockIdx.x, t = threadIdx.x; // 64
  float m = (t<32) ? fmaxp[z*32+t] : -1e30f;
  #pragma unroll
  for (int off=32; off; off>>=1) m = fmaxf(m, __shfl_xor(m,off));
  if (t==0) stab[z] = m;
}

__global__ void ksum_reduce(const float* __restrict__ part, float* __restrict__ ksum){
  int z = blockIdx.x; int t = threadIdx.x;
  float s = 0.f;
  #pragma unroll
  for (int c=0;c<16;c++) s += part[((long)z*16+c)*MF_ + t];
  ksum[z*MF_+t] = s;
}

// ---- Q feature GEMM + per-row max + qp + dinv, all in one block (64 rows x 256 m) ----
// hi/lo split proj for near-fp32 argument precision. grid (32, BH_)
__global__ __launch_bounds__(256) void qfeatgemm(const u16* __restrict__ X,
     const u16* __restrict__ PH, const u16* __restrict__ PL,
     const float* __restrict__ diagq, const float* __restrict__ ksum,
     u16* __restrict__ qp, float* __restrict__ dinv){
  __shared__ u16 As[64*32];       // 4 KB
  __shared__ u16 Bh[256*32];      // 16 KB
  __shared__ u16 Bl[256*32];      // 16 KB
  __shared__ float ksl[256];
  __shared__ float rmax[64][4];
  __shared__ float rsum[64][4];
  int tid = threadIdx.x; int w = tid>>6, l = tid&63;
  int n0 = blockIdx.x*64;
  int z = blockIdx.y;
  const u16* A = X + (long)(z/HEADS_)*SEQ_*QKVW_ + (z%HEADS_)*DH_;  // Q cols
  ksl[tid] = ksum[(long)z*MF_ + tid];
  f32x4 acc[4][4];
  #pragma unroll
  for (int i=0;i<4;i++)
    #pragma unroll
    for (int j=0;j<4;j++) acc[i][j] = (f32x4){0.f,0.f,0.f,0.f};
  const int row_l = l>>2, cq_l = l&3;
  const int kq = l>>4, rl15 = l&15;

  for (int k0=0; k0<64; k0+=32){
    __syncthreads();
    { // A: 4 chunks of 16 rows, one per wave
      int r = w*16 + row_l;
      int gq = cq_l ^ ((r>>1)&3);
      gload16(A + (long)(n0+r)*QKVW_ + k0 + gq*8, As + w*512);
    }
    for (int c = w; c < 16; c += 4){
      int r = c*16 + row_l;
      int gq = cq_l ^ ((r>>1)&3);
      gload16(PH + (long)r*64 + k0 + gq*8, Bh + c*512);
      gload16(PL + (long)r*64 + k0 + gq*8, Bl + c*512);
    }
    __syncthreads();
    bf16x8 af[4], bh[4], bl[4];
    #pragma unroll
    for (int mi=0; mi<4; mi++){
      int rr = mi*16 + rl15;
      int g = kq ^ ((rr>>1)&3);
      af[mi] = *(const bf16x8*)(As + rr*32 + g*8);
    }
    #pragma unroll
    for (int ni=0; ni<4; ni++){
      int rr = (w*4 + ni)*16 + rl15;
      int g = kq ^ ((rr>>1)&3);
      bh[ni] = *(const bf16x8*)(Bh + rr*32 + g*8);
      bl[ni] = *(const bf16x8*)(Bl + rr*32 + g*8);
    }
    #pragma unroll
    for (int mi=0; mi<4; mi++)
      #pragma unroll
      for (int ni=0; ni<4; ni++){
        acc[mi][ni] = __builtin_amdgcn_mfma_f32_16x16x32_bf16(af[mi], bh[ni], acc[mi][ni], 0, 0, 0);
        acc[mi][ni] = __builtin_amdgcn_mfma_f32_16x16x32_bf16(af[mi], bl[ni], acc[mi][ni], 0, 0, 0);
      }
  }

  int cc = l&15, rq = l>>4;
  // per-row max over all 256 m
  #pragma unroll
  for (int mi=0; mi<4; mi++){
    #pragma unroll
    for (int r4=0; r4<4; r4++){
      float pm = fmaxf(fmaxf(acc[mi][0][r4],acc[mi][1][r4]),
                       fmaxf(acc[mi][2][r4],acc[mi][3][r4]));
      pm = fmaxf(pm, __shfl_xor(pm,1)); pm = fmaxf(pm, __shfl_xor(pm,2));
      pm = fmaxf(pm, __shfl_xor(pm,4)); pm = fmaxf(pm, __shfl_xor(pm,8));
      if (cc==0) rmax[mi*16 + rq*4 + r4][w] = pm;
    }
  }
  __syncthreads();
  #pragma unroll
  for (int mi=0; mi<4; mi++){
    #pragma unroll
    for (int r4=0; r4<4; r4++){
      int row = mi*16 + rq*4 + r4;
      float mx = fmaxf(fmaxf(rmax[row][0],rmax[row][1]),
                       fmaxf(rmax[row][2],rmax[row][3])) * DN_;
      float dq = diagq[(long)z*SEQ_ + n0 + row];
      float dv = 0.f;
      #pragma unroll
      for (int ni=0; ni<4; ni++){
        int col = w*64 + ni*16 + cc;
        float qpv = RATIO_*(expf(acc[mi][ni][r4]*DN_ - dq - mx) + EPSK_);
        u16 qb = f2bf(qpv);
        qp[((long)z*SEQ_ + n0 + row)*MF_ + col] = qb;
        dv += bf2f(qb)*ksl[col];
      }
      dv += __shfl_xor(dv,1); dv += __shfl_xor(dv,2);
      dv += __shfl_xor(dv,4); dv += __shfl_xor(dv,8);
      if (cc==0) rsum[row][w] = dv;
    }
  }
  __syncthreads();
  if (tid < 64){
    float s = rsum[tid][0]+rsum[tid][1]+rsum[tid][2]+rsum[tid][3];
    dinv[(long)z*SEQ_ + n0 + tid] = 1.0f/s;
  }
}

// ---- ctxgemm: ctxT-partial[d=64][m=256] = sum_n V[n][d]*kp[n][m] (TN, transpose-on-stage)
__global__ __launch_bounds__(256) void ctxgemm(const u16* __restrict__ qkv,
     const u16* __restrict__ kp, float* __restrict__ part){
  int kc = blockIdx.x;      // 0..1 (1024 rows each)
  int z  = blockIdx.y;
  int b = z/HEADS_, hh = z%HEADS_;
  int tid = threadIdx.x; int w = tid>>6, l = tid&63;
  __shared__ u16 Vt[64*40];
  __shared__ u16 Kpt[256*40];
  f32x4 acc[4][4];
  #pragma unroll
  for (int i=0;i<4;i++)
    #pragma unroll
    for (int j=0;j<4;j++) acc[i][j] = (f32x4){0.f,0.f,0.f,0.f};
  int n_l = tid&31, grp = tid>>5;
  const int kq = l>>4, rl15 = l&15;
  const long vbase = (long)b*SEQ_*QKVW_ + hh*DH_ + 1536;
  const long kbase = (long)z*SEQ_*MF_;

  for (int s=0; s<32; s++){
    int nG = kc*1024 + s*32 + n_l;
    __syncthreads();
    {
      u16x8 v = *(const u16x8*)(qkv + vbase + (long)nG*QKVW_ + grp*8);
      #pragma unroll
      for (int j=0;j<8;j++) Vt[(grp*8+j)*40 + n_l] = v[j];
    }
    {
      const u16* src = kp + kbase + (long)nG*MF_ + grp*32;
      #pragma unroll
      for (int q=0;q<4;q++){
        u16x8 v = *(const u16x8*)(src + q*8);
        #pragma unroll
        for (int j=0;j<8;j++) Kpt[(grp*32+q*8+j)*40 + n_l] = v[j];
      }
    }
    __syncthreads();
    bf16x8 af[4], bfr[4];
    #pragma unroll
    for (int mi=0; mi<4; mi++)
      af[mi] = *(const bf16x8*)(Vt + (mi*16+rl15)*40 + kq*8);
    #pragma unroll
    for (int ni=0; ni<4; ni++)
      bfr[ni] = *(const bf16x8*)(Kpt + ((w*4+ni)*16+rl15)*40 + kq*8);
    #pragma unroll
    for (int mi=0; mi<4; mi++)
      #pragma unroll
      for (int ni=0; ni<4; ni++)
        acc[mi][ni] = __builtin_amdgcn_mfma_f32_16x16x32_bf16(af[mi], bfr[ni], acc[mi][ni], 0, 0, 0);
  }

  int cc = l&15, rq = l>>4;
  float* pb = part + ((long)kc*BH_ + z)*(64*MF_);
  #pragma unroll
  for (int mi=0; mi<4; mi++){
    #pragma unroll
    for (int ni=0; ni<4; ni++){
      int m = (w*4+ni)*16 + cc;
      #pragma unroll
      for (int r4=0; r4<4; r4++){
        int d = mi*16 + rq*4 + r4;
        pb[(long)d*MF_ + m] = acc[mi][ni][r4];
      }
    }
  }
}

// reduce 2 ctx partials -> ctxT bf16 [z][d][m]
__global__ void ctx_reduce2(const float* __restrict__ part, u16* __restrict__ ctxT){
  const long NT = (long)BH_*64*MF_; // 786432
  for (long i = (long)blockIdx.x*256 + threadIdx.x; i < NT; i += (long)gridDim.x*256){
    ctxT[i] = f2bf(part[i] + part[NT + i]);
  }
}

// ---------------- final LN(row0) -> xnf fp32 [4][768] ----------------
__global__ __launch_bounds__(256) void lnrow0_kernel(const float* __restrict__ h,
                          const float* __restrict__ g, const float* __restrict__ bta,
                          float* __restrict__ xnf){
  int b = blockIdx.x; int t = threadIdx.x;
  const float* row = h + (long)b*SEQ_*DIM_;
  float v0=row[t], v1=row[t+256], v2=row[t+512];
  float s = v0+v1+v2, ss = v0*v0+v1*v1+v2*v2;
  int lane=t&63, wid=t>>6;
  #pragma unroll
  for (int off=32; off; off>>=1){ s += __shfl_xor(s,off); ss += __shfl_xor(ss,off); }
  __shared__ float red[8];
  if (lane==0){ red[wid]=s; red[4+wid]=ss; }
  __syncthreads();
  s  = red[0]+red[1]+red[2]+red[3];
  ss = red[4]+red[5]+red[6]+red[7];
  float mu = s*(1.0f/DIM_);
  float var = ss*(1.0f/DIM_) - mu*mu;
  float rs = rsqrtf(var + EPSLN_);
  float* xr = xnf + b*DIM_;
  xr[t]     = (v0-mu)*rs*g[t]     + bta[t];
  xr[t+256] = (v1-mu)*rs*g[t+256] + bta[t+256];
  xr[t+512] = (v2-mu)*rs*g[t+512] + bta[t+512];
}

// ---------------- pooler matvec: pooled[b][col] = tanh(xnf[b]·Wp[:,col] + bp) ----------------
__global__ __launch_bounds__(256) void poolmv_kernel(const float* __restrict__ xnf,
        const float* __restrict__ Wp, const float* __restrict__ bp,
        float* __restrict__ pooled){
  int c = blockIdx.x;      // 12 chunks of 64 cols
  int b = blockIdx.y;
  __shared__ float xs[768];
  __shared__ float red[64][5];
  int t = threadIdx.x;
  xs[t] = xnf[b*DIM_+t]; xs[t+256] = xnf[b*DIM_+t+256]; xs[t+512] = xnf[b*DIM_+t+512];
  __syncthreads();
  int col_l = t & 63, seg = t >> 6;
  int col = c*64 + col_l;
  const float* wp = Wp + col;
  float a = 0.f;
  #pragma unroll 4
  for (int i = seg*192; i < (seg+1)*192; i++) a += xs[i]*wp[(long)i*DIM_];
  red[col_l][seg] = a;
  __syncthreads();
  if (t < 64){
    float s = red[t][0]+red[t][1]+red[t][2]+red[t][3] + bp[c*64+t];
    pooled[b*DIM_ + c*64 + t] = tanhf(s);
  }
}

// ---------------- classifier: out[b][c] = pooled[b]·Wc[:,c] + bc ----------------
__global__ __launch_bounds__(256) void cls_kernel(const float* __restrict__ pooled,
        const float* __restrict__ Wc, const float* __restrict__ bc,
        float* __restrict__ out){
  int t = threadIdx.x;
  int b = t >> 6, lane = t & 63;
  float a0 = 0.f, a1 = 0.f;
  for (int i = lane; i < 768; i += 64){
    float p = pooled[b*DIM_ + i];
    a0 += p*Wc[i*2]; a1 += p*Wc[i*2+1];
  }
  #pragma unroll
  for (int off=32; off; off>>=1){ a0 += __shfl_xor(a0,off); a1 += __shfl_xor(a1,off); }
  if (lane==0){ out[b*2] = a0 + bc[0]; out[b*2+1] = a1 + bc[1]; }
}

extern "C" void kernel_launch(void* const* d_in, const int* in_sizes, int n_in,
                              void* d_out, int out_size, void* d_ws, size_t ws_size,
                              hipStream_t stream) {
  (void)in_sizes; (void)n_in; (void)out_size; (void)ws_size;
  const int*   x    = (const int*)  d_in[0];
  const float* tok  = (const float*)d_in[1];
  const float* pos  = (const float*)d_in[2];
  const float* ln1g = (const float*)d_in[3];
  const float* ln1b = (const float*)d_in[4];
  const float* Wq   = (const float*)d_in[5];
  const float* Wk   = (const float*)d_in[6];
  const float* Wv   = (const float*)d_in[7];
  const float* Wo   = (const float*)d_in[8];
  const float* bo   = (const float*)d_in[9];
  const float* proj = (const float*)d_in[10];
  const float* ln2g = (const float*)d_in[11];
  const float* ln2b = (const float*)d_in[12];
  const float* W1   = (const float*)d_in[13];
  const float* b1   = (const float*)d_in[14];
  const float* W2   = (const float*)d_in[15];
  const float* b2   = (const float*)d_in[16];
  const float* lnfg = (const float*)d_in[17];
  const float* lnfb = (const float*)d_in[18];
  const float* Wp   = (const float*)d_in[19];
  const float* bp   = (const float*)d_in[20];
  const float* Wc   = (const float*)d_in[21];
  const float* bc   = (const float*)d_in[22];
  float* out = (float*)d_out;

  // ---- workspace layout (bytes), peak 142,000,128 ----
  char* wsb = (char*)d_ws;
  float* h     = (float*)(wsb + 0);                 // 25165824 B fp32
  u16*   ybf   = (u16*)  (wsb + 25165824);          // 12582912 B region (ln out / attn out)
  // early-attn aliases inside ybf region (ln1-out dead after QKV gemm; all dead before PV):
  float* ctxp2 = (float*)(wsb + 25165824);          // 6291456 B (2 partials)
  float* diag  = (float*)(wsb + 31457280);          // 393216 B (K)
  float* diagq = (float*)(wsb + 31850496);          // 393216 B (Q)
  float* ksp   = (float*)(wsb + 32243712);          // 786432 B (16 partials)
  float* fmaxp = (float*)(wsb + 33030144);          // 6144 B
  u16*   projbf= (u16*)  (wsb + 33036288);          // 32768 B (hi)
  u16*   projlo= (u16*)  (wsb + 33069056);          // 32768 B (lo)
  float* stab  = (float*)(wsb + 33101824);          // 256 B
  // post-loop pooler aliases (whole ybf region dead then):
  float* xnf   = (float*)(wsb + 25165824);          // 12288 B
  float* pooled= (float*)(wsb + 25178112);          // 12288 B
  u16*   qkv   = (u16*)  (wsb + 37748736);          // 37748736 B = [8192][2304] bf16
  u16*   ffnbf = (u16*)  (wsb + 75497472);          // 50331648 B region
  u16*   kp    = (u16*)  (wsb + 75497472);          // alias: kp then qp then ffn
  u16*   qp    = (u16*)  (wsb + 75497472);
  u16*   wT    = (u16*)  (wsb + 125829120);         // 14155776 B
  u16*   ctxT  = (u16*)  (wsb + 139984896);         // 1572864 B
  float* ksum  = (float*)(wsb + 141557760);         // 49152 B
  float* dinv  = (float*)(wsb + 141606912);         // 393216 B -> 142000128
  u16* attnbf  = ybf;

  u16* wtq = wT;                 // [2304][768] stacked q,k,v (+o right after)
  u16* wto = wT + 1769472;
  u16* wt1 = wT + 2359296;       // [3072][768]
  u16* wt2 = wT + 4718592;       // [768][3072]

  embed_kernel<<<2048,256,0,stream>>>(x,(const float4*)tok,(const float4*)pos,(float4*)h);

  dim3 gD64(6, 128);            // N=768, 64-row tiles (FFN2 / Wo)
  dim3 gQKV(18, 64);            // N=2304
  dim3 gF(24, 64);              // N=3072
  dim3 gQ2(1, 16, BH_);         // PV batched
  dim3 gFG(2, 16, BH_);         // featgemm K
  dim3 gQF(32, BH_);            // qfeatgemm

  for (int l=0; l<DEPTH_; l++){
    const float* wq  = Wq + (size_t)l*DIM_*DIM_;
    const float* wk  = Wk + (size_t)l*DIM_*DIM_;
    const float* wv  = Wv + (size_t)l*DIM_*DIM_;
    const float* wo  = Wo + (size_t)l*DIM_*DIM_;
    const float* prj = proj + (size_t)l*MF_*DH_;
    const float* w1  = W1 + (size_t)l*DIM_*FF_;
    const float* w2  = W2 + (size_t)l*FF_*DIM_;

    tconv4_kernel<<<dim3(24,24,4),256,0,stream>>>(wq, wk, wv, wo, wtq);
    tconv_kernel<<<dim3(96,24),256,0,stream>>>(w1, wt1, 768, 3072);
    tconv_kernel<<<dim3(24,96),256,0,stream>>>(w2, wt2, 3072, 768);

    ln_kernel<<<ROWS_,256,0,stream>>>(h, ln1g+(size_t)l*DIM_, ln1b+(size_t)l*DIM_, ybf);
    mgemm<4,4,2,2,0,0,0><<<gQKV,256,0,stream>>>(ybf, wtq, nullptr, qkv, nullptr, ROWS_, QKVW_, 768, QKVW_);

    // ---- K-side FAVOR on MFMA ----
    projcvt_kernel<<<64,256,0,stream>>>(prj, projbf, projlo);
    diag2_kernel<<<dim3(8,BH_,2),256,0,stream>>>(qkv, diagq, diag);
    featgemm<0><<<gFG,256,0,stream>>>(qkv + 768, projbf, nullptr, nullptr, nullptr, fmaxp);
    fmax_reduce<<<BH_,64,0,stream>>>(fmaxp, stab);
    featgemm<1><<<gFG,256,0,stream>>>(qkv + 768, projbf, diag, stab, kp, ksp);
    ctxgemm<<<dim3(2,BH_),256,0,stream>>>(qkv, kp, ctxp2);
    ctx_reduce2<<<768,256,0,stream>>>(ctxp2, ctxT);
    ksum_reduce<<<BH_,256,0,stream>>>(ksp, ksum);

    // ---- Q-side on MFMA + PV ----
    qfeatgemm<<<gQF,256,0,stream>>>(qkv, projbf, projlo, diagq, ksum, qp, dinv);
    mgemm<2,4,4,1,0,2,1><<<gQ2,256,0,stream>>>(qp, ctxT, nullptr, attnbf, dinv, SEQ_, 64, 256, 768);

    mgemm<2,4,2,2,0,1,0><<<gD64,256,0,stream>>>(attnbf, wto, bo+(size_t)l*DIM_, h, nullptr, ROWS_, 768, 768, 768);

    ln_kernel<<<ROWS_,256,0,stream>>>(h, ln2g+(size_t)l*DIM_, ln2b+(size_t)l*DIM_, ybf);
    mgemm<4,4,2,2,1,0,0><<<gF,256,0,stream>>>(ybf, wt1, b1+(size_t)l*FF_, ffnbf, nullptr, ROWS_, 3072, 768, 3072);
    mgemm<2,4,2,2,0,1,0><<<gD64,256,0,stream>>>(ffnbf, wt2, b2+(size_t)l*DIM_, h, nullptr, ROWS_, 768, 3072, 768);
  }

  lnrow0_kernel<<<B_,256,0,stream>>>(h, lnfg, lnfb, xnf);
  poolmv_kernel<<<dim3(12,B_),256,0,stream>>>(xnf, Wp, bp, pooled);
  cls_kernel<<<1,256,0,stream>>>(pooled, Wc, bc, out);
}

// Round 10
// 2256.166 us; speedup vs baseline: 11.3870x; 1.0688x over previous
//
#include <hip/hip_runtime.h>
#include <hip/hip_bf16.h>
#include <math.h>

#define B_ 4
#define SEQ_ 2048
#define DIM_ 768
#define DEPTH_ 6
#define HEADS_ 12
#define DH_ 64
#define MF_ 256
#define FF_ 3072
#define ROWS_ 8192
#define BH_ 48
#define QKVW_ 2304
#define DN_ 0.3535533905932738f   /* 64^-0.25 */
#define RATIO_ 0.0625f            /* 256^-0.5 */
#define EPSK_ 1e-4f
#define EPSLN_ 1e-5f

typedef unsigned short u16;
typedef unsigned int   u32;
typedef __bf16 bf16x8 __attribute__((ext_vector_type(8)));
typedef u16    u16x8  __attribute__((ext_vector_type(8)));
typedef float  f32x4  __attribute__((ext_vector_type(4)));

__device__ inline u16 f2bf(float x){
  u32 u = __builtin_bit_cast(u32, x);
  return (u16)((u + 0x7FFFu + ((u>>16)&1u)) >> 16);
}
__device__ inline float bf2f(u16 v){ return __builtin_bit_cast(float, (u32)v<<16); }

__device__ inline void gload16(const u16* g, u16* lds){
  __builtin_amdgcn_global_load_lds(
    (const __attribute__((address_space(1))) u32*)(const void*)g,
    (__attribute__((address_space(3))) u32*)(void*)lds, 16, 0, 0);
}

// ---------------- embedding (h fp32) ----------------
__global__ void embed_kernel(const int* __restrict__ x, const float4* __restrict__ tok,
                             const float4* __restrict__ pos, float4* __restrict__ h){
  const int C4 = DIM_/4;
  long total = (long)ROWS_*C4;
  for (long i = (long)blockIdx.x*blockDim.x + threadIdx.x; i < total;
       i += (long)gridDim.x*blockDim.x){
    int row = (int)(i / C4); int c = (int)(i - (long)row*C4);
    int n = row & (SEQ_-1);
    float4 a = tok[(long)x[row]*C4 + c];
    float4 p = pos[(long)n*C4 + c];
    float4 o; o.x=a.x+p.x; o.y=a.y+p.y; o.z=a.z+p.z; o.w=a.w+p.w;
    h[i] = o;
  }
}

// ---------------- layernorm fp32 -> bf16 ----------------
__global__ __launch_bounds__(256) void ln_kernel(const float* __restrict__ X,
                          const float* __restrict__ g, const float* __restrict__ bta,
                          u16* __restrict__ Y){
  int row = blockIdx.x; int t = threadIdx.x;
  const float* xr = X + (long)row*DIM_;
  float v0 = xr[t], v1 = xr[t+256], v2 = xr[t+512];
  float s = v0+v1+v2;
  float ss = v0*v0+v1*v1+v2*v2;
  int lane = t&63, wid = t>>6;
  #pragma unroll
  for (int off=32; off; off>>=1){ s += __shfl_xor(s,off); ss += __shfl_xor(ss,off); }
  __shared__ float red[8];
  if (lane==0){ red[wid]=s; red[4+wid]=ss; }
  __syncthreads();
  s  = red[0]+red[1]+red[2]+red[3];
  ss = red[4]+red[5]+red[6]+red[7];
  float mu  = s*(1.0f/DIM_);
  float var = ss*(1.0f/DIM_) - mu*mu;
  float rs  = rsqrtf(var + EPSLN_);
  u16* yr = Y + (long)row*DIM_;
  yr[t]     = f2bf((v0-mu)*rs*g[t]     + bta[t]);
  yr[t+256] = f2bf((v1-mu)*rs*g[t+256] + bta[t+256]);
  yr[t+512] = f2bf((v2-mu)*rs*g[t+512] + bta[t+512]);
}

// ---------------- transpose + convert: WT[n][k] = bf16(W[k][n]) ----------------
__global__ __launch_bounds__(256) void tconv_kernel(const float* __restrict__ W,
        u16* __restrict__ WT, int K, int N){
  __shared__ float tile[32][33];
  int n0 = blockIdx.x*32, k0 = blockIdx.y*32;
  int tx = threadIdx.x & 31, ty = threadIdx.x >> 5;
  #pragma unroll
  for (int i=0;i<32;i+=8) tile[ty+i][tx] = W[(long)(k0+ty+i)*N + n0+tx];
  __syncthreads();
  #pragma unroll
  for (int i=0;i<32;i+=8) WT[(long)(n0+ty+i)*K + k0+tx] = f2bf(tile[tx][ty+i]);
}

// 4x 768x768 transposes in one launch (z selects q,k,v,o); dst blocks contiguous
__global__ __launch_bounds__(256) void tconv4_kernel(const float* __restrict__ Wq,
        const float* __restrict__ Wk, const float* __restrict__ Wv,
        const float* __restrict__ Wo, u16* __restrict__ dst){
  __shared__ float tile[32][33];
  int z = blockIdx.z;
  const float* W = (z==0)?Wq:(z==1)?Wk:(z==2)?Wv:Wo;
  u16* WT = dst + (long)z*589824;
  int n0 = blockIdx.x*32, k0 = blockIdx.y*32;
  int tx = threadIdx.x & 31, ty = threadIdx.x >> 5;
  #pragma unroll
  for (int i=0;i<32;i+=8) tile[ty+i][tx] = W[(long)(k0+ty+i)*768 + n0+tx];
  __syncthreads();
  #pragma unroll
  for (int i=0;i<32;i+=8) WT[(long)(n0+ty+i)*768 + k0+tx] = f2bf(tile[tx][ty+i]);
}

// ---------------- MFMA GEMM, BK=64 (two interleaved 32-k sub-buffers) ----------------
// C = f(A[M,K]bf16 @ BT[N,K]^T bf16 + bias)
// CMODE: 0 = bf16 store (+bias,+gelu if ACT); 1 = fp32 C += (+bias); 2 = bf16 store * scale[row]
// BATCH==0: XCD-aware bijective block swizzle (requires gridDim.x*gridDim.y % 8 == 0)
// Requires K % 64 == 0.
template<int FM, int FN, int WM, int WN, int ACT, int CMODE, int BATCH>
__global__ __launch_bounds__(256) void mgemm(const u16* __restrict__ A,
     const u16* __restrict__ BT, const float* __restrict__ bias,
     void* __restrict__ Cv, const float* __restrict__ scale,
     int M, int N, int K, int ldC){
  (void)M;
  constexpr int BM = WM*FM*16, BN = WN*FN*16;
  constexpr int ACH = BM/16, BCH = BN/16;   // 16-row chunks per half
  __shared__ u16 As[BM*64];
  __shared__ u16 Bs[BN*64];
  int tid = threadIdx.x; int w = tid>>6, l = tid&63;
  int bx, by;
  if (BATCH){ bx = blockIdx.x; by = blockIdx.y; }
  else {
    int bid = blockIdx.y*gridDim.x + blockIdx.x;
    int cpx = (gridDim.x*gridDim.y) >> 3;
    int swz = (bid & 7)*cpx + (bid >> 3);
    bx = swz % gridDim.x; by = swz / gridDim.x;
  }
  int m0 = by*BM, n0 = bx*BN;
  long coff = 0, srow0 = 0;
  if (BATCH){
    int z = blockIdx.z;
    A  += (long)z*2048*K;
    BT += (long)z*(long)N*K;
    coff  = (long)(z/HEADS_)*SEQ_*(long)ldC + (long)(z%HEADS_)*64;
    srow0 = (long)z*SEQ_;
  }
  f32x4 acc[FM][FN];
  #pragma unroll
  for (int i=0;i<FM;i++)
    #pragma unroll
    for (int j=0;j<FN;j++) acc[i][j] = (f32x4){0.f,0.f,0.f,0.f};

  const int row_l = l>>2, cq_l = l&3;
  const int wm = w / WN, wn = w % WN;
  const int kq = l>>4, rl15 = l&15;

  for (int k0=0; k0<K; k0+=64){
    __syncthreads();
    for (int c = w; c < 2*ACH; c += 4){
      int rc = c>>1, ks = c&1;
      int r = rc*16 + row_l;
      int gq = cq_l ^ ((r>>1)&3);
      gload16(A + (long)(m0+r)*K + k0 + ks*32 + gq*8, As + c*512);
    }
    for (int c = w; c < 2*BCH; c += 4){
      int rc = c>>1, ks = c&1;
      int r = rc*16 + row_l;
      int gq = cq_l ^ ((r>>1)&3);
      gload16(BT + (long)(n0+r)*K + k0 + ks*32 + gq*8, Bs + c*512);
    }
    __syncthreads();
    #pragma unroll
    for (int ks=0; ks<2; ks++){
      bf16x8 af[FM], bfr[FN];
      #pragma unroll
      for (int mi=0; mi<FM; mi++){
        int rr = (wm*FM + mi)*16 + rl15;
        int g = kq ^ ((rr>>1)&3);
        af[mi] = *(const bf16x8*)(As + ((rr>>4)*2 + ks)*512 + (rr&15)*32 + g*8);
      }
      #pragma unroll
      for (int ni=0; ni<FN; ni++){
        int rr = (wn*FN + ni)*16 + rl15;
        int g = kq ^ ((rr>>1)&3);
        bfr[ni] = *(const bf16x8*)(Bs + ((rr>>4)*2 + ks)*512 + (rr&15)*32 + g*8);
      }
      #pragma unroll
      for (int mi=0; mi<FM; mi++)
        #pragma unroll
        for (int ni=0; ni<FN; ni++)
          acc[mi][ni] = __builtin_amdgcn_mfma_f32_16x16x32_bf16(af[mi], bfr[ni], acc[mi][ni], 0, 0, 0);
    }
  }

  int cc = l&15, rq = l>>4;
  #pragma unroll
  for (int mi=0; mi<FM; mi++){
    #pragma unroll
    for (int ni=0; ni<FN; ni++){
      int gcol = n0 + (wn*FN+ni)*16 + cc;
      float bv = bias ? bias[gcol] : 0.f;
      #pragma unroll
      for (int r4=0; r4<4; r4++){
        int grow = m0 + (wm*FM+mi)*16 + rq*4 + r4;
        float v = acc[mi][ni][r4] + bv;
        if (ACT) v = 0.5f*v*(1.0f + erff(v*0.70710678118654752f));
        if (CMODE==1){
          float* C = (float*)Cv;
          C[(long)grow*ldC + gcol] += v;
        } else if (CMODE==2){
          v *= scale[srow0 + grow];
          ((u16*)Cv)[coff + (long)grow*ldC + gcol] = f2bf(v);
        } else {
          ((u16*)Cv)[(long)grow*ldC + gcol] = f2bf(v);
        }
      }
    }
  }
}

// ---- projcvt: proj fp32 [256][64] -> bf16 hi + bf16 lo (residual) ----
__global__ void projcvt_kernel(const float* __restrict__ p, u16* __restrict__ hi,
                               u16* __restrict__ lo){
  int i = blockIdx.x*256 + threadIdx.x;   // grid 64 -> 16384
  float v = p[i];
  u16 h = f2bf(v);
  hi[i] = h;
  lo[i] = f2bf(v - bf2f(h));
}

// ---- diag2: z-dim 0 -> Q cols, 1 -> K cols. diag[z][n] = 0.5*DN^2*||row||^2 ----
__global__ __launch_bounds__(256) void diag2_kernel(const u16* __restrict__ qkvp,
        float* __restrict__ diagq, float* __restrict__ diagk){
  int chunk = blockIdx.x, z = blockIdx.y, which = blockIdx.z, t = threadIdx.x;
  const u16* X = qkvp + (which ? 768 : 0);
  float* outp = which ? diagk : diagq;
  int n = chunk*256 + t;
  const u16* r = X + ((long)(z/HEADS_)*SEQ_ + n)*QKVW_ + (z%HEADS_)*DH_;
  float s = 0.f;
  #pragma unroll
  for (int q=0;q<8;q++){
    u16x8 v = *(const u16x8*)(r + q*8);
    #pragma unroll
    for (int j=0;j<8;j++){ float f = bf2f(v[j]); s += f*f; }
  }
  outp[(long)z*SEQ_ + n] = 0.5f*DN_*DN_*s;
}

// ---- FAVOR K feature GEMM (batched per z): xd = K_head[2048x64] @ projbf[256x64]^T
// MODE 0: write per-block max of xd*DN -> fmaxp[z*32 + by*2 + bx]
// MODE 1: kp[z][n][m] = bf16( RATIO*(exp(xd*DN - diag[z][n] - stab[z]) + EPS) )
//         + ksum partials: fmaxp reused as ksp[(z*16+by)*256 + col]
template<int MODE>
__global__ __launch_bounds__(256) void featgemm(const u16* __restrict__ X,
     const u16* __restrict__ PB, const float* __restrict__ diag,
     const float* __restrict__ stab, u16* __restrict__ kp,
     float* __restrict__ fmaxp){
  __shared__ u16 As[128*32];
  __shared__ u16 Bs[128*32];
  __shared__ float wred[4];
  int tid = threadIdx.x; int w = tid>>6, l = tid&63;
  int n0 = blockIdx.x*128, m0 = blockIdx.y*128;
  int z = blockIdx.z;
  const u16* A = X + (long)(z/HEADS_)*SEQ_*QKVW_ + (z%HEADS_)*DH_;
  f32x4 acc[4][4];
  #pragma unroll
  for (int i=0;i<4;i++)
    #pragma unroll
    for (int j=0;j<4;j++) acc[i][j] = (f32x4){0.f,0.f,0.f,0.f};
  const int row_l = l>>2, cq_l = l&3;
  const int wm = w>>1, wn = w&1;
  const int kq = l>>4, rl15 = l&15;

  for (int k0=0; k0<64; k0+=32){
    __syncthreads();
    for (int c = w; c < 8; c += 4){
      int r = c*16 + row_l;
      int gq = cq_l ^ ((r>>1)&3);
      gload16(A + (long)(m0+r)*QKVW_ + k0 + gq*8, As + c*512);
    }
    for (int c = w; c < 8; c += 4){
      int r = c*16 + row_l;
      int gq = cq_l ^ ((r>>1)&3);
      gload16(PB + (long)(n0+r)*64 + k0 + gq*8, Bs + c*512);
    }
    __syncthreads();
    bf16x8 af[4], bfr[4];
    #pragma unroll
    for (int mi=0; mi<4; mi++){
      int rr = (wm*4 + mi)*16 + rl15;
      int g = kq ^ ((rr>>1)&3);
      af[mi] = *(const bf16x8*)(As + rr*32 + g*8);
    }
    #pragma unroll
    for (int ni=0; ni<4; ni++){
      int rr = (wn*4 + ni)*16 + rl15;
      int g = kq ^ ((rr>>1)&3);
      bfr[ni] = *(const bf16x8*)(Bs + rr*32 + g*8);
    }
    #pragma unroll
    for (int mi=0; mi<4; mi++)
      #pragma unroll
      for (int ni=0; ni<4; ni++)
        acc[mi][ni] = __builtin_amdgcn_mfma_f32_16x16x32_bf16(af[mi], bfr[ni], acc[mi][ni], 0, 0, 0);
  }

  if (MODE==0){
    float bm = -1e30f;
    #pragma unroll
    for (int mi=0;mi<4;mi++)
      #pragma unroll
      for (int ni=0;ni<4;ni++)
        #pragma unroll
        for (int r4=0;r4<4;r4++) bm = fmaxf(bm, acc[mi][ni][r4]);
    bm *= DN_;
    #pragma unroll
    for (int off=32; off; off>>=1) bm = fmaxf(bm, __shfl_xor(bm,off));
    if (l==0) wred[w] = bm;
    __syncthreads();
    if (tid==0)
      fmaxp[z*32 + blockIdx.y*2 + blockIdx.x] =
        fmaxf(fmaxf(wred[0],wred[1]),fmaxf(wred[2],wred[3]));
  } else {
    __shared__ float ksred[128][8];
    float st = stab[z];
    int cc = l&15, rq = l>>4;
    #pragma unroll
    for (int ni=0; ni<4; ni++){
      int gcol = n0 + (wn*4+ni)*16 + cc;
      float cs = 0.f;
      #pragma unroll
      for (int mi=0; mi<4; mi++){
        #pragma unroll
        for (int r4=0; r4<4; r4++){
          int grow = m0 + (wm*4+mi)*16 + rq*4 + r4;
          float v = acc[mi][ni][r4]*DN_;
          float e = RATIO_*(expf(v - diag[(long)z*SEQ_ + grow] - st) + EPSK_);
          u16 eb = f2bf(e);
          kp[((long)z*SEQ_ + grow)*MF_ + gcol] = eb;
          cs += bf2f(eb);
        }
      }
      ksred[(wn*4+ni)*16 + cc][wm*4 + rq] = cs;
    }
    __syncthreads();
    if (tid < 128){
      float s = 0.f;
      #pragma unroll
      for (int q=0;q<8;q++) s += ksred[tid][q];
      fmaxp[((long)z*16 + blockIdx.y)*MF_ + n0 + tid] = s;
    }
  }
}

__global__ void fmax_reduce(const float* __restrict__ fmaxp, float* __restrict__ stab){
  int z = blockIdx.x, t = threadIdx.x; // 64
  float m = (t<32) ? fmaxp[z*32+t] : -1e30f;
  #pragma unroll
  for (int off=32; off; off>>=1) m = fmaxf(m, __shfl_xor(m,off));
  if (t==0) stab[z] = m;
}

__global__ void ksum_reduce(const float* __restrict__ part, float* __restrict__ ksum){
  int z = blockIdx.x; int t = threadIdx.x;
  float s = 0.f;
  #pragma unroll
  for (int c=0;c<16;c++) s += part[((long)z*16+c)*MF_ + t];
  ksum[z*MF_+t] = s;
}

// ---- Q feature GEMM + per-row max + qp + dinv, all in one block (64 rows x 256 m) ----
// hi/lo split proj for near-fp32 argument precision. grid (32, BH_)
__global__ __launch_bounds__(256) void qfeatgemm(const u16* __restrict__ X,
     const u16* __restrict__ PH, const u16* __restrict__ PL,
     const float* __restrict__ diagq, const float* __restrict__ ksum,
     u16* __restrict__ qp, float* __restrict__ dinv){
  __shared__ u16 As[64*32];       // 4 KB
  __shared__ u16 Bh[256*32];      // 16 KB
  __shared__ u16 Bl[256*32];      // 16 KB
  __shared__ float ksl[256];
  __shared__ float rmax[64][4];
  __shared__ float rsum[64][4];
  int tid = threadIdx.x; int w = tid>>6, l = tid&63;
  int n0 = blockIdx.x*64;
  int z = blockIdx.y;
  const u16* A = X + (long)(z/HEADS_)*SEQ_*QKVW_ + (z%HEADS_)*DH_;  // Q cols
  ksl[tid] = ksum[(long)z*MF_ + tid];
  f32x4 acc[4][4];
  #pragma unroll
  for (int i=0;i<4;i++)
    #pragma unroll
    for (int j=0;j<4;j++) acc[i][j] = (f32x4){0.f,0.f,0.f,0.f};
  const int row_l = l>>2, cq_l = l&3;
  const int kq = l>>4, rl15 = l&15;

  for (int k0=0; k0<64; k0+=32){
    __syncthreads();
    { // A: 4 chunks of 16 rows, one per wave
      int r = w*16 + row_l;
      int gq = cq_l ^ ((r>>1)&3);
      gload16(A + (long)(n0+r)*QKVW_ + k0 + gq*8, As + w*512);
    }
    for (int c = w; c < 16; c += 4){
      int r = c*16 + row_l;
      int gq = cq_l ^ ((r>>1)&3);
      gload16(PH + (long)r*64 + k0 + gq*8, Bh + c*512);
      gload16(PL + (long)r*64 + k0 + gq*8, Bl + c*512);
    }
    __syncthreads();
    bf16x8 af[4], bh[4], bl[4];
    #pragma unroll
    for (int mi=0; mi<4; mi++){
      int rr = mi*16 + rl15;
      int g = kq ^ ((rr>>1)&3);
      af[mi] = *(const bf16x8*)(As + rr*32 + g*8);
    }
    #pragma unroll
    for (int ni=0; ni<4; ni++){
      int rr = (w*4 + ni)*16 + rl15;
      int g = kq ^ ((rr>>1)&3);
      bh[ni] = *(const bf16x8*)(Bh + rr*32 + g*8);
      bl[ni] = *(const bf16x8*)(Bl + rr*32 + g*8);
    }
    #pragma unroll
    for (int mi=0; mi<4; mi++)
      #pragma unroll
      for (int ni=0; ni<4; ni++){
        acc[mi][ni] = __builtin_amdgcn_mfma_f32_16x16x32_bf16(af[mi], bh[ni], acc[mi][ni], 0, 0, 0);
        acc[mi][ni] = __builtin_amdgcn_mfma_f32_16x16x32_bf16(af[mi], bl[ni], acc[mi][ni], 0, 0, 0);
      }
  }

  int cc = l&15, rq = l>>4;
  // per-row max over all 256 m
  #pragma unroll
  for (int mi=0; mi<4; mi++){
    #pragma unroll
    for (int r4=0; r4<4; r4++){
      float pm = fmaxf(fmaxf(acc[mi][0][r4],acc[mi][1][r4]),
                       fmaxf(acc[mi][2][r4],acc[mi][3][r4]));
      pm = fmaxf(pm, __shfl_xor(pm,1)); pm = fmaxf(pm, __shfl_xor(pm,2));
      pm = fmaxf(pm, __shfl_xor(pm,4)); pm = fmaxf(pm, __shfl_xor(pm,8));
      if (cc==0) rmax[mi*16 + rq*4 + r4][w] = pm;
    }
  }
  __syncthreads();
  #pragma unroll
  for (int mi=0; mi<4; mi++){
    #pragma unroll
    for (int r4=0; r4<4; r4++){
      int row = mi*16 + rq*4 + r4;
      float mx = fmaxf(fmaxf(rmax[row][0],rmax[row][1]),
                       fmaxf(rmax[row][2],rmax[row][3])) * DN_;
      float dq = diagq[(long)z*SEQ_ + n0 + row];
      float dv = 0.f;
      #pragma unroll
      for (int ni=0; ni<4; ni++){
        int col = w*64 + ni*16 + cc;
        float qpv = RATIO_*(expf(acc[mi][ni][r4]*DN_ - dq - mx) + EPSK_);
        u16 qb = f2bf(qpv);
        qp[((long)z*SEQ_ + n0 + row)*MF_ + col] = qb;
        dv += bf2f(qb)*ksl[col];
      }
      dv += __shfl_xor(dv,1); dv += __shfl_xor(dv,2);
      dv += __shfl_xor(dv,4); dv += __shfl_xor(dv,8);
      if (cc==0) rsum[row][w] = dv;
    }
  }
  __syncthreads();
  if (tid < 64){
    float s = rsum[tid][0]+rsum[tid][1]+rsum[tid][2]+rsum[tid][3];
    dinv[(long)z*SEQ_ + n0 + tid] = 1.0f/s;
  }
}

// ---- ctxgemm: ctxT-partial[d=64][m=256] = sum_n V[n][d]*kp[n][m] (TN, transpose-on-stage)
__global__ __launch_bounds__(256) void ctxgemm(const u16* __restrict__ qkv,
     const u16* __restrict__ kp, float* __restrict__ part){
  int kc = blockIdx.x;      // 0..1 (1024 rows each)
  int z  = blockIdx.y;
  int b = z/HEADS_, hh = z%HEADS_;
  int tid = threadIdx.x; int w = tid>>6, l = tid&63;
  __shared__ u16 Vt[64*40];
  __shared__ u16 Kpt[256*40];
  f32x4 acc[4][4];
  #pragma unroll
  for (int i=0;i<4;i++)
    #pragma unroll
    for (int j=0;j<4;j++) acc[i][j] = (f32x4){0.f,0.f,0.f,0.f};
  int n_l = tid&31, grp = tid>>5;
  const int kq = l>>4, rl15 = l&15;
  const long vbase = (long)b*SEQ_*QKVW_ + hh*DH_ + 1536;
  const long kbase = (long)z*SEQ_*MF_;

  for (int s=0; s<32; s++){
    int nG = kc*1024 + s*32 + n_l;
    __syncthreads();
    {
      u16x8 v = *(const u16x8*)(qkv + vbase + (long)nG*QKVW_ + grp*8);
      #pragma unroll
      for (int j=0;j<8;j++) Vt[(grp*8+j)*40 + n_l] = v[j];
    }
    {
      const u16* src = kp + kbase + (long)nG*MF_ + grp*32;
      #pragma unroll
      for (int q=0;q<4;q++){
        u16x8 v = *(const u16x8*)(src + q*8);
        #pragma unroll
        for (int j=0;j<8;j++) Kpt[(grp*32+q*8+j)*40 + n_l] = v[j];
      }
    }
    __syncthreads();
    bf16x8 af[4], bfr[4];
    #pragma unroll
    for (int mi=0; mi<4; mi++)
      af[mi] = *(const bf16x8*)(Vt + (mi*16+rl15)*40 + kq*8);
    #pragma unroll
    for (int ni=0; ni<4; ni++)
      bfr[ni] = *(const bf16x8*)(Kpt + ((w*4+ni)*16+rl15)*40 + kq*8);
    #pragma unroll
    for (int mi=0; mi<4; mi++)
      #pragma unroll
      for (int ni=0; ni<4; ni++)
        acc[mi][ni] = __builtin_amdgcn_mfma_f32_16x16x32_bf16(af[mi], bfr[ni], acc[mi][ni], 0, 0, 0);
  }

  int cc = l&15, rq = l>>4;
  float* pb = part + ((long)kc*BH_ + z)*(64*MF_);
  #pragma unroll
  for (int mi=0; mi<4; mi++){
    #pragma unroll
    for (int ni=0; ni<4; ni++){
      int m = (w*4+ni)*16 + cc;
      #pragma unroll
      for (int r4=0; r4<4; r4++){
        int d = mi*16 + rq*4 + r4;
        pb[(long)d*MF_ + m] = acc[mi][ni][r4];
      }
    }
  }
}

// reduce 2 ctx partials -> ctxT bf16 [z][d][m]
__global__ void ctx_reduce2(const float* __restrict__ part, u16* __restrict__ ctxT){
  const long NT = (long)BH_*64*MF_; // 786432
  for (long i = (long)blockIdx.x*256 + threadIdx.x; i < NT; i += (long)gridDim.x*256){
    ctxT[i] = f2bf(part[i] + part[NT + i]);
  }
}

// ---------------- final LN(row0) -> xnf fp32 [4][768] ----------------
__global__ __launch_bounds__(256) void lnrow0_kernel(const float* __restrict__ h,
                          const float* __restrict__ g, const float* __restrict__ bta,
                          float* __restrict__ xnf){
  int b = blockIdx.x; int t = threadIdx.x;
  const float* row = h + (long)b*SEQ_*DIM_;
  float v0=row[t], v1=row[t+256], v2=row[t+512];
  float s = v0+v1+v2, ss = v0*v0+v1*v1+v2*v2;
  int lane=t&63, wid=t>>6;
  #pragma unroll
  for (int off=32; off; off>>=1){ s += __shfl_xor(s,off); ss += __shfl_xor(ss,off); }
  __shared__ float red[8];
  if (lane==0){ red[wid]=s; red[4+wid]=ss; }
  __syncthreads();
  s  = red[0]+red[1]+red[2]+red[3];
  ss = red[4]+red[5]+red[6]+red[7];
  float mu = s*(1.0f/DIM_);
  float var = ss*(1.0f/DIM_) - mu*mu;
  float rs = rsqrtf(var + EPSLN_);
  float* xr = xnf + b*DIM_;
  xr[t]     = (v0-mu)*rs*g[t]     + bta[t];
  xr[t+256] = (v1-mu)*rs*g[t+256] + bta[t+256];
  xr[t+512] = (v2-mu)*rs*g[t+512] + bta[t+512];
}

// ---------------- pooler matvec: pooled[b][col] = tanh(xnf[b]·Wp[:,col] + bp) ----------------
__global__ __launch_bounds__(256) void poolmv_kernel(const float* __restrict__ xnf,
        const float* __restrict__ Wp, const float* __restrict__ bp,
        float* __restrict__ pooled){
  int c = blockIdx.x;      // 12 chunks of 64 cols
  int b = blockIdx.y;
  __shared__ float xs[768];
  __shared__ float red[64][5];
  int t = threadIdx.x;
  xs[t] = xnf[b*DIM_+t]; xs[t+256] = xnf[b*DIM_+t+256]; xs[t+512] = xnf[b*DIM_+t+512];
  __syncthreads();
  int col_l = t & 63, seg = t >> 6;
  int col = c*64 + col_l;
  const float* wp = Wp + col;
  float a = 0.f;
  #pragma unroll 4
  for (int i = seg*192; i < (seg+1)*192; i++) a += xs[i]*wp[(long)i*DIM_];
  red[col_l][seg] = a;
  __syncthreads();
  if (t < 64){
    float s = red[t][0]+red[t][1]+red[t][2]+red[t][3] + bp[c*64+t];
    pooled[b*DIM_ + c*64 + t] = tanhf(s);
  }
}

// ---------------- classifier: out[b][c] = pooled[b]·Wc[:,c] + bc ----------------
__global__ __launch_bounds__(256) void cls_kernel(const float* __restrict__ pooled,
        const float* __restrict__ Wc, const float* __restrict__ bc,
        float* __restrict__ out){
  int t = threadIdx.x;
  int b = t >> 6, lane = t & 63;
  float a0 = 0.f, a1 = 0.f;
  for (int i = lane; i < 768; i += 64){
    float p = pooled[b*DIM_ + i];
    a0 += p*Wc[i*2]; a1 += p*Wc[i*2+1];
  }
  #pragma unroll
  for (int off=32; off; off>>=1){ a0 += __shfl_xor(a0,off); a1 += __shfl_xor(a1,off); }
  if (lane==0){ out[b*2] = a0 + bc[0]; out[b*2+1] = a1 + bc[1]; }
}

extern "C" void kernel_launch(void* const* d_in, const int* in_sizes, int n_in,
                              void* d_out, int out_size, void* d_ws, size_t ws_size,
                              hipStream_t stream) {
  (void)in_sizes; (void)n_in; (void)out_size; (void)ws_size;
  const int*   x    = (const int*)  d_in[0];
  const float* tok  = (const float*)d_in[1];
  const float* pos  = (const float*)d_in[2];
  const float* ln1g = (const float*)d_in[3];
  const float* ln1b = (const float*)d_in[4];
  const float* Wq   = (const float*)d_in[5];
  const float* Wk   = (const float*)d_in[6];
  const float* Wv   = (const float*)d_in[7];
  const float* Wo   = (const float*)d_in[8];
  const float* bo   = (const float*)d_in[9];
  const float* proj = (const float*)d_in[10];
  const float* ln2g = (const float*)d_in[11];
  const float* ln2b = (const float*)d_in[12];
  const float* W1   = (const float*)d_in[13];
  const float* b1   = (const float*)d_in[14];
  const float* W2   = (const float*)d_in[15];
  const float* b2   = (const float*)d_in[16];
  const float* lnfg = (const float*)d_in[17];
  const float* lnfb = (const float*)d_in[18];
  const float* Wp   = (const float*)d_in[19];
  const float* bp   = (const float*)d_in[20];
  const float* Wc   = (const float*)d_in[21];
  const float* bc   = (const float*)d_in[22];
  float* out = (float*)d_out;

  // ---- workspace layout (bytes), peak 142,000,128 ----
  char* wsb = (char*)d_ws;
  float* h     = (float*)(wsb + 0);                 // 25165824 B fp32
  u16*   ybf   = (u16*)  (wsb + 25165824);          // 12582912 B region (ln out / attn out)
  // early-attn aliases inside ybf region (ln1-out dead after QKV gemm; all dead before PV):
  float* ctxp2 = (float*)(wsb + 25165824);          // 6291456 B (2 partials)
  float* diag  = (float*)(wsb + 31457280);          // 393216 B (K)
  float* diagq = (float*)(wsb + 31850496);          // 393216 B (Q)
  float* ksp   = (float*)(wsb + 32243712);          // 786432 B (16 partials)
  float* fmaxp = (float*)(wsb + 33030144);          // 6144 B
  u16*   projbf= (u16*)  (wsb + 33036288);          // 32768 B (hi)
  u16*   projlo= (u16*)  (wsb + 33069056);          // 32768 B (lo)
  float* stab  = (float*)(wsb + 33101824);          // 256 B
  // post-loop pooler aliases (whole ybf region dead then):
  float* xnf   = (float*)(wsb + 25165824);          // 12288 B
  float* pooled= (float*)(wsb + 25178112);          // 12288 B
  u16*   qkv   = (u16*)  (wsb + 37748736);          // 37748736 B = [8192][2304] bf16
  u16*   ffnbf = (u16*)  (wsb + 75497472);          // 50331648 B region
  u16*   kp    = (u16*)  (wsb + 75497472);          // alias: kp then qp then ffn
  u16*   qp    = (u16*)  (wsb + 75497472);
  u16*   wT    = (u16*)  (wsb + 125829120);         // 14155776 B
  u16*   ctxT  = (u16*)  (wsb + 139984896);         // 1572864 B
  float* ksum  = (float*)(wsb + 141557760);         // 49152 B
  float* dinv  = (float*)(wsb + 141606912);         // 393216 B -> 142000128
  u16* attnbf  = ybf;

  u16* wtq = wT;                 // [2304][768] stacked q,k,v (+o right after)
  u16* wto = wT + 1769472;
  u16* wt1 = wT + 2359296;       // [3072][768]
  u16* wt2 = wT + 4718592;       // [768][3072]

  embed_kernel<<<2048,256,0,stream>>>(x,(const float4*)tok,(const float4*)pos,(float4*)h);

  dim3 gD64(6, 128);            // N=768, 64-row tiles (FFN2 / Wo)
  dim3 gQKV(18, 64);            // N=2304
  dim3 gF(24, 64);              // N=3072
  dim3 gQ2(1, 16, BH_);         // PV batched
  dim3 gFG(2, 16, BH_);         // featgemm K
  dim3 gQF(32, BH_);            // qfeatgemm

  for (int l=0; l<DEPTH_; l++){
    const float* wq  = Wq + (size_t)l*DIM_*DIM_;
    const float* wk  = Wk + (size_t)l*DIM_*DIM_;
    const float* wv  = Wv + (size_t)l*DIM_*DIM_;
    const float* wo  = Wo + (size_t)l*DIM_*DIM_;
    const float* prj = proj + (size_t)l*MF_*DH_;
    const float* w1  = W1 + (size_t)l*DIM_*FF_;
    const float* w2  = W2 + (size_t)l*FF_*DIM_;

    tconv4_kernel<<<dim3(24,24,4),256,0,stream>>>(wq, wk, wv, wo, wtq);
    tconv_kernel<<<dim3(96,24),256,0,stream>>>(w1, wt1, 768, 3072);
    tconv_kernel<<<dim3(24,96),256,0,stream>>>(w2, wt2, 3072, 768);

    ln_kernel<<<ROWS_,256,0,stream>>>(h, ln1g+(size_t)l*DIM_, ln1b+(size_t)l*DIM_, ybf);
    mgemm<4,4,2,2,0,0,0><<<gQKV,256,0,stream>>>(ybf, wtq, nullptr, qkv, nullptr, ROWS_, QKVW_, 768, QKVW_);

    // ---- K-side FAVOR on MFMA ----
    projcvt_kernel<<<64,256,0,stream>>>(prj, projbf, projlo);
    diag2_kernel<<<dim3(8,BH_,2),256,0,stream>>>(qkv, diagq, diag);
    featgemm<0><<<gFG,256,0,stream>>>(qkv + 768, projbf, nullptr, nullptr, nullptr, fmaxp);
    fmax_reduce<<<BH_,64,0,stream>>>(fmaxp, stab);
    featgemm<1><<<gFG,256,0,stream>>>(qkv + 768, projbf, diag, stab, kp, ksp);
    ctxgemm<<<dim3(2,BH_),256,0,stream>>>(qkv, kp, ctxp2);
    ctx_reduce2<<<768,256,0,stream>>>(ctxp2, ctxT);
    ksum_reduce<<<BH_,256,0,stream>>>(ksp, ksum);

    // ---- Q-side on MFMA + PV ----
    qfeatgemm<<<gQF,256,0,stream>>>(qkv, projbf, projlo, diagq, ksum, qp, dinv);
    mgemm<2,4,4,1,0,2,1><<<gQ2,256,0,stream>>>(qp, ctxT, nullptr, attnbf, dinv, SEQ_, 64, 256, 768);

    mgemm<2,4,2,2,0,1,0><<<gD64,256,0,stream>>>(attnbf, wto, bo+(size_t)l*DIM_, h, nullptr, ROWS_, 768, 768, 768);

    ln_kernel<<<ROWS_,256,0,stream>>>(h, ln2g+(size_t)l*DIM_, ln2b+(size_t)l*DIM_, ybf);
    mgemm<4,4,2,2,1,0,0><<<gF,256,0,stream>>>(ybf, wt1, b1+(size_t)l*FF_, ffnbf, nullptr, ROWS_, 3072, 768, 3072);
    mgemm<2,4,2,2,0,1,0><<<gD64,256,0,stream>>>(ffnbf, wt2, b2+(size_t)l*DIM_, h, nullptr, ROWS_, 768, 3072, 768);
  }

  lnrow0_kernel<<<B_,256,0,stream>>>(h, lnfg, lnfb, xnf);
  poolmv_kernel<<<dim3(12,B_),256,0,stream>>>(xnf, Wp, bp, pooled);
  cls_kernel<<<1,256,0,stream>>>(pooled, Wc, bc, out);
}